// Round 3
// baseline (1667.358 us; speedup 1.0000x reference)
//
#include <hip/hip_runtime.h>
#include <hip/hip_bf16.h>

typedef __hip_bfloat16 bf16;
__device__ __forceinline__ bf16 tobf(float v){ return __float2bfloat16(v); }
__device__ __forceinline__ float frombf(bf16 v){ return __bfloat162float(v); }

static constexpr int cB=4, cN=256, cDX=256, cDE=64, cDY=128, cNH=8, cDF=32;

// ---- workspace layout (bytes) ----
// [0, 33554432)           Gbf   (bf16, 16.7M elems)
// [33554432, 67108864)    Bbf   (bf16, 16.7M elems)
// [67108864, ...)         f32 region, offsets below in floats:
static constexpr size_t F_SIM  = 0;        // 262144
static constexpr size_t F_P    = 262144;   // 2097152
static constexpr size_t F_NP   = 2359296;  // 4194304
static constexpr size_t F_DP   = 6553600;  // 65536
static constexpr size_t F_S    = 6619136;  // 65536
static constexpr size_t F_EENC = 6684672;  // 262144
static constexpr size_t F_XPL  = 6946816;  // 262144
static constexpr size_t F_QB   = 7208960;  // 262144
static constexpr size_t F_KB   = 7471104;  // 262144
static constexpr size_t F_VB   = 7733248;  // 262144
static constexpr size_t F_YW   = 7995392;  // 1024
static constexpr size_t F_XPY  = 7996416;  // 262144
static constexpr size_t F_COEF = 8258560;  // 16
static constexpr size_t F_GENC = 8258576;  // 32768
static constexpr size_t F_XENC = 8291344;  // 65536
static constexpr size_t F_GP   = 8356880;  // 16384
static constexpr size_t F_XP   = 8373264;  // 16384
// total ~100.7 MB

// ---------------- coeff = y@Wc+bc ; yw = relu(y@W_y2) ----------------
__global__ void k_coeff_yw(const float* y, const float* Wc, const float* bc,
                           const float* W_y2, float* coeff, float* yw){
  int b = blockIdx.x; int f = threadIdx.x; // 256
  float acc = 0.f;
  for(int r=0;r<cDY;++r) acc += y[b*cDY+r]*W_y2[r*cDX+f];
  yw[b*cDX+f] = fmaxf(acc,0.f);
  if (f < 3){
    float c = bc[f];
    for(int r=0;r<cDY;++r) c += y[b*cDY+r]*Wc[r*3+f];
    coeff[b*3+f] = c;
  }
}

// ---------------- S[b,i,d] = sum_j E[b,i,j,d]*m_j ----------------
__global__ void k_reduceE(const float* E, const int* nm, float* S){
  int bi = blockIdx.x; int b = bi / cN;
  int d = threadIdx.x;  // 64
  int jy = threadIdx.y; // 4
  const float* Eb = E + (size_t)bi*cN*cDE;
  float acc = 0.f;
  for(int j=jy;j<cN;j+=4){
    acc += Eb[j*cDE+d] * (float)nm[b*cN+j];
  }
  __shared__ float red[4][64];
  red[jy][d]=acc; __syncthreads();
  if (jy==0) S[(size_t)bi*cDE+d] = red[0][d]+red[1][d]+red[2][d]+red[3][d];
}

// ---------------- e_enc[b,i,f] = relu(m_i/N * S[b,i,:]@W_emax[:,f]) ----------------
__global__ void k_eenc(const float* S, const float* W_emax, const int* nm, float* eenc){
  int bi = blockIdx.x; int b = bi/cN; int i = bi%cN;
  int f = threadIdx.x;
  __shared__ float s[cDE];
  if (f<cDE) s[f]=S[(size_t)bi*cDE+f];
  __syncthreads();
  float acc=0.f;
  for(int d=0;d<cDE;++d) acc += s[d]*W_emax[d*cDX+f];
  float mi=(float)nm[b*cN+i];
  eenc[(size_t)bi*cDX+f] = fmaxf(acc*mi*(1.f/cN), 0.f);
}

// ---------------- xplus = (X + relu(eenc@W_x1)) * m_i ----------------
__global__ void k_xplus(const float* X, const float* eenc, const float* W_x1,
                        const int* nm, float* xplus){
  int bi=blockIdx.x; int b=bi/cN; int i=bi%cN;
  int f=threadIdx.x;
  __shared__ float row[cDX];
  row[f]=eenc[(size_t)bi*cDX+f];
  __syncthreads();
  float acc=0.f;
  for(int c=0;c<cDX;++c) acc += row[c]*W_x1[c*cDX+f];
  float mi=(float)nm[b*cN+i];
  xplus[(size_t)bi*cDX+f] = (X[(size_t)bi*cDX+f] + fmaxf(acc,0.f))*mi;
}

// ---------------- q,k,v projections ----------------
__global__ void k_qkv(const float* xplus, const float* Wq, const float* Wk, const float* Wv,
                      float* qb, float* kb, float* vb){
  int bi=blockIdx.x; int f=threadIdx.x;
  __shared__ float row[cDX];
  row[f]=xplus[(size_t)bi*cDX+f];
  __syncthreads();
  float aq=0,ak=0,av=0;
  for(int c=0;c<cDX;++c){ float r=row[c]; aq+=r*Wq[c*cDX+f]; ak+=r*Wk[c*cDX+f]; av+=r*Wv[c*cDX+f]; }
  qb[(size_t)bi*cDX+f]=aq; kb[(size_t)bi*cDX+f]=ak; vb[(size_t)bi*cDX+f]=av;
}

// ---------------- attention softmax rows -> P[b,h,i,j] ----------------
__global__ void k_attn_softmax(const float* qb, const float* kb, const int* nm, float* P){
  int id=blockIdx.x; int b=id/(cNH*cN); int rem=id%(cNH*cN); int h=rem/cN; int i=rem%cN;
  int j=threadIdx.x;
  __shared__ float qrow[cDF];
  if (j<cDF) qrow[j]=qb[((size_t)b*cN+i)*cDX + h*cDF + j];
  __syncthreads();
  const float* krow = kb + ((size_t)b*cN+j)*cDX + h*cDF;
  float s=0.f;
  for(int c=0;c<cDF;++c) s += qrow[c]*krow[c];
  s *= 0.17677669529663687f; // 1/sqrt(32)
  float val = (nm[b*cN+j]>0) ? s : -1e9f;
  __shared__ float red[256];
  red[j]=val; __syncthreads();
  for(int st=128;st>0;st>>=1){ if(j<st) red[j]=fmaxf(red[j],red[j+st]); __syncthreads(); }
  float mx=red[0]; __syncthreads();
  float e=__expf(val-mx);
  red[j]=e; __syncthreads();
  for(int st=128;st>0;st>>=1){ if(j<st) red[j]+=red[j+st]; __syncthreads(); }
  float denom=red[0];
  P[(size_t)id*cN + j] = e/denom;
}

// ---------------- P@V, @Wo, *mask, +X, LayerNorm -> new_X (f32) ----------------
__global__ void k_attn_out(const float* P, const float* vb, const float* Wo,
                           const float* X, const int* nm, const float* gx, const float* bx,
                           float* newX){
  int bi=blockIdx.x; int b=bi/cN; int i=bi%cN;
  int t=threadIdx.x;
  __shared__ float p8[cNH][cN];
  for(int h=0;h<cNH;++h) p8[h][t]=P[(((size_t)b*cNH+h)*cN+i)*cN + t];
  __syncthreads();
  int h=t/cDF;
  float acc=0.f;
  for(int j=0;j<cN;++j) acc += p8[h][j]*vb[((size_t)b*cN+j)*cDX + t];
  __shared__ float arow[cDX];
  arow[t]=acc; __syncthreads();
  float o=0.f;
  for(int c=0;c<cDX;++c) o += arow[c]*Wo[c*cDX+t];
  float mi=(float)nm[b*cN+i];
  float v = o*mi + X[(size_t)bi*cDX+t];
  __shared__ float red[256];
  red[t]=v; __syncthreads();
  for(int st=128;st>0;st>>=1){ if(t<st) red[t]+=red[t+st]; __syncthreads(); }
  float mean=red[0]*(1.f/cDX); __syncthreads();
  float dv=v-mean;
  red[t]=dv*dv; __syncthreads();
  for(int st=128;st>0;st>>=1){ if(t<st) red[t]+=red[t+st]; __syncthreads(); }
  float var=red[0]*(1.f/cDX);
  newX[(size_t)bi*cDX+t]=dv*rsqrtf(var+1e-6f)*gx[t]+bx[t];
}

// ---------------- xplusy = relu((X + yw)@W_x2) ----------------
__global__ void k_xplusy(const float* X, const float* yw, const float* W_x2, float* xpy){
  int bi=blockIdx.x; int b=bi/cN;
  int f=threadIdx.x;
  __shared__ float row[cDX];
  row[f]=X[(size_t)bi*cDX+f]+yw[b*cDX+f];
  __syncthreads();
  float acc=0.f;
  for(int c=0;c<cDX;++c) acc += row[c]*W_x2[c*cDX+f];
  xpy[(size_t)bi*cDX+f]=fmaxf(acc,0.f);
}

// ---------------- sim = xpy @ xpy^T / 16 ----------------
__global__ void k_sim(const float* xp, float* sim){
  int b=blockIdx.z;
  int tx=threadIdx.x, ty=threadIdx.y;
  __shared__ float Aa[16][17], Bb[16][17];
  const float* base = xp + (size_t)b*cN*cDX;
  float acc=0.f;
  for(int kt=0;kt<cDX;kt+=16){
    Aa[ty][tx]=base[(size_t)(blockIdx.y*16+ty)*cDX + kt+tx];
    Bb[ty][tx]=base[(size_t)(blockIdx.x*16+ty)*cDX + kt+tx];
    __syncthreads();
    for(int c=0;c<16;++c) acc += Aa[ty][c]*Bb[tx][c];
    __syncthreads();
  }
  sim[((size_t)b*cN + blockIdx.y*16+ty)*cN + blockIdx.x*16+tx] = acc*(1.f/16.f);
}

// ---------------- G = (alpha*sim + E) * emask  (bf16 out) ----------------
__global__ void k_G(const float* E, const float* sim, const int* nm, const float* alpha_p,
                    bf16* G){
  int bi=blockIdx.x; int b=bi/cN; int i=bi%cN;
  float mi=(float)nm[b*cN+i];
  float alpha=alpha_p[0];
  size_t base=(size_t)bi*cN*cDE;
  for(int t=threadIdx.x;t<cN*cDE;t+=blockDim.x){
    int j=t>>6;
    float mj=(float)nm[b*cN+j];
    G[base+t]=tobf((alpha*sim[(size_t)bi*cN+j]+E[base+t])*mi*mj);
  }
}

__device__ __forceinline__ void store_out(bf16* p, float v){ *p = tobf(v); }
__device__ __forceinline__ void store_out(float* p, float v){ *p = v; }

// ---------------- batched 256x256 GEMM (bf16 in, f32 accum):
//                  C = alpha*(A@B) + beta*A ----------------
template<typename OT>
__global__ void k_bmm_poly(const bf16* A, const bf16* Bm, OT* C, const float* coeff,
                           int ia, int ib){
  int bc=blockIdx.z; int b=bc>>6;
  float alpha=(ia>=0)?coeff[b*3+ia]:1.0f;
  float beta=coeff[b*3+ib];
  const bf16* Ab=A+(size_t)bc*cN*cN;
  const bf16* Bb=Bm+(size_t)bc*cN*cN;
  OT* Cb=C+(size_t)bc*cN*cN;
  int tx=threadIdx.x, ty=threadIdx.y;
  int tid=ty*16+tx;
  __shared__ float As[16][65]; // [k][row]
  __shared__ float Bs[16][65]; // [k][col]
  float acc[4][4]={};
  for(int kt=0;kt<cN;kt+=16){
#pragma unroll
    for(int l=0;l<4;++l){
      int idx=tid+l*256;
      int rr=idx>>4, cc=idx&15;
      As[cc][rr]=frombf(Ab[(size_t)(blockIdx.y*64+rr)*cN + kt+cc]);
    }
#pragma unroll
    for(int l=0;l<4;++l){
      int idx=tid+l*256;
      int rr=idx>>6, cc=idx&63;
      Bs[rr][cc]=frombf(Bb[(size_t)(kt+rr)*cN + blockIdx.x*64+cc]);
    }
    __syncthreads();
#pragma unroll
    for(int kk=0;kk<16;++kk){
      float a0=As[kk][ty*4+0],a1=As[kk][ty*4+1],a2=As[kk][ty*4+2],a3=As[kk][ty*4+3];
      float b0=Bs[kk][tx*4+0],b1=Bs[kk][tx*4+1],b2=Bs[kk][tx*4+2],b3=Bs[kk][tx*4+3];
      acc[0][0]+=a0*b0; acc[0][1]+=a0*b1; acc[0][2]+=a0*b2; acc[0][3]+=a0*b3;
      acc[1][0]+=a1*b0; acc[1][1]+=a1*b1; acc[1][2]+=a1*b2; acc[1][3]+=a1*b3;
      acc[2][0]+=a2*b0; acc[2][1]+=a2*b1; acc[2][2]+=a2*b2; acc[2][3]+=a2*b3;
      acc[3][0]+=a3*b0; acc[3][1]+=a3*b1; acc[3][2]+=a3*b2; acc[3][3]+=a3*b3;
    }
    __syncthreads();
  }
  int r0=blockIdx.y*64+ty*4, c0=blockIdx.x*64+tx*4;
#pragma unroll
  for(int i=0;i<4;++i){
#pragma unroll
    for(int j=0;j<4;++j){
      size_t off=(size_t)(r0+i)*cN + (c0+j);
      store_out(&Cb[off], alpha*acc[i][j]+beta*frombf(Ab[off]));
    }
  }
}

// ---------------- newE(f32, staged in-place) -> relu(@W_Eout)*emask + E -> LN -> new_E (f32) ----------------
__global__ void k_Eout(const float* newE_in, const float* E, const int* nm,
                       const float* W_Eout, const float* ge, const float* be, float* outE){
  int wav=threadIdx.x>>6; int lane=threadIdx.x&63;
  size_t row=(size_t)blockIdx.x*4+wav;
  int b=(int)(row>>16); int ij=(int)(row&65535); int i=ij>>8; int j=ij&255;
  float mij=(float)(nm[b*cN+i]*nm[b*cN+j]);
  __shared__ float lds[4][cDE];
  size_t off=row*cDE;
  lds[wav][lane]=newE_in[off+lane];
  __syncthreads();
  float acc=0.f;
  for(int d=0;d<cDE;++d) acc += lds[wav][d]*W_Eout[d*cDE+lane];
  float v=fmaxf(acc,0.f)*mij + E[off+lane];
  float s=v;
  for(int m=32;m>0;m>>=1) s += __shfl_xor(s,m,64);
  float mean=s*(1.f/cDE);
  float dv=v-mean; float q=dv*dv;
  for(int m=32;m>0;m>>=1) q += __shfl_xor(q,m,64);
  float var=q*(1.f/cDE);
  outE[off+lane]=dv*rsqrtf(var+1e-6f)*ge[lane]+be[lane];
}

// ---------------- fused aG-softmax numerator/denominator partials ----------------
__global__ void __launch_bounds__(256) k_Gaccum(const float* E, const int* nm,
                                                const float* G_kernel,
                                                float* Npart, float* Dpart){
  int chunk=blockIdx.x; // 64
  int b=blockIdx.y;     // 4
  int t=threadIdx.x;    // 256
  int k=t&127; int half=t>>7;
  __shared__ float em[8][cDE];
  __shared__ float mrow[8];
  float gk[cDE];
#pragma unroll
  for(int d=0;d<cDE;++d) gk[d]=G_kernel[d*128+k];
  float acc[cDE];
#pragma unroll
  for(int d=0;d<cDE;++d) acc[d]=0.f;
  float den=0.f;
  const size_t ebase=((size_t)b)<<16;
  int base=chunk*1024;
  for(int s=0;s<128;++s){
    int p0=base+8*s;
    __syncthreads();
#pragma unroll
    for(int l=0;l<2;++l){
      int idx=t+l*256;
      int rr=idx>>6, d=idx&63;
      int pp=p0+rr;
      float m=(float)(nm[b*cN+(pp>>8)]*nm[b*cN+(pp&255)]);
      em[rr][d]=E[(ebase+pp)*cDE+d]*m;
      if(d==0) mrow[rr]=m;
    }
    __syncthreads();
#pragma unroll
    for(int rr=0;rr<4;++rr){
      int row=half*4+rr;
      if(mrow[row]>0.f){
        float lg=0.f;
#pragma unroll
        for(int d=0;d<cDE;++d) lg += em[row][d]*gk[d];
        float w=__expf(lg*0.125f);
        den+=w;
#pragma unroll
        for(int d=0;d<cDE;++d) acc[d]+=w*em[row][d];
      }
    }
  }
  size_t pi=(size_t)b*128 + chunk*2 + half;
  size_t o=(pi*128+k)*cDE;
#pragma unroll
  for(int d=0;d<cDE;++d) Npart[o+d]=acc[d];
  Dpart[pi*128+k]=den;
}

// ---------------- combine partials -> Genc[b, k*64+d] ----------------
__global__ void k_Gcombine(const float* Npart, const float* Dpart, float* Genc){
  int bk=blockIdx.x; int b=bk>>7; int k=bk&127;
  int d=threadIdx.x; // 64
  float n=0.f, dd=0.f;
  for(int pi=0;pi<128;++pi){
    size_t base=((size_t)b*128+pi)*128+k;
    n += Npart[base*cDE+d];
    dd += Dpart[base];
  }
  Genc[(size_t)b*8192 + k*cDE + d]=n/dd;
}

// ---------------- aX softmax + X_enc[b, k*256+d] ----------------
__global__ void k_Xenc(const float* X, const int* nm, const float* X_kernel, float* Xenc){
  int k=blockIdx.x;  // 64
  int b=blockIdx.y;  // 4
  int n=threadIdx.x; // 256
  float m=(float)nm[b*cN+n];
  const float* xr=X+((size_t)b*cN+n)*cDX;
  float acc=0.f;
  for(int c=0;c<cDX;++c) acc += xr[c]*X_kernel[c*64+k];
  float lg=(m>0.f)?acc*(1.f/16.f):-1e9f;
  __shared__ float red[256];
  red[n]=lg; __syncthreads();
  for(int st=128;st>0;st>>=1){ if(n<st) red[n]=fmaxf(red[n],red[n+st]); __syncthreads(); }
  float mx=red[0]; __syncthreads();
  float e=__expf(lg-mx);
  red[n]=e; __syncthreads();
  for(int st=128;st>0;st>>=1){ if(n<st) red[n]+=red[n+st]; __syncthreads(); }
  float denom=red[0]; __syncthreads();
  __shared__ float ps[256];
  ps[n]=e/denom;  // exactly 0 for masked rows
  __syncthreads();
  int d=n;
  float s=0.f;
  for(int nn=0;nn<cN;++nn) s += ps[nn]*X[((size_t)b*cN+nn)*cDX+d];
  Xenc[(size_t)b*16384 + k*cDX + d]=s;
}

// ---------------- head split-K partials ----------------
__global__ void k_headA(const float* Genc, const float* Xenc, const float* W_Gtrans,
                        const float* W_Xtrans, float* Gp, float* Xp){
  int b=blockIdx.x, ch=blockIdx.y, o=threadIdx.x; // 128
  float g=0.f;
  for(int q=ch*256;q<(ch+1)*256;++q) g += Genc[(size_t)b*8192+q]*W_Gtrans[(size_t)q*cDY+o];
  float x=0.f;
  for(int q=ch*512;q<(ch+1)*512;++q) x += Xenc[(size_t)b*16384+q]*W_Xtrans[(size_t)q*cDY+o];
  Gp[((size_t)b*32+ch)*cDY+o]=g;
  Xp[((size_t)b*32+ch)*cDY+o]=x;
}

// ---------------- head final -> new_y (f32) ----------------
__global__ void k_headB(const float* Gp, const float* Xp, const float* W_yout,
                        const float* y, const float* gy, const float* by, float* newy){
  int b=blockIdx.x; int o=threadIdx.x; // 128
  float g=0.f,x=0.f;
  for(int ch=0;ch<32;++ch){ g+=Gp[((size_t)b*32+ch)*cDY+o]; x+=Xp[((size_t)b*32+ch)*cDY+o]; }
  __shared__ float srow[cDY];
  srow[o]=fmaxf(g,0.f)+fmaxf(x,0.f);
  __syncthreads();
  float h=0.f;
  for(int r=0;r<cDY;++r) h += srow[r]*W_yout[r*cDY+o];
  float v=fmaxf(h,0.f)+y[b*cDY+o];
  __shared__ float red[cDY];
  red[o]=v; __syncthreads();
  for(int st=64;st>0;st>>=1){ if(o<st) red[o]+=red[o+st]; __syncthreads(); }
  float mean=red[0]*(1.f/cDY); __syncthreads();
  float dv=v-mean;
  red[o]=dv*dv; __syncthreads();
  for(int st=64;st>0;st>>=1){ if(o<st) red[o]+=red[o+st]; __syncthreads(); }
  float var=red[0]*(1.f/cDY);
  newy[b*cDY+o]=dv*rsqrtf(var+1e-6f)*gy[o]+by[o];
}

extern "C" void kernel_launch(void* const* d_in, const int* in_sizes, int n_in,
                              void* d_out, int out_size, void* d_ws, size_t ws_size,
                              hipStream_t stream){
  const float* X     =(const float*)d_in[0];
  const float* E     =(const float*)d_in[1];
  const float* y     =(const float*)d_in[2];
  const int*   nm    =(const int*)  d_in[3];
  const float* W_emax=(const float*)d_in[4];
  const float* W_x1  =(const float*)d_in[5];
  const float* Wq    =(const float*)d_in[6];
  const float* Wk    =(const float*)d_in[7];
  const float* Wv    =(const float*)d_in[8];
  const float* Wo    =(const float*)d_in[9];
  const float* W_y2  =(const float*)d_in[10];
  const float* W_x2  =(const float*)d_in[11];
  const float* Wc    =(const float*)d_in[12];
  const float* bc    =(const float*)d_in[13];
  const float* salpha=(const float*)d_in[14];
  const float* W_Eout=(const float*)d_in[15];
  const float* G_kern=(const float*)d_in[16];
  const float* X_kern=(const float*)d_in[17];
  const float* W_Gtr =(const float*)d_in[18];
  const float* W_Xtr =(const float*)d_in[19];
  const float* W_yout=(const float*)d_in[20];
  const float* gx    =(const float*)d_in[21];
  const float* bx    =(const float*)d_in[22];
  const float* ge    =(const float*)d_in[23];
  const float* be    =(const float*)d_in[24];
  const float* gy    =(const float*)d_in[25];
  const float* by    =(const float*)d_in[26];

  char* wsb=(char*)d_ws;
  bf16* Gbf=(bf16*)wsb;
  bf16* Bbf=(bf16*)(wsb+33554432);
  float* f32=(float*)(wsb+67108864);
  float* sim  = f32+F_SIM;
  float* P    = f32+F_P;
  float* Npart= f32+F_NP;
  float* Dpart= f32+F_DP;
  float* S    = f32+F_S;
  float* eenc = f32+F_EENC;
  float* xplus= f32+F_XPL;
  float* qb   = f32+F_QB;
  float* kb   = f32+F_KB;
  float* vb   = f32+F_VB;
  float* yw   = f32+F_YW;
  float* xpy  = f32+F_XPY;
  float* coeff= f32+F_COEF;
  float* Genc = f32+F_GENC;
  float* Xenc = f32+F_XENC;
  float* Gp   = f32+F_GP;
  float* Xp   = f32+F_XP;

  float* out=(float*)d_out;          // reference outputs are float32
  float* newX=out;                   // [0, 262144)
  float* newE_out=out+262144;        // [262144, 17039360) — also stages pre-Eout NEWE
  float* newy=out+17039360;          // [17039360, 17039872)

  k_coeff_yw<<<cB,256,0,stream>>>(y,Wc,bc,W_y2,coeff,yw);
  k_reduceE<<<cB*cN,dim3(64,4),0,stream>>>(E,nm,S);
  k_eenc<<<cB*cN,256,0,stream>>>(S,W_emax,nm,eenc);
  k_xplus<<<cB*cN,256,0,stream>>>(X,eenc,W_x1,nm,xplus);
  k_qkv<<<cB*cN,256,0,stream>>>(xplus,Wq,Wk,Wv,qb,kb,vb);
  k_attn_softmax<<<cB*cNH*cN,256,0,stream>>>(qb,kb,nm,P);
  k_attn_out<<<cB*cN,256,0,stream>>>(P,vb,Wo,X,nm,gx,bx,newX);
  k_xplusy<<<cB*cN,256,0,stream>>>(X,yw,W_x2,xpy);
  k_sim<<<dim3(16,16,cB),dim3(16,16),0,stream>>>(xpy,sim);
  k_G<<<cB*cN,256,0,stream>>>(E,sim,nm,salpha,Gbf);
  // Bbf = c0*(G@G) + c1*G ; NEWE = G@Bbf + c2*G  (staged f32 in d_out new_E slot)
  k_bmm_poly<bf16><<<dim3(4,4,cB*cDE),dim3(16,16),0,stream>>>(Gbf,Gbf,Bbf,coeff,0,1);
  k_bmm_poly<float><<<dim3(4,4,cB*cDE),dim3(16,16),0,stream>>>(Gbf,Bbf,newE_out,coeff,-1,2);
  k_Eout<<<65536,256,0,stream>>>(newE_out,E,nm,W_Eout,ge,be,newE_out);
  k_Gaccum<<<dim3(64,cB),256,0,stream>>>(E,nm,G_kern,Npart,Dpart);
  k_Gcombine<<<cB*128,64,0,stream>>>(Npart,Dpart,Genc);
  k_Xenc<<<dim3(64,cB),256,0,stream>>>(X,nm,X_kern,Xenc);
  k_headA<<<dim3(cB,32),128,0,stream>>>(Genc,Xenc,W_Gtr,W_Xtr,Gp,Xp);
  k_headB<<<cB,128,0,stream>>>(Gp,Xp,W_yout,y,gy,by,newy);
}

// Round 4
// 1008.077 us; speedup vs baseline: 1.6540x; 1.6540x over previous
//
#include <hip/hip_runtime.h>
#include <hip/hip_bf16.h>

typedef __hip_bfloat16 bf16;
__device__ __forceinline__ bf16 tobf(float v){ return __float2bfloat16(v); }
__device__ __forceinline__ float frombf(bf16 v){ return __bfloat162float(v); }

static constexpr int cB=4, cN=256, cDX=256, cDE=64, cDY=128, cNH=8, cDF=32;

// ---- workspace layout (bytes) ----
// [0, 33554432)           Gbf   (bf16, 16.7M elems)
// [33554432, 67108864)    Bbf   (bf16, 16.7M elems)  -- after poly2: Npart f32 (8388608 floats, exact fit)
// [67108864, ...)         f32 region, offsets below in floats:
static constexpr size_t F_SIM  = 0;        // 262144
static constexpr size_t F_P    = 262144;   // 2097152
static constexpr size_t F_NP   = 2359296;  // 4194304 (holds Dpart now: 131072 used)
static constexpr size_t F_DP   = 6553600;  // 65536 (unused)
static constexpr size_t F_S    = 6619136;  // 65536
static constexpr size_t F_EENC = 6684672;  // 262144
static constexpr size_t F_XPL  = 6946816;  // 262144
static constexpr size_t F_QB   = 7208960;  // 262144
static constexpr size_t F_KB   = 7471104;  // 262144
static constexpr size_t F_VB   = 7733248;  // 262144
static constexpr size_t F_YW   = 7995392;  // 1024
static constexpr size_t F_XPY  = 7996416;  // 262144
static constexpr size_t F_COEF = 8258560;  // 16
static constexpr size_t F_GENC = 8258576;  // 32768
static constexpr size_t F_XENC = 8291344;  // 65536
static constexpr size_t F_GP   = 8356880;  // 16384
static constexpr size_t F_XP   = 8373264;  // 16384

// ---------------- coeff = y@Wc+bc ; yw = relu(y@W_y2) ----------------
__global__ void k_coeff_yw(const float* y, const float* Wc, const float* bc,
                           const float* W_y2, float* coeff, float* yw){
  int b = blockIdx.x; int f = threadIdx.x; // 256
  float acc = 0.f;
  for(int r=0;r<cDY;++r) acc += y[b*cDY+r]*W_y2[r*cDX+f];
  yw[b*cDX+f] = fmaxf(acc,0.f);
  if (f < 3){
    float c = bc[f];
    for(int r=0;r<cDY;++r) c += y[b*cDY+r]*Wc[r*3+f];
    coeff[b*3+f] = c;
  }
}

// ---------------- S[b,i,d] = sum_j E[b,i,j,d]*m_j ----------------
__global__ void k_reduceE(const float* E, const int* nm, float* S){
  int bi = blockIdx.x; int b = bi / cN;
  int d = threadIdx.x;  // 64
  int jy = threadIdx.y; // 4
  const float* Eb = E + (size_t)bi*cN*cDE;
  float acc = 0.f;
  for(int j=jy;j<cN;j+=4){
    acc += Eb[j*cDE+d] * (float)nm[b*cN+j];
  }
  __shared__ float red[4][64];
  red[jy][d]=acc; __syncthreads();
  if (jy==0) S[(size_t)bi*cDE+d] = red[0][d]+red[1][d]+red[2][d]+red[3][d];
}

// ---------------- e_enc[b,i,f] = relu(m_i/N * S[b,i,:]@W_emax[:,f]) ----------------
__global__ void k_eenc(const float* S, const float* W_emax, const int* nm, float* eenc){
  int bi = blockIdx.x; int b = bi/cN; int i = bi%cN;
  int f = threadIdx.x;
  __shared__ float s[cDE];
  if (f<cDE) s[f]=S[(size_t)bi*cDE+f];
  __syncthreads();
  float acc=0.f;
  for(int d=0;d<cDE;++d) acc += s[d]*W_emax[d*cDX+f];
  float mi=(float)nm[b*cN+i];
  eenc[(size_t)bi*cDX+f] = fmaxf(acc*mi*(1.f/cN), 0.f);
}

// ---------------- xplus = (X + relu(eenc@W_x1)) * m_i ----------------
__global__ void k_xplus(const float* X, const float* eenc, const float* W_x1,
                        const int* nm, float* xplus){
  int bi=blockIdx.x; int b=bi/cN; int i=bi%cN;
  int f=threadIdx.x;
  __shared__ float row[cDX];
  row[f]=eenc[(size_t)bi*cDX+f];
  __syncthreads();
  float acc=0.f;
  for(int c=0;c<cDX;++c) acc += row[c]*W_x1[c*cDX+f];
  float mi=(float)nm[b*cN+i];
  xplus[(size_t)bi*cDX+f] = (X[(size_t)bi*cDX+f] + fmaxf(acc,0.f))*mi;
}

// ---------------- q,k,v projections ----------------
__global__ void k_qkv(const float* xplus, const float* Wq, const float* Wk, const float* Wv,
                      float* qb, float* kb, float* vb){
  int bi=blockIdx.x; int f=threadIdx.x;
  __shared__ float row[cDX];
  row[f]=xplus[(size_t)bi*cDX+f];
  __syncthreads();
  float aq=0,ak=0,av=0;
  for(int c=0;c<cDX;++c){ float r=row[c]; aq+=r*Wq[c*cDX+f]; ak+=r*Wk[c*cDX+f]; av+=r*Wv[c*cDX+f]; }
  qb[(size_t)bi*cDX+f]=aq; kb[(size_t)bi*cDX+f]=ak; vb[(size_t)bi*cDX+f]=av;
}

// ---------------- attention softmax rows -> P[b,h,i,j] ----------------
__global__ void k_attn_softmax(const float* qb, const float* kb, const int* nm, float* P){
  int id=blockIdx.x; int b=id/(cNH*cN); int rem=id%(cNH*cN); int h=rem/cN; int i=rem%cN;
  int j=threadIdx.x;
  __shared__ float qrow[cDF];
  if (j<cDF) qrow[j]=qb[((size_t)b*cN+i)*cDX + h*cDF + j];
  __syncthreads();
  const float* krow = kb + ((size_t)b*cN+j)*cDX + h*cDF;
  float s=0.f;
  for(int c=0;c<cDF;++c) s += qrow[c]*krow[c];
  s *= 0.17677669529663687f; // 1/sqrt(32)
  float val = (nm[b*cN+j]>0) ? s : -1e9f;
  __shared__ float red[256];
  red[j]=val; __syncthreads();
  for(int st=128;st>0;st>>=1){ if(j<st) red[j]=fmaxf(red[j],red[j+st]); __syncthreads(); }
  float mx=red[0]; __syncthreads();
  float e=__expf(val-mx);
  red[j]=e; __syncthreads();
  for(int st=128;st>0;st>>=1){ if(j<st) red[j]+=red[j+st]; __syncthreads(); }
  float denom=red[0];
  P[(size_t)id*cN + j] = e/denom;
}

// ---------------- P@V, @Wo, *mask, +X, LayerNorm -> new_X (f32) ----------------
__global__ void k_attn_out(const float* P, const float* vb, const float* Wo,
                           const float* X, const int* nm, const float* gx, const float* bx,
                           float* newX){
  int bi=blockIdx.x; int b=bi/cN; int i=bi%cN;
  int t=threadIdx.x;
  __shared__ float p8[cNH][cN];
  for(int h=0;h<cNH;++h) p8[h][t]=P[(((size_t)b*cNH+h)*cN+i)*cN + t];
  __syncthreads();
  int h=t/cDF;
  float acc=0.f;
  for(int j=0;j<cN;++j) acc += p8[h][j]*vb[((size_t)b*cN+j)*cDX + t];
  __shared__ float arow[cDX];
  arow[t]=acc; __syncthreads();
  float o=0.f;
  for(int c=0;c<cDX;++c) o += arow[c]*Wo[c*cDX+t];
  float mi=(float)nm[b*cN+i];
  float v = o*mi + X[(size_t)bi*cDX+t];
  __shared__ float red[256];
  red[t]=v; __syncthreads();
  for(int st=128;st>0;st>>=1){ if(t<st) red[t]+=red[t+st]; __syncthreads(); }
  float mean=red[0]*(1.f/cDX); __syncthreads();
  float dv=v-mean;
  red[t]=dv*dv; __syncthreads();
  for(int st=128;st>0;st>>=1){ if(t<st) red[t]+=red[t+st]; __syncthreads(); }
  float var=red[0]*(1.f/cDX);
  newX[(size_t)bi*cDX+t]=dv*rsqrtf(var+1e-6f)*gx[t]+bx[t];
}

// ---------------- xplusy = relu((X + yw)@W_x2) ----------------
__global__ void k_xplusy(const float* X, const float* yw, const float* W_x2, float* xpy){
  int bi=blockIdx.x; int b=bi/cN;
  int f=threadIdx.x;
  __shared__ float row[cDX];
  row[f]=X[(size_t)bi*cDX+f]+yw[b*cDX+f];
  __syncthreads();
  float acc=0.f;
  for(int c=0;c<cDX;++c) acc += row[c]*W_x2[c*cDX+f];
  xpy[(size_t)bi*cDX+f]=fmaxf(acc,0.f);
}

// ---------------- sim = xpy @ xpy^T / 16 ----------------
__global__ void k_sim(const float* xp, float* sim){
  int b=blockIdx.z;
  int tx=threadIdx.x, ty=threadIdx.y;
  __shared__ float Aa[16][17], Bb[16][17];
  const float* base = xp + (size_t)b*cN*cDX;
  float acc=0.f;
  for(int kt=0;kt<cDX;kt+=16){
    Aa[ty][tx]=base[(size_t)(blockIdx.y*16+ty)*cDX + kt+tx];
    Bb[ty][tx]=base[(size_t)(blockIdx.x*16+ty)*cDX + kt+tx];
    __syncthreads();
    for(int c=0;c<16;++c) acc += Aa[ty][c]*Bb[tx][c];
    __syncthreads();
  }
  sim[((size_t)b*cN + blockIdx.y*16+ty)*cN + blockIdx.x*16+tx] = acc*(1.f/16.f);
}

// ---------------- G = (alpha*sim + E) * emask  (bf16 out) ----------------
__global__ void k_G(const float* E, const float* sim, const int* nm, const float* alpha_p,
                    bf16* G){
  int bi=blockIdx.x; int b=bi/cN; int i=bi%cN;
  float mi=(float)nm[b*cN+i];
  float alpha=alpha_p[0];
  size_t base=(size_t)bi*cN*cDE;
  for(int t=threadIdx.x;t<cN*cDE;t+=blockDim.x){
    int j=t>>6;
    float mj=(float)nm[b*cN+j];
    G[base+t]=tobf((alpha*sim[(size_t)bi*cN+j]+E[base+t])*mi*mj);
  }
}

__device__ __forceinline__ void store_out(bf16* p, float v){ *p = tobf(v); }
__device__ __forceinline__ void store_out(float* p, float v){ *p = v; }

// ---------------- batched 256x256 GEMM (bf16 in, f32 accum):
//                  C = alpha*(A@B) + beta*A ----------------
template<typename OT>
__global__ void k_bmm_poly(const bf16* A, const bf16* Bm, OT* C, const float* coeff,
                           int ia, int ib){
  int bc=blockIdx.z; int b=bc>>6;
  float alpha=(ia>=0)?coeff[b*3+ia]:1.0f;
  float beta=coeff[b*3+ib];
  const bf16* Ab=A+(size_t)bc*cN*cN;
  const bf16* Bb=Bm+(size_t)bc*cN*cN;
  OT* Cb=C+(size_t)bc*cN*cN;
  int tx=threadIdx.x, ty=threadIdx.y;
  int tid=ty*16+tx;
  __shared__ float As[16][65]; // [k][row]
  __shared__ float Bs[16][65]; // [k][col]
  float acc[4][4]={};
  for(int kt=0;kt<cN;kt+=16){
#pragma unroll
    for(int l=0;l<4;++l){
      int idx=tid+l*256;
      int rr=idx>>4, cc=idx&15;
      As[cc][rr]=frombf(Ab[(size_t)(blockIdx.y*64+rr)*cN + kt+cc]);
    }
#pragma unroll
    for(int l=0;l<4;++l){
      int idx=tid+l*256;
      int rr=idx>>6, cc=idx&63;
      Bs[rr][cc]=frombf(Bb[(size_t)(kt+rr)*cN + blockIdx.x*64+cc]);
    }
    __syncthreads();
#pragma unroll
    for(int kk=0;kk<16;++kk){
      float a0=As[kk][ty*4+0],a1=As[kk][ty*4+1],a2=As[kk][ty*4+2],a3=As[kk][ty*4+3];
      float b0=Bs[kk][tx*4+0],b1=Bs[kk][tx*4+1],b2=Bs[kk][tx*4+2],b3=Bs[kk][tx*4+3];
      acc[0][0]+=a0*b0; acc[0][1]+=a0*b1; acc[0][2]+=a0*b2; acc[0][3]+=a0*b3;
      acc[1][0]+=a1*b0; acc[1][1]+=a1*b1; acc[1][2]+=a1*b2; acc[1][3]+=a1*b3;
      acc[2][0]+=a2*b0; acc[2][1]+=a2*b1; acc[2][2]+=a2*b2; acc[2][3]+=a2*b3;
      acc[3][0]+=a3*b0; acc[3][1]+=a3*b1; acc[3][2]+=a3*b2; acc[3][3]+=a3*b3;
    }
    __syncthreads();
  }
  int r0=blockIdx.y*64+ty*4, c0=blockIdx.x*64+tx*4;
#pragma unroll
  for(int i=0;i<4;++i){
#pragma unroll
    for(int j=0;j<4;++j){
      size_t off=(size_t)(r0+i)*cN + (c0+j);
      store_out(&Cb[off], alpha*acc[i][j]+beta*frombf(Ab[off]));
    }
  }
}

// ---------------- newE(f32, staged in-place) -> relu(@W_Eout)*emask + E -> LN -> new_E (f32) ----------------
__global__ void k_Eout(const float* newE_in, const float* E, const int* nm,
                       const float* W_Eout, const float* ge, const float* be, float* outE){
  int wav=threadIdx.x>>6; int lane=threadIdx.x&63;
  size_t row=(size_t)blockIdx.x*4+wav;
  int b=(int)(row>>16); int ij=(int)(row&65535); int i=ij>>8; int j=ij&255;
  float mij=(float)(nm[b*cN+i]*nm[b*cN+j]);
  __shared__ float lds[4][cDE];
  size_t off=row*cDE;
  lds[wav][lane]=newE_in[off+lane];
  __syncthreads();
  float acc=0.f;
  for(int d=0;d<cDE;++d) acc += lds[wav][d]*W_Eout[d*cDE+lane];
  float v=fmaxf(acc,0.f)*mij + E[off+lane];
  float s=v;
  for(int m=32;m>0;m>>=1) s += __shfl_xor(s,m,64);
  float mean=s*(1.f/cDE);
  float dv=v-mean; float q=dv*dv;
  for(int m=32;m>0;m>>=1) q += __shfl_xor(q,m,64);
  float var=q*(1.f/cDE);
  outE[off+lane]=dv*rsqrtf(var+1e-6f)*ge[lane]+be[lane];
}

// ---------------- fused aG-softmax partials (restructured: no spills) ----------------
// thread = (dq = t&3 owns d in [dq*16, dq*16+16); kk = t>>2 owns k in {kk, kk+64})
// 64-d logit dot built from 16-d partials combined via shfl_xor(1,2) in 4-lane groups.
__global__ void __launch_bounds__(256) k_Gaccum(const float* E, const int* nm,
                                                const float* G_kernel,
                                                float* Npart, float* Dpart){
  int chunk=blockIdx.x; // 256 chunks of 256 p-rows
  int b=blockIdx.y;     // 4
  int t=threadIdx.x;    // 256
  int dq=t&3;
  int kk=t>>2;          // 0..63
  float gk0[16], gk1[16];
#pragma unroll
  for(int d=0;d<16;++d){
    gk0[d]=G_kernel[(dq*16+d)*128 + kk];
    gk1[d]=G_kernel[(dq*16+d)*128 + kk+64];
  }
  float acc0[16], acc1[16];
#pragma unroll
  for(int d=0;d<16;++d){ acc0[d]=0.f; acc1[d]=0.f; }
  float den0=0.f, den1=0.f;
  __shared__ float em[8][cDE];
  __shared__ float mrow[8];
  const size_t ebase=((size_t)b)<<16;
  int base=chunk*256;
  for(int s=0;s<32;++s){
    int p0=base+8*s;
    __syncthreads();
#pragma unroll
    for(int l=0;l<2;++l){
      int idx=t+l*256;
      int rr=idx>>6, d=idx&63;
      int pp=p0+rr;
      float m=(float)(nm[b*cN+(pp>>8)]*nm[b*cN+(pp&255)]);
      em[rr][d]=E[(ebase+pp)*cDE+d]*m;
      if(d==0) mrow[rr]=m;
    }
    __syncthreads();
    for(int rr=0;rr<8;++rr){
      if(mrow[rr]<=0.f) continue;   // wave-uniform skip
      float r[16];
#pragma unroll
      for(int d=0;d<16;++d) r[d]=em[rr][dq*16+d];
      float pd0=0.f, pd1=0.f;
#pragma unroll
      for(int d=0;d<16;++d){ pd0+=r[d]*gk0[d]; pd1+=r[d]*gk1[d]; }
      pd0+=__shfl_xor(pd0,1); pd0+=__shfl_xor(pd0,2);
      pd1+=__shfl_xor(pd1,1); pd1+=__shfl_xor(pd1,2);
      float w0=__expf(pd0*0.125f), w1=__expf(pd1*0.125f);
      den0+=w0; den1+=w1;
#pragma unroll
      for(int d=0;d<16;++d){ acc0[d]+=w0*r[d]; acc1[d]+=w1*r[d]; }
    }
  }
  size_t pi=(size_t)b*256+chunk;
  float* np=Npart + pi*128*cDE;
#pragma unroll
  for(int d=0;d<16;++d){
    np[(size_t)kk*cDE + dq*16+d]=acc0[d];
    np[(size_t)(kk+64)*cDE + dq*16+d]=acc1[d];
  }
  if(dq==0){
    Dpart[pi*128+kk]=den0;
    Dpart[pi*128+kk+64]=den1;
  }
}

// ---------------- combine partials -> Genc[b, k*64+d] ----------------
__global__ void k_Gcombine(const float* Npart, const float* Dpart, float* Genc){
  int bk=blockIdx.x; int b=bk>>7; int k=bk&127;
  int d=threadIdx.x; // 64
  float n=0.f, dd=0.f;
  for(int pi=0;pi<256;++pi){
    size_t base=((size_t)b*256+pi)*128+k;
    n += Npart[base*cDE+d];
    dd += Dpart[base];
  }
  Genc[(size_t)b*8192 + k*cDE + d]=n/dd;
}

// ---------------- aX softmax + X_enc[b, k*256+d] ----------------
__global__ void k_Xenc(const float* X, const int* nm, const float* X_kernel, float* Xenc){
  int k=blockIdx.x;  // 64
  int b=blockIdx.y;  // 4
  int n=threadIdx.x; // 256
  float m=(float)nm[b*cN+n];
  const float* xr=X+((size_t)b*cN+n)*cDX;
  float acc=0.f;
  for(int c=0;c<cDX;++c) acc += xr[c]*X_kernel[c*64+k];
  float lg=(m>0.f)?acc*(1.f/16.f):-1e9f;
  __shared__ float red[256];
  red[n]=lg; __syncthreads();
  for(int st=128;st>0;st>>=1){ if(n<st) red[n]=fmaxf(red[n],red[n+st]); __syncthreads(); }
  float mx=red[0]; __syncthreads();
  float e=__expf(lg-mx);
  red[n]=e; __syncthreads();
  for(int st=128;st>0;st>>=1){ if(n<st) red[n]+=red[n+st]; __syncthreads(); }
  float denom=red[0]; __syncthreads();
  __shared__ float ps[256];
  ps[n]=e/denom;  // exactly 0 for masked rows
  __syncthreads();
  int d=n;
  float s=0.f;
  for(int nn=0;nn<cN;++nn) s += ps[nn]*X[((size_t)b*cN+nn)*cDX+d];
  Xenc[(size_t)b*16384 + k*cDX + d]=s;
}

// ---------------- head split-K partials ----------------
__global__ void k_headA(const float* Genc, const float* Xenc, const float* W_Gtrans,
                        const float* W_Xtrans, float* Gp, float* Xp){
  int b=blockIdx.x, ch=blockIdx.y, o=threadIdx.x; // 128
  float g=0.f;
  for(int q=ch*256;q<(ch+1)*256;++q) g += Genc[(size_t)b*8192+q]*W_Gtrans[(size_t)q*cDY+o];
  float x=0.f;
  for(int q=ch*512;q<(ch+1)*512;++q) x += Xenc[(size_t)b*16384+q]*W_Xtrans[(size_t)q*cDY+o];
  Gp[((size_t)b*32+ch)*cDY+o]=g;
  Xp[((size_t)b*32+ch)*cDY+o]=x;
}

// ---------------- head final -> new_y (f32) ----------------
__global__ void k_headB(const float* Gp, const float* Xp, const float* W_yout,
                        const float* y, const float* gy, const float* by, float* newy){
  int b=blockIdx.x; int o=threadIdx.x; // 128
  float g=0.f,x=0.f;
  for(int ch=0;ch<32;++ch){ g+=Gp[((size_t)b*32+ch)*cDY+o]; x+=Xp[((size_t)b*32+ch)*cDY+o]; }
  __shared__ float srow[cDY];
  srow[o]=fmaxf(g,0.f)+fmaxf(x,0.f);
  __syncthreads();
  float h=0.f;
  for(int r=0;r<cDY;++r) h += srow[r]*W_yout[r*cDY+o];
  float v=fmaxf(h,0.f)+y[b*cDY+o];
  __shared__ float red[cDY];
  red[o]=v; __syncthreads();
  for(int st=64;st>0;st>>=1){ if(o<st) red[o]+=red[o+st]; __syncthreads(); }
  float mean=red[0]*(1.f/cDY); __syncthreads();
  float dv=v-mean;
  red[o]=dv*dv; __syncthreads();
  for(int st=64;st>0;st>>=1){ if(o<st) red[o]+=red[o+st]; __syncthreads(); }
  float var=red[0]*(1.f/cDY);
  newy[b*cDY+o]=dv*rsqrtf(var+1e-6f)*gy[o]+by[o];
}

extern "C" void kernel_launch(void* const* d_in, const int* in_sizes, int n_in,
                              void* d_out, int out_size, void* d_ws, size_t ws_size,
                              hipStream_t stream){
  const float* X     =(const float*)d_in[0];
  const float* E     =(const float*)d_in[1];
  const float* y     =(const float*)d_in[2];
  const int*   nm    =(const int*)  d_in[3];
  const float* W_emax=(const float*)d_in[4];
  const float* W_x1  =(const float*)d_in[5];
  const float* Wq    =(const float*)d_in[6];
  const float* Wk    =(const float*)d_in[7];
  const float* Wv    =(const float*)d_in[8];
  const float* Wo    =(const float*)d_in[9];
  const float* W_y2  =(const float*)d_in[10];
  const float* W_x2  =(const float*)d_in[11];
  const float* Wc    =(const float*)d_in[12];
  const float* bc    =(const float*)d_in[13];
  const float* salpha=(const float*)d_in[14];
  const float* W_Eout=(const float*)d_in[15];
  const float* G_kern=(const float*)d_in[16];
  const float* X_kern=(const float*)d_in[17];
  const float* W_Gtr =(const float*)d_in[18];
  const float* W_Xtr =(const float*)d_in[19];
  const float* W_yout=(const float*)d_in[20];
  const float* gx    =(const float*)d_in[21];
  const float* bx    =(const float*)d_in[22];
  const float* ge    =(const float*)d_in[23];
  const float* be    =(const float*)d_in[24];
  const float* gy    =(const float*)d_in[25];
  const float* by    =(const float*)d_in[26];

  char* wsb=(char*)d_ws;
  bf16* Gbf=(bf16*)wsb;
  bf16* Bbf=(bf16*)(wsb+33554432);
  float* Npart=(float*)(wsb+33554432);   // aliases Bbf (dead after poly2); 33.5 MB exact
  float* f32=(float*)(wsb+67108864);
  float* sim  = f32+F_SIM;
  float* P    = f32+F_P;
  float* Dpart= f32+F_NP;                // 131072 floats used of 4194304
  float* S    = f32+F_S;
  float* eenc = f32+F_EENC;
  float* xplus= f32+F_XPL;
  float* qb   = f32+F_QB;
  float* kb   = f32+F_KB;
  float* vb   = f32+F_VB;
  float* yw   = f32+F_YW;
  float* xpy  = f32+F_XPY;
  float* coeff= f32+F_COEF;
  float* Genc = f32+F_GENC;
  float* Xenc = f32+F_XENC;
  float* Gp   = f32+F_GP;
  float* Xp   = f32+F_XP;

  float* out=(float*)d_out;          // reference outputs are float32
  float* newX=out;                   // [0, 262144)
  float* newE_out=out+262144;        // [262144, 17039360) — also stages pre-Eout NEWE
  float* newy=out+17039360;          // [17039360, 17039872)

  k_coeff_yw<<<cB,256,0,stream>>>(y,Wc,bc,W_y2,coeff,yw);
  k_reduceE<<<cB*cN,dim3(64,4),0,stream>>>(E,nm,S);
  k_eenc<<<cB*cN,256,0,stream>>>(S,W_emax,nm,eenc);
  k_xplus<<<cB*cN,256,0,stream>>>(X,eenc,W_x1,nm,xplus);
  k_qkv<<<cB*cN,256,0,stream>>>(xplus,Wq,Wk,Wv,qb,kb,vb);
  k_attn_softmax<<<cB*cNH*cN,256,0,stream>>>(qb,kb,nm,P);
  k_attn_out<<<cB*cN,256,0,stream>>>(P,vb,Wo,X,nm,gx,bx,newX);
  k_xplusy<<<cB*cN,256,0,stream>>>(X,yw,W_x2,xpy);
  k_sim<<<dim3(16,16,cB),dim3(16,16),0,stream>>>(xpy,sim);
  k_G<<<cB*cN,256,0,stream>>>(E,sim,nm,salpha,Gbf);
  // Bbf = c0*(G@G) + c1*G ; NEWE = G@Bbf + c2*G  (staged f32 in d_out new_E slot)
  k_bmm_poly<bf16><<<dim3(4,4,cB*cDE),dim3(16,16),0,stream>>>(Gbf,Gbf,Bbf,coeff,0,1);
  k_bmm_poly<float><<<dim3(4,4,cB*cDE),dim3(16,16),0,stream>>>(Gbf,Bbf,newE_out,coeff,-1,2);
  k_Eout<<<65536,256,0,stream>>>(newE_out,E,nm,W_Eout,ge,be,newE_out);
  k_Gaccum<<<dim3(256,cB),256,0,stream>>>(E,nm,G_kern,Npart,Dpart);
  k_Gcombine<<<cB*128,64,0,stream>>>(Npart,Dpart,Genc);
  k_Xenc<<<dim3(64,cB),256,0,stream>>>(X,nm,X_kern,Xenc);
  k_headA<<<dim3(cB,32),128,0,stream>>>(Genc,Xenc,W_Gtr,W_Xtr,Gp,Xp);
  k_headB<<<cB,128,0,stream>>>(Gp,Xp,W_yout,y,gy,by,newy);
}

// Round 5
// 833.088 us; speedup vs baseline: 2.0014x; 1.2100x over previous
//
#include <hip/hip_runtime.h>
#include <hip/hip_bf16.h>

typedef __hip_bfloat16 bf16;
__device__ __forceinline__ bf16 tobf(float v){ return __float2bfloat16(v); }
__device__ __forceinline__ float frombf(bf16 v){ return __bfloat162float(v); }

static constexpr int cB=4, cN=256, cDX=256, cDE=64, cDY=128, cNH=8, cDF=32;

// ---- workspace layout (bytes) ----
// [0, 33554432)           Gbf   (bf16, 16.7M elems)
// [33554432, 67108864)    Bbf   (bf16, 16.7M elems)  -- after poly2: Npart f32 (8388608 floats, exact fit)
// [67108864, ...)         f32 region, offsets below in floats:
static constexpr size_t F_SIM  = 0;        // 262144
static constexpr size_t F_P    = 262144;   // 2097152
static constexpr size_t F_NP   = 2359296;  // 4194304 region: Dpart [0,131072), Gp/Xp at +1048576
static constexpr size_t F_GP   = F_NP + 1048576;          // 32768 floats (4*64*128)
static constexpr size_t F_XP   = F_NP + 1048576 + 32768;  // 65536 floats (4*128*128)
static constexpr size_t F_S    = 6619136;  // 65536
static constexpr size_t F_EENC = 6684672;  // 262144
static constexpr size_t F_XPL  = 6946816;  // 262144
static constexpr size_t F_QB   = 7208960;  // 262144
static constexpr size_t F_KB   = 7471104;  // 262144
static constexpr size_t F_VB   = 7733248;  // 262144
static constexpr size_t F_YW   = 7995392;  // 1024
static constexpr size_t F_XPY  = 7996416;  // 262144
static constexpr size_t F_COEF = 8258560;  // 16
static constexpr size_t F_GENC = 8258576;  // 32768
static constexpr size_t F_XENC = 8291344;  // 65536

// ---------------- coeff = y@Wc+bc ; yw = relu(y@W_y2) ----------------
__global__ void k_coeff_yw(const float* y, const float* Wc, const float* bc,
                           const float* W_y2, float* coeff, float* yw){
  int b = blockIdx.x; int f = threadIdx.x; // 256
  float acc = 0.f;
  for(int r=0;r<cDY;++r) acc += y[b*cDY+r]*W_y2[r*cDX+f];
  yw[b*cDX+f] = fmaxf(acc,0.f);
  if (f < 3){
    float c = bc[f];
    for(int r=0;r<cDY;++r) c += y[b*cDY+r]*Wc[r*3+f];
    coeff[b*3+f] = c;
  }
}

// ---------------- S[b,i,d] = sum_j E[b,i,j,d]*m_j ----------------
__global__ void k_reduceE(const float* E, const int* nm, float* S){
  int bi = blockIdx.x; int b = bi / cN;
  int d = threadIdx.x;  // 64
  int jy = threadIdx.y; // 4
  const float* Eb = E + (size_t)bi*cN*cDE;
  float acc = 0.f;
  for(int j=jy;j<cN;j+=4){
    acc += Eb[j*cDE+d] * (float)nm[b*cN+j];
  }
  __shared__ float red[4][64];
  red[jy][d]=acc; __syncthreads();
  if (jy==0) S[(size_t)bi*cDE+d] = red[0][d]+red[1][d]+red[2][d]+red[3][d];
}

// ---------------- e_enc[b,i,f] = relu(m_i/N * S[b,i,:]@W_emax[:,f]) ----------------
__global__ void k_eenc(const float* S, const float* W_emax, const int* nm, float* eenc){
  int bi = blockIdx.x; int b = bi/cN; int i = bi%cN;
  int f = threadIdx.x;
  __shared__ float s[cDE];
  if (f<cDE) s[f]=S[(size_t)bi*cDE+f];
  __syncthreads();
  float acc=0.f;
  for(int d=0;d<cDE;++d) acc += s[d]*W_emax[d*cDX+f];
  float mi=(float)nm[b*cN+i];
  eenc[(size_t)bi*cDX+f] = fmaxf(acc*mi*(1.f/cN), 0.f);
}

// ---------------- xplus = (X + relu(eenc@W_x1)) * m_i ----------------
__global__ void k_xplus(const float* X, const float* eenc, const float* W_x1,
                        const int* nm, float* xplus){
  int bi=blockIdx.x; int b=bi/cN; int i=bi%cN;
  int f=threadIdx.x;
  __shared__ float row[cDX];
  row[f]=eenc[(size_t)bi*cDX+f];
  __syncthreads();
  float acc=0.f;
  for(int c=0;c<cDX;++c) acc += row[c]*W_x1[c*cDX+f];
  float mi=(float)nm[b*cN+i];
  xplus[(size_t)bi*cDX+f] = (X[(size_t)bi*cDX+f] + fmaxf(acc,0.f))*mi;
}

// ---------------- q,k,v projections ----------------
__global__ void k_qkv(const float* xplus, const float* Wq, const float* Wk, const float* Wv,
                      float* qb, float* kb, float* vb){
  int bi=blockIdx.x; int f=threadIdx.x;
  __shared__ float row[cDX];
  row[f]=xplus[(size_t)bi*cDX+f];
  __syncthreads();
  float aq=0,ak=0,av=0;
  for(int c=0;c<cDX;++c){ float r=row[c]; aq+=r*Wq[c*cDX+f]; ak+=r*Wk[c*cDX+f]; av+=r*Wv[c*cDX+f]; }
  qb[(size_t)bi*cDX+f]=aq; kb[(size_t)bi*cDX+f]=ak; vb[(size_t)bi*cDX+f]=av;
}

// ---------------- attention softmax rows -> P[b,h,i,j] ----------------
__global__ void k_attn_softmax(const float* qb, const float* kb, const int* nm, float* P){
  int id=blockIdx.x; int b=id/(cNH*cN); int rem=id%(cNH*cN); int h=rem/cN; int i=rem%cN;
  int j=threadIdx.x;
  __shared__ float qrow[cDF];
  if (j<cDF) qrow[j]=qb[((size_t)b*cN+i)*cDX + h*cDF + j];
  __syncthreads();
  const float* krow = kb + ((size_t)b*cN+j)*cDX + h*cDF;
  float s=0.f;
  for(int c=0;c<cDF;++c) s += qrow[c]*krow[c];
  s *= 0.17677669529663687f; // 1/sqrt(32)
  float val = (nm[b*cN+j]>0) ? s : -1e9f;
  __shared__ float red[256];
  red[j]=val; __syncthreads();
  for(int st=128;st>0;st>>=1){ if(j<st) red[j]=fmaxf(red[j],red[j+st]); __syncthreads(); }
  float mx=red[0]; __syncthreads();
  float e=__expf(val-mx);
  red[j]=e; __syncthreads();
  for(int st=128;st>0;st>>=1){ if(j<st) red[j]+=red[j+st]; __syncthreads(); }
  float denom=red[0];
  P[(size_t)id*cN + j] = e/denom;
}

// ---------------- P@V, @Wo, *mask, +X, LayerNorm -> new_X (f32) ----------------
__global__ void k_attn_out(const float* P, const float* vb, const float* Wo,
                           const float* X, const int* nm, const float* gx, const float* bx,
                           float* newX){
  int bi=blockIdx.x; int b=bi/cN; int i=bi%cN;
  int t=threadIdx.x;
  __shared__ float p8[cNH][cN];
  for(int h=0;h<cNH;++h) p8[h][t]=P[(((size_t)b*cNH+h)*cN+i)*cN + t];
  __syncthreads();
  int h=t/cDF;
  float acc=0.f;
  for(int j=0;j<cN;++j) acc += p8[h][j]*vb[((size_t)b*cN+j)*cDX + t];
  __shared__ float arow[cDX];
  arow[t]=acc; __syncthreads();
  float o=0.f;
  for(int c=0;c<cDX;++c) o += arow[c]*Wo[c*cDX+t];
  float mi=(float)nm[b*cN+i];
  float v = o*mi + X[(size_t)bi*cDX+t];
  __shared__ float red[256];
  red[t]=v; __syncthreads();
  for(int st=128;st>0;st>>=1){ if(t<st) red[t]+=red[t+st]; __syncthreads(); }
  float mean=red[0]*(1.f/cDX); __syncthreads();
  float dv=v-mean;
  red[t]=dv*dv; __syncthreads();
  for(int st=128;st>0;st>>=1){ if(t<st) red[t]+=red[t+st]; __syncthreads(); }
  float var=red[0]*(1.f/cDX);
  newX[(size_t)bi*cDX+t]=dv*rsqrtf(var+1e-6f)*gx[t]+bx[t];
}

// ---------------- xplusy = relu((X + yw)@W_x2) ----------------
__global__ void k_xplusy(const float* X, const float* yw, const float* W_x2, float* xpy){
  int bi=blockIdx.x; int b=bi/cN;
  int f=threadIdx.x;
  __shared__ float row[cDX];
  row[f]=X[(size_t)bi*cDX+f]+yw[b*cDX+f];
  __syncthreads();
  float acc=0.f;
  for(int c=0;c<cDX;++c) acc += row[c]*W_x2[c*cDX+f];
  xpy[(size_t)bi*cDX+f]=fmaxf(acc,0.f);
}

// ---------------- sim = xpy @ xpy^T / 16 ----------------
__global__ void k_sim(const float* xp, float* sim){
  int b=blockIdx.z;
  int tx=threadIdx.x, ty=threadIdx.y;
  __shared__ float Aa[16][17], Bb[16][17];
  const float* base = xp + (size_t)b*cN*cDX;
  float acc=0.f;
  for(int kt=0;kt<cDX;kt+=16){
    Aa[ty][tx]=base[(size_t)(blockIdx.y*16+ty)*cDX + kt+tx];
    Bb[ty][tx]=base[(size_t)(blockIdx.x*16+ty)*cDX + kt+tx];
    __syncthreads();
    for(int c=0;c<16;++c) acc += Aa[ty][c]*Bb[tx][c];
    __syncthreads();
  }
  sim[((size_t)b*cN + blockIdx.y*16+ty)*cN + blockIdx.x*16+tx] = acc*(1.f/16.f);
}

// ---------------- G = (alpha*sim + E) * emask  (bf16 out) ----------------
__global__ void k_G(const float* E, const float* sim, const int* nm, const float* alpha_p,
                    bf16* G){
  int bi=blockIdx.x; int b=bi/cN; int i=bi%cN;
  float mi=(float)nm[b*cN+i];
  float alpha=alpha_p[0];
  size_t base=(size_t)bi*cN*cDE;
  for(int t=threadIdx.x;t<cN*cDE;t+=blockDim.x){
    int j=t>>6;
    float mj=(float)nm[b*cN+j];
    G[base+t]=tobf((alpha*sim[(size_t)bi*cN+j]+E[base+t])*mi*mj);
  }
}

__device__ __forceinline__ void store_out(bf16* p, float v){ *p = tobf(v); }
__device__ __forceinline__ void store_out(float* p, float v){ *p = v; }

// ---------------- batched 256x256 GEMM (bf16 in, f32 accum):
//                  C = alpha*(A@B) + beta*A ----------------
template<typename OT>
__global__ void k_bmm_poly(const bf16* A, const bf16* Bm, OT* C, const float* coeff,
                           int ia, int ib){
  int bc=blockIdx.z; int b=bc>>6;
  float alpha=(ia>=0)?coeff[b*3+ia]:1.0f;
  float beta=coeff[b*3+ib];
  const bf16* Ab=A+(size_t)bc*cN*cN;
  const bf16* Bb=Bm+(size_t)bc*cN*cN;
  OT* Cb=C+(size_t)bc*cN*cN;
  int tx=threadIdx.x, ty=threadIdx.y;
  int tid=ty*16+tx;
  __shared__ float As[16][65]; // [k][row]
  __shared__ float Bs[16][65]; // [k][col]
  float acc[4][4]={};
  for(int kt=0;kt<cN;kt+=16){
#pragma unroll
    for(int l=0;l<4;++l){
      int idx=tid+l*256;
      int rr=idx>>4, cc=idx&15;
      As[cc][rr]=frombf(Ab[(size_t)(blockIdx.y*64+rr)*cN + kt+cc]);
    }
#pragma unroll
    for(int l=0;l<4;++l){
      int idx=tid+l*256;
      int rr=idx>>6, cc=idx&63;
      Bs[rr][cc]=frombf(Bb[(size_t)(kt+rr)*cN + blockIdx.x*64+cc]);
    }
    __syncthreads();
#pragma unroll
    for(int kk=0;kk<16;++kk){
      float a0=As[kk][ty*4+0],a1=As[kk][ty*4+1],a2=As[kk][ty*4+2],a3=As[kk][ty*4+3];
      float b0=Bs[kk][tx*4+0],b1=Bs[kk][tx*4+1],b2=Bs[kk][tx*4+2],b3=Bs[kk][tx*4+3];
      acc[0][0]+=a0*b0; acc[0][1]+=a0*b1; acc[0][2]+=a0*b2; acc[0][3]+=a0*b3;
      acc[1][0]+=a1*b0; acc[1][1]+=a1*b1; acc[1][2]+=a1*b2; acc[1][3]+=a1*b3;
      acc[2][0]+=a2*b0; acc[2][1]+=a2*b1; acc[2][2]+=a2*b2; acc[2][3]+=a2*b3;
      acc[3][0]+=a3*b0; acc[3][1]+=a3*b1; acc[3][2]+=a3*b2; acc[3][3]+=a3*b3;
    }
    __syncthreads();
  }
  int r0=blockIdx.y*64+ty*4, c0=blockIdx.x*64+tx*4;
#pragma unroll
  for(int i=0;i<4;++i){
#pragma unroll
    for(int j=0;j<4;++j){
      size_t off=(size_t)(r0+i)*cN + (c0+j);
      store_out(&Cb[off], alpha*acc[i][j]+beta*frombf(Ab[off]));
    }
  }
}

// ---------------- newE(f32, staged in-place) -> relu(@W_Eout)*emask + E -> LN -> new_E (f32) ----------------
__global__ void k_Eout(const float* newE_in, const float* E, const int* nm,
                       const float* W_Eout, const float* ge, const float* be, float* outE){
  int wav=threadIdx.x>>6; int lane=threadIdx.x&63;
  size_t row=(size_t)blockIdx.x*4+wav;
  int b=(int)(row>>16); int ij=(int)(row&65535); int i=ij>>8; int j=ij&255;
  float mij=(float)(nm[b*cN+i]*nm[b*cN+j]);
  __shared__ float lds[4][cDE];
  size_t off=row*cDE;
  lds[wav][lane]=newE_in[off+lane];
  __syncthreads();
  float acc=0.f;
  for(int d=0;d<cDE;++d) acc += lds[wav][d]*W_Eout[d*cDE+lane];
  float v=fmaxf(acc,0.f)*mij + E[off+lane];
  float s=v;
  for(int m=32;m>0;m>>=1) s += __shfl_xor(s,m,64);
  float mean=s*(1.f/cDE);
  float dv=v-mean; float q=dv*dv;
  for(int m=32;m>0;m>>=1) q += __shfl_xor(q,m,64);
  float var=q*(1.f/cDE);
  outE[off+lane]=dv*rsqrtf(var+1e-6f)*ge[lane]+be[lane];
}

// ---------------- fused aG-softmax partials (no spills) ----------------
__global__ void __launch_bounds__(256) k_Gaccum(const float* E, const int* nm,
                                                const float* G_kernel,
                                                float* Npart, float* Dpart){
  int chunk=blockIdx.x; // 256 chunks of 256 p-rows
  int b=blockIdx.y;     // 4
  int t=threadIdx.x;    // 256
  int dq=t&3;
  int kk=t>>2;          // 0..63
  float gk0[16], gk1[16];
#pragma unroll
  for(int d=0;d<16;++d){
    gk0[d]=G_kernel[(dq*16+d)*128 + kk];
    gk1[d]=G_kernel[(dq*16+d)*128 + kk+64];
  }
  float acc0[16], acc1[16];
#pragma unroll
  for(int d=0;d<16;++d){ acc0[d]=0.f; acc1[d]=0.f; }
  float den0=0.f, den1=0.f;
  __shared__ float em[8][cDE];
  __shared__ float mrow[8];
  const size_t ebase=((size_t)b)<<16;
  int base=chunk*256;
  for(int s=0;s<32;++s){
    int p0=base+8*s;
    __syncthreads();
#pragma unroll
    for(int l=0;l<2;++l){
      int idx=t+l*256;
      int rr=idx>>6, d=idx&63;
      int pp=p0+rr;
      float m=(float)(nm[b*cN+(pp>>8)]*nm[b*cN+(pp&255)]);
      em[rr][d]=E[(ebase+pp)*cDE+d]*m;
      if(d==0) mrow[rr]=m;
    }
    __syncthreads();
    for(int rr=0;rr<8;++rr){
      if(mrow[rr]<=0.f) continue;   // wave-uniform skip
      float r[16];
#pragma unroll
      for(int d=0;d<16;++d) r[d]=em[rr][dq*16+d];
      float pd0=0.f, pd1=0.f;
#pragma unroll
      for(int d=0;d<16;++d){ pd0+=r[d]*gk0[d]; pd1+=r[d]*gk1[d]; }
      pd0+=__shfl_xor(pd0,1); pd0+=__shfl_xor(pd0,2);
      pd1+=__shfl_xor(pd1,1); pd1+=__shfl_xor(pd1,2);
      float w0=__expf(pd0*0.125f), w1=__expf(pd1*0.125f);
      den0+=w0; den1+=w1;
#pragma unroll
      for(int d=0;d<16;++d){ acc0[d]+=w0*r[d]; acc1[d]+=w1*r[d]; }
    }
  }
  size_t pi=(size_t)b*256+chunk;
  float* np=Npart + pi*128*cDE;
#pragma unroll
  for(int d=0;d<16;++d){
    np[(size_t)kk*cDE + dq*16+d]=acc0[d];
    np[(size_t)(kk+64)*cDE + dq*16+d]=acc1[d];
  }
  if(dq==0){
    Dpart[pi*128+kk]=den0;
    Dpart[pi*128+kk+64]=den1;
  }
}

// ---------------- combine partials -> Genc[b, k*64+d] ----------------
__global__ void k_Gcombine(const float* Npart, const float* Dpart, float* Genc){
  int bk=blockIdx.x; int b=bk>>7; int k=bk&127;
  int d=threadIdx.x; // 64
  float n=0.f, dd=0.f;
  for(int pi=0;pi<256;++pi){
    size_t base=((size_t)b*256+pi)*128+k;
    n += Npart[base*cDE+d];
    dd += Dpart[base];
  }
  Genc[(size_t)b*8192 + k*cDE + d]=n/dd;
}

// ---------------- aX softmax + X_enc[b, k*256+d] ----------------
__global__ void k_Xenc(const float* X, const int* nm, const float* X_kernel, float* Xenc){
  int k=blockIdx.x;  // 64
  int b=blockIdx.y;  // 4
  int n=threadIdx.x; // 256
  float m=(float)nm[b*cN+n];
  const float* xr=X+((size_t)b*cN+n)*cDX;
  float acc=0.f;
  for(int c=0;c<cDX;++c) acc += xr[c]*X_kernel[c*64+k];
  float lg=(m>0.f)?acc*(1.f/16.f):-1e9f;
  __shared__ float red[256];
  red[n]=lg; __syncthreads();
  for(int st=128;st>0;st>>=1){ if(n<st) red[n]=fmaxf(red[n],red[n+st]); __syncthreads(); }
  float mx=red[0]; __syncthreads();
  float e=__expf(lg-mx);
  red[n]=e; __syncthreads();
  for(int st=128;st>0;st>>=1){ if(n<st) red[n]+=red[n+st]; __syncthreads(); }
  float denom=red[0]; __syncthreads();
  __shared__ float ps[256];
  ps[n]=e/denom;  // exactly 0 for masked rows
  __syncthreads();
  int d=n;
  float s=0.f;
  for(int nn=0;nn<cN;++nn) s += ps[nn]*X[((size_t)b*cN+nn)*cDX+d];
  Xenc[(size_t)b*16384 + k*cDX + d]=s;
}

// ---------------- head weight-streaming partials ----------------
// blocks [0,64): G-path chunk ch=blk, q in [ch*128, ch*128+128) of W_Gtrans (8192 q total)
// blocks [64,192): X-path chunk ch=blk-64, q in [ch*128, ch*128+128) of W_Xtrans (16384 q)
// thread: o = t&127 output column; sub = t>>7 picks batches {0,1} or {2,3}.
__global__ void __launch_bounds__(256) k_headA(const float* Genc, const float* Xenc,
                        const float* W_Gtrans, const float* W_Xtrans,
                        float* Gp, float* Xp){
  int blk=blockIdx.x;
  int t=threadIdx.x;
  int o=t&127, sub=t>>7;
  int b0=sub*2, b1=sub*2+1;
  __shared__ float ash[4][128];
  if(blk<64){
    int ch=blk;
    for(int l=t;l<512;l+=256){
      int b=l>>7, q=l&127;
      ash[b][q]=Genc[(size_t)b*8192 + ch*128 + q];
    }
    __syncthreads();
    const float* wbase=W_Gtrans + (size_t)ch*128*cDY + o;
    float a0=0.f, a1=0.f;
#pragma unroll 4
    for(int qq=0;qq<128;++qq){
      float w=wbase[(size_t)qq*cDY];
      a0+=ash[b0][qq]*w; a1+=ash[b1][qq]*w;
    }
    Gp[((size_t)b0*64+ch)*cDY+o]=a0;
    Gp[((size_t)b1*64+ch)*cDY+o]=a1;
  } else {
    int ch=blk-64;
    for(int l=t;l<512;l+=256){
      int b=l>>7, q=l&127;
      ash[b][q]=Xenc[(size_t)b*16384 + ch*128 + q];
    }
    __syncthreads();
    const float* wbase=W_Xtrans + (size_t)ch*128*cDY + o;
    float a0=0.f, a1=0.f;
#pragma unroll 4
    for(int qq=0;qq<128;++qq){
      float w=wbase[(size_t)qq*cDY];
      a0+=ash[b0][qq]*w; a1+=ash[b1][qq]*w;
    }
    Xp[((size_t)b0*128+ch)*cDY+o]=a0;
    Xp[((size_t)b1*128+ch)*cDY+o]=a1;
  }
}

// ---------------- head final -> new_y (f32) ----------------
__global__ void k_headB(const float* Gp, const float* Xp, const float* W_yout,
                        const float* y, const float* gy, const float* by, float* newy){
  int b=blockIdx.x; int o=threadIdx.x; // 128
  float g=0.f,x=0.f;
  for(int ch=0;ch<64;++ch)  g+=Gp[((size_t)b*64+ch)*cDY+o];
  for(int ch=0;ch<128;++ch) x+=Xp[((size_t)b*128+ch)*cDY+o];
  __shared__ float srow[cDY];
  srow[o]=fmaxf(g,0.f)+fmaxf(x,0.f);
  __syncthreads();
  float h=0.f;
  for(int r=0;r<cDY;++r) h += srow[r]*W_yout[r*cDY+o];
  float v=fmaxf(h,0.f)+y[b*cDY+o];
  __shared__ float red[cDY];
  red[o]=v; __syncthreads();
  for(int st=64;st>0;st>>=1){ if(o<st) red[o]+=red[o+st]; __syncthreads(); }
  float mean=red[0]*(1.f/cDY); __syncthreads();
  float dv=v-mean;
  red[o]=dv*dv; __syncthreads();
  for(int st=64;st>0;st>>=1){ if(o<st) red[o]+=red[o+st]; __syncthreads(); }
  float var=red[0]*(1.f/cDY);
  newy[b*cDY+o]=dv*rsqrtf(var+1e-6f)*gy[o]+by[o];
}

extern "C" void kernel_launch(void* const* d_in, const int* in_sizes, int n_in,
                              void* d_out, int out_size, void* d_ws, size_t ws_size,
                              hipStream_t stream){
  const float* X     =(const float*)d_in[0];
  const float* E     =(const float*)d_in[1];
  const float* y     =(const float*)d_in[2];
  const int*   nm    =(const int*)  d_in[3];
  const float* W_emax=(const float*)d_in[4];
  const float* W_x1  =(const float*)d_in[5];
  const float* Wq    =(const float*)d_in[6];
  const float* Wk    =(const float*)d_in[7];
  const float* Wv    =(const float*)d_in[8];
  const float* Wo    =(const float*)d_in[9];
  const float* W_y2  =(const float*)d_in[10];
  const float* W_x2  =(const float*)d_in[11];
  const float* Wc    =(const float*)d_in[12];
  const float* bc    =(const float*)d_in[13];
  const float* salpha=(const float*)d_in[14];
  const float* W_Eout=(const float*)d_in[15];
  const float* G_kern=(const float*)d_in[16];
  const float* X_kern=(const float*)d_in[17];
  const float* W_Gtr =(const float*)d_in[18];
  const float* W_Xtr =(const float*)d_in[19];
  const float* W_yout=(const float*)d_in[20];
  const float* gx    =(const float*)d_in[21];
  const float* bx    =(const float*)d_in[22];
  const float* ge    =(const float*)d_in[23];
  const float* be    =(const float*)d_in[24];
  const float* gy    =(const float*)d_in[25];
  const float* by    =(const float*)d_in[26];

  char* wsb=(char*)d_ws;
  bf16* Gbf=(bf16*)wsb;
  bf16* Bbf=(bf16*)(wsb+33554432);
  float* Npart=(float*)(wsb+33554432);   // aliases Bbf (dead after poly2); 33.5 MB exact
  float* f32=(float*)(wsb+67108864);
  float* sim  = f32+F_SIM;
  float* P    = f32+F_P;
  float* Dpart= f32+F_NP;                // 131072 floats used
  float* Gp   = f32+F_GP;                // 32768 floats
  float* Xp   = f32+F_XP;                // 65536 floats
  float* S    = f32+F_S;
  float* eenc = f32+F_EENC;
  float* xplus= f32+F_XPL;
  float* qb   = f32+F_QB;
  float* kb   = f32+F_KB;
  float* vb   = f32+F_VB;
  float* yw   = f32+F_YW;
  float* xpy  = f32+F_XPY;
  float* coeff= f32+F_COEF;
  float* Genc = f32+F_GENC;
  float* Xenc = f32+F_XENC;

  float* out=(float*)d_out;          // reference outputs are float32
  float* newX=out;                   // [0, 262144)
  float* newE_out=out+262144;        // [262144, 17039360) — also stages pre-Eout NEWE
  float* newy=out+17039360;          // [17039360, 17039872)

  k_coeff_yw<<<cB,256,0,stream>>>(y,Wc,bc,W_y2,coeff,yw);
  k_reduceE<<<cB*cN,dim3(64,4),0,stream>>>(E,nm,S);
  k_eenc<<<cB*cN,256,0,stream>>>(S,W_emax,nm,eenc);
  k_xplus<<<cB*cN,256,0,stream>>>(X,eenc,W_x1,nm,xplus);
  k_qkv<<<cB*cN,256,0,stream>>>(xplus,Wq,Wk,Wv,qb,kb,vb);
  k_attn_softmax<<<cB*cNH*cN,256,0,stream>>>(qb,kb,nm,P);
  k_attn_out<<<cB*cN,256,0,stream>>>(P,vb,Wo,X,nm,gx,bx,newX);
  k_xplusy<<<cB*cN,256,0,stream>>>(X,yw,W_x2,xpy);
  k_sim<<<dim3(16,16,cB),dim3(16,16),0,stream>>>(xpy,sim);
  k_G<<<cB*cN,256,0,stream>>>(E,sim,nm,salpha,Gbf);
  // Bbf = c0*(G@G) + c1*G ; NEWE = G@Bbf + c2*G  (staged f32 in d_out new_E slot)
  k_bmm_poly<bf16><<<dim3(4,4,cB*cDE),dim3(16,16),0,stream>>>(Gbf,Gbf,Bbf,coeff,0,1);
  k_bmm_poly<float><<<dim3(4,4,cB*cDE),dim3(16,16),0,stream>>>(Gbf,Bbf,newE_out,coeff,-1,2);
  k_Eout<<<65536,256,0,stream>>>(newE_out,E,nm,W_Eout,ge,be,newE_out);
  k_Gaccum<<<dim3(256,cB),256,0,stream>>>(E,nm,G_kern,Npart,Dpart);
  k_Gcombine<<<cB*128,64,0,stream>>>(Npart,Dpart,Genc);
  k_Xenc<<<dim3(64,cB),256,0,stream>>>(X,nm,X_kern,Xenc);
  k_headA<<<192,256,0,stream>>>(Genc,Xenc,W_Gtr,W_Xtr,Gp,Xp);
  k_headB<<<cB,128,0,stream>>>(Gp,Xp,W_yout,y,gy,by,newy);
}

// Round 6
// 624.133 us; speedup vs baseline: 2.6715x; 1.3348x over previous
//
#include <hip/hip_runtime.h>
#include <hip/hip_bf16.h>

typedef __hip_bfloat16 bf16;
__device__ __forceinline__ bf16 tobf(float v){ return __float2bfloat16(v); }
__device__ __forceinline__ float frombf(bf16 v){ return __bfloat162float(v); }

typedef __attribute__((ext_vector_type(8))) short bf16x8;
typedef __attribute__((ext_vector_type(4))) float f32x4;
typedef __attribute__((ext_vector_type(4))) int int4v;

static constexpr int cB=4, cN=256, cDX=256, cDE=64, cDY=128, cNH=8, cDF=32;

// ---- workspace layout (bytes) ----
// [0, 33554432)           Gbf   (bf16, 16.7M elems)
// [33554432, 67108864)    Bbf   (bf16, 16.7M elems)  -- after poly2: Npart f32 (8388608 floats, exact fit)
// [67108864, ...)         f32 region, offsets below in floats:
static constexpr size_t F_SIM  = 0;        // 262144
static constexpr size_t F_P    = 262144;   // 2097152
static constexpr size_t F_NP   = 2359296;  // region: Dpart [0,131072), Gp/Xp at +1048576
static constexpr size_t F_GP   = F_NP + 1048576;          // 32768 floats
static constexpr size_t F_XP   = F_NP + 1048576 + 32768;  // 65536 floats
static constexpr size_t F_S    = 6619136;  // 65536
static constexpr size_t F_EENC = 6684672;  // 262144
static constexpr size_t F_XPL  = 6946816;  // 262144
static constexpr size_t F_QB   = 7208960;  // 262144
static constexpr size_t F_KB   = 7471104;  // 262144
static constexpr size_t F_VB   = 7733248;  // 262144
static constexpr size_t F_YW   = 7995392;  // 1024
static constexpr size_t F_XPY  = 7996416;  // 262144
static constexpr size_t F_COEF = 8258560;  // 16
static constexpr size_t F_GENC = 8258576;  // 32768
static constexpr size_t F_XENC = 8291344;  // 65536

// ---------------- coeff = y@Wc+bc ; yw = relu(y@W_y2) ----------------
__global__ void k_coeff_yw(const float* y, const float* Wc, const float* bc,
                           const float* W_y2, float* coeff, float* yw){
  int b = blockIdx.x; int f = threadIdx.x; // 256
  float acc = 0.f;
  for(int r=0;r<cDY;++r) acc += y[b*cDY+r]*W_y2[r*cDX+f];
  yw[b*cDX+f] = fmaxf(acc,0.f);
  if (f < 3){
    float c = bc[f];
    for(int r=0;r<cDY;++r) c += y[b*cDY+r]*Wc[r*3+f];
    coeff[b*3+f] = c;
  }
}

// ---------------- S[b,i,d] = sum_j E[b,i,j,d]*m_j ----------------
__global__ void k_reduceE(const float* E, const int* nm, float* S){
  int bi = blockIdx.x; int b = bi / cN;
  int d = threadIdx.x;  // 64
  int jy = threadIdx.y; // 4
  const float* Eb = E + (size_t)bi*cN*cDE;
  float acc = 0.f;
  for(int j=jy;j<cN;j+=4){
    acc += Eb[j*cDE+d] * (float)nm[b*cN+j];
  }
  __shared__ float red[4][64];
  red[jy][d]=acc; __syncthreads();
  if (jy==0) S[(size_t)bi*cDE+d] = red[0][d]+red[1][d]+red[2][d]+red[3][d];
}

// ---------------- e_enc[b,i,f] = relu(m_i/N * S[b,i,:]@W_emax[:,f]) ----------------
__global__ void k_eenc(const float* S, const float* W_emax, const int* nm, float* eenc){
  int bi = blockIdx.x; int b = bi/cN; int i = bi%cN;
  int f = threadIdx.x;
  __shared__ float s[cDE];
  if (f<cDE) s[f]=S[(size_t)bi*cDE+f];
  __syncthreads();
  float acc=0.f;
  for(int d=0;d<cDE;++d) acc += s[d]*W_emax[d*cDX+f];
  float mi=(float)nm[b*cN+i];
  eenc[(size_t)bi*cDX+f] = fmaxf(acc*mi*(1.f/cN), 0.f);
}

// ---------------- xplus = (X + relu(eenc@W_x1)) * m_i ----------------
__global__ void k_xplus(const float* X, const float* eenc, const float* W_x1,
                        const int* nm, float* xplus){
  int bi=blockIdx.x; int b=bi/cN; int i=bi%cN;
  int f=threadIdx.x;
  __shared__ float row[cDX];
  row[f]=eenc[(size_t)bi*cDX+f];
  __syncthreads();
  float acc=0.f;
  for(int c=0;c<cDX;++c) acc += row[c]*W_x1[c*cDX+f];
  float mi=(float)nm[b*cN+i];
  xplus[(size_t)bi*cDX+f] = (X[(size_t)bi*cDX+f] + fmaxf(acc,0.f))*mi;
}

// ---------------- q,k,v projections ----------------
__global__ void k_qkv(const float* xplus, const float* Wq, const float* Wk, const float* Wv,
                      float* qb, float* kb, float* vb){
  int bi=blockIdx.x; int f=threadIdx.x;
  __shared__ float row[cDX];
  row[f]=xplus[(size_t)bi*cDX+f];
  __syncthreads();
  float aq=0,ak=0,av=0;
  for(int c=0;c<cDX;++c){ float r=row[c]; aq+=r*Wq[c*cDX+f]; ak+=r*Wk[c*cDX+f]; av+=r*Wv[c*cDX+f]; }
  qb[(size_t)bi*cDX+f]=aq; kb[(size_t)bi*cDX+f]=ak; vb[(size_t)bi*cDX+f]=av;
}

// ---------------- attention softmax rows -> P[b,h,i,j] ----------------
__global__ void k_attn_softmax(const float* qb, const float* kb, const int* nm, float* P){
  int id=blockIdx.x; int b=id/(cNH*cN); int rem=id%(cNH*cN); int h=rem/cN; int i=rem%cN;
  int j=threadIdx.x;
  __shared__ float qrow[cDF];
  if (j<cDF) qrow[j]=qb[((size_t)b*cN+i)*cDX + h*cDF + j];
  __syncthreads();
  const float* krow = kb + ((size_t)b*cN+j)*cDX + h*cDF;
  float s=0.f;
  for(int c=0;c<cDF;++c) s += qrow[c]*krow[c];
  s *= 0.17677669529663687f; // 1/sqrt(32)
  float val = (nm[b*cN+j]>0) ? s : -1e9f;
  __shared__ float red[256];
  red[j]=val; __syncthreads();
  for(int st=128;st>0;st>>=1){ if(j<st) red[j]=fmaxf(red[j],red[j+st]); __syncthreads(); }
  float mx=red[0]; __syncthreads();
  float e=__expf(val-mx);
  red[j]=e; __syncthreads();
  for(int st=128;st>0;st>>=1){ if(j<st) red[j]+=red[j+st]; __syncthreads(); }
  float denom=red[0];
  P[(size_t)id*cN + j] = e/denom;
}

// ---------------- P@V, @Wo, *mask, +X, LayerNorm -> new_X (f32) ----------------
__global__ void k_attn_out(const float* P, const float* vb, const float* Wo,
                           const float* X, const int* nm, const float* gx, const float* bx,
                           float* newX){
  int bi=blockIdx.x; int b=bi/cN; int i=bi%cN;
  int t=threadIdx.x;
  __shared__ float p8[cNH][cN];
  for(int h=0;h<cNH;++h) p8[h][t]=P[(((size_t)b*cNH+h)*cN+i)*cN + t];
  __syncthreads();
  int h=t/cDF;
  float acc=0.f;
  for(int j=0;j<cN;++j) acc += p8[h][j]*vb[((size_t)b*cN+j)*cDX + t];
  __shared__ float arow[cDX];
  arow[t]=acc; __syncthreads();
  float o=0.f;
  for(int c=0;c<cDX;++c) o += arow[c]*Wo[c*cDX+t];
  float mi=(float)nm[b*cN+i];
  float v = o*mi + X[(size_t)bi*cDX+t];
  __shared__ float red[256];
  red[t]=v; __syncthreads();
  for(int st=128;st>0;st>>=1){ if(t<st) red[t]+=red[t+st]; __syncthreads(); }
  float mean=red[0]*(1.f/cDX); __syncthreads();
  float dv=v-mean;
  red[t]=dv*dv; __syncthreads();
  for(int st=128;st>0;st>>=1){ if(t<st) red[t]+=red[t+st]; __syncthreads(); }
  float var=red[0]*(1.f/cDX);
  newX[(size_t)bi*cDX+t]=dv*rsqrtf(var+1e-6f)*gx[t]+bx[t];
}

// ---------------- xplusy = relu((X + yw)@W_x2) ----------------
__global__ void k_xplusy(const float* X, const float* yw, const float* W_x2, float* xpy){
  int bi=blockIdx.x; int b=bi/cN;
  int f=threadIdx.x;
  __shared__ float row[cDX];
  row[f]=X[(size_t)bi*cDX+f]+yw[b*cDX+f];
  __syncthreads();
  float acc=0.f;
  for(int c=0;c<cDX;++c) acc += row[c]*W_x2[c*cDX+f];
  xpy[(size_t)bi*cDX+f]=fmaxf(acc,0.f);
}

// ---------------- sim = xpy @ xpy^T / 16 ----------------
__global__ void k_sim(const float* xp, float* sim){
  int b=blockIdx.z;
  int tx=threadIdx.x, ty=threadIdx.y;
  __shared__ float Aa[16][17], Bb[16][17];
  const float* base = xp + (size_t)b*cN*cDX;
  float acc=0.f;
  for(int kt=0;kt<cDX;kt+=16){
    Aa[ty][tx]=base[(size_t)(blockIdx.y*16+ty)*cDX + kt+tx];
    Bb[ty][tx]=base[(size_t)(blockIdx.x*16+ty)*cDX + kt+tx];
    __syncthreads();
    for(int c=0;c<16;++c) acc += Aa[ty][c]*Bb[tx][c];
    __syncthreads();
  }
  sim[((size_t)b*cN + blockIdx.y*16+ty)*cN + blockIdx.x*16+tx] = acc*(1.f/16.f);
}

// ---------------- G = (alpha*sim + E) * emask  (bf16 out) ----------------
__global__ void k_G(const float* E, const float* sim, const int* nm, const float* alpha_p,
                    bf16* G){
  int bi=blockIdx.x; int b=bi/cN; int i=bi%cN;
  float mi=(float)nm[b*cN+i];
  float alpha=alpha_p[0];
  size_t base=(size_t)bi*cN*cDE;
  for(int t=threadIdx.x;t<cN*cDE;t+=blockDim.x){
    int j=t>>6;
    float mj=(float)nm[b*cN+j];
    G[base+t]=tobf((alpha*sim[(size_t)bi*cN+j]+E[base+t])*mi*mj);
  }
}

__device__ __forceinline__ void store_out(bf16* p, float v){ *p = tobf(v); }
__device__ __forceinline__ void store_out(float* p, float v){ *p = v; }

// ---------------- batched 256x256 MFMA GEMM (bf16 in, f32 accum):
//                  C = alpha*(A@B) + beta*A ----------------
// grid (2,2,256): 128x128 tile per block; 4 waves, each 64x64 (4x4 frags 16x16).
// LDS: A_s[row][k], B_s[col][k] (transposed), pad +8 shorts (rows 144B: 16B-aligned,
// frag-read rows 4 banks apart -> 2-way = free).
template<typename OT>
__global__ void __launch_bounds__(256) k_bmm_mfma(const bf16* A, const bf16* Bm, OT* C,
                                                  const float* coeff, int ia, int ib){
  int bc=blockIdx.z; int b=bc>>6;
  float alpha=(ia>=0)?coeff[b*3+ia]:1.0f;
  float beta=coeff[b*3+ib];
  const short* Ab=(const short*)(A+(size_t)bc*65536);
  const short* Bb=(const short*)(Bm+(size_t)bc*65536);
  OT* Cb=C+(size_t)bc*65536;
  const int row0=blockIdx.y*128, col0=blockIdx.x*128;
  const int t=threadIdx.x;
  const int lane=t&63, w=t>>6;
  const int wr=w>>1, wc=w&1;
  const int l15=lane&15, l4=lane>>4;
  __shared__ short A_s[128][72];
  __shared__ short B_s[128][72];   // B transposed: [n][k]
  f32x4 acc[4][4];
#pragma unroll
  for(int m=0;m<4;++m)
#pragma unroll
    for(int n=0;n<4;++n) acc[m][n]=(f32x4){0.f,0.f,0.f,0.f};

  const int kh=t>>7;          // 0..1 (wave-uniform)
  const int nB=t&127;
  for(int kt=0;kt<256;kt+=64){
    // stage A: [128 rows][64 k] via 16B vector loads
#pragma unroll
    for(int l=0;l<4;++l){
      int idx=t+l*256;
      int r=idx>>3, seg=idx&7;
      *(int4v*)&A_s[r][seg*8] = *(const int4v*)&Ab[(size_t)(row0+r)*256 + kt + seg*8];
    }
    // stage B transposed: B_s[n][k] = B[kt+k][col0+n]
#pragma unroll 8
    for(int kk=0;kk<32;++kk){
      int k=kh*32+kk;
      B_s[nB][k]=Bb[(size_t)(kt+k)*256 + col0 + nB];
    }
    __syncthreads();
#pragma unroll
    for(int ks=0;ks<64;ks+=32){
      bf16x8 am[4], bn[4];
#pragma unroll
      for(int m=0;m<4;++m) am[m]=*(const bf16x8*)&A_s[wr*64+m*16+l15][ks+l4*8];
#pragma unroll
      for(int n=0;n<4;++n) bn[n]=*(const bf16x8*)&B_s[wc*64+n*16+l15][ks+l4*8];
#pragma unroll
      for(int m=0;m<4;++m)
#pragma unroll
        for(int n=0;n<4;++n)
          acc[m][n]=__builtin_amdgcn_mfma_f32_16x16x32_bf16(am[m],bn[n],acc[m][n],0,0,0);
    }
    __syncthreads();
  }
  // epilogue: C = alpha*acc + beta*A
#pragma unroll
  for(int m=0;m<4;++m){
#pragma unroll
    for(int n=0;n<4;++n){
#pragma unroll
      for(int r=0;r<4;++r){
        int row=row0+wr*64+m*16+l4*4+r;
        int col=col0+wc*64+n*16+l15;
        size_t off=(size_t)row*256+col;
        float a0; { unsigned short u=(unsigned short)Ab[off]; unsigned int v=((unsigned int)u)<<16; a0=__int_as_float((int)v); }
        store_out(&Cb[off], alpha*acc[m][n][r]+beta*a0);
      }
    }
  }
}

// ---------------- newE(f32, staged in-place) -> relu(@W_Eout)*emask + E -> LN -> new_E (f32) ----------------
__global__ void k_Eout(const float* newE_in, const float* E, const int* nm,
                       const float* W_Eout, const float* ge, const float* be, float* outE){
  int wav=threadIdx.x>>6; int lane=threadIdx.x&63;
  size_t row=(size_t)blockIdx.x*4+wav;
  int b=(int)(row>>16); int ij=(int)(row&65535); int i=ij>>8; int j=ij&255;
  float mij=(float)(nm[b*cN+i]*nm[b*cN+j]);
  __shared__ float lds[4][cDE];
  size_t off=row*cDE;
  lds[wav][lane]=newE_in[off+lane];
  __syncthreads();
  float acc=0.f;
  for(int d=0;d<cDE;++d) acc += lds[wav][d]*W_Eout[d*cDE+lane];
  float v=fmaxf(acc,0.f)*mij + E[off+lane];
  float s=v;
  for(int m=32;m>0;m>>=1) s += __shfl_xor(s,m,64);
  float mean=s*(1.f/cDE);
  float dv=v-mean; float q=dv*dv;
  for(int m=32;m>0;m>>=1) q += __shfl_xor(q,m,64);
  float var=q*(1.f/cDE);
  outE[off+lane]=dv*rsqrtf(var+1e-6f)*ge[lane]+be[lane];
}

// ---------------- fused aG-softmax partials (no spills) ----------------
__global__ void __launch_bounds__(256) k_Gaccum(const float* E, const int* nm,
                                                const float* G_kernel,
                                                float* Npart, float* Dpart){
  int chunk=blockIdx.x; // 256 chunks of 256 p-rows
  int b=blockIdx.y;     // 4
  int t=threadIdx.x;    // 256
  int dq=t&3;
  int kk=t>>2;          // 0..63
  float gk0[16], gk1[16];
#pragma unroll
  for(int d=0;d<16;++d){
    gk0[d]=G_kernel[(dq*16+d)*128 + kk];
    gk1[d]=G_kernel[(dq*16+d)*128 + kk+64];
  }
  float acc0[16], acc1[16];
#pragma unroll
  for(int d=0;d<16;++d){ acc0[d]=0.f; acc1[d]=0.f; }
  float den0=0.f, den1=0.f;
  __shared__ float em[8][cDE];
  __shared__ float mrow[8];
  const size_t ebase=((size_t)b)<<16;
  int base=chunk*256;
  for(int s=0;s<32;++s){
    int p0=base+8*s;
    __syncthreads();
#pragma unroll
    for(int l=0;l<2;++l){
      int idx=t+l*256;
      int rr=idx>>6, d=idx&63;
      int pp=p0+rr;
      float m=(float)(nm[b*cN+(pp>>8)]*nm[b*cN+(pp&255)]);
      em[rr][d]=E[(ebase+pp)*cDE+d]*m;
      if(d==0) mrow[rr]=m;
    }
    __syncthreads();
    for(int rr=0;rr<8;++rr){
      if(mrow[rr]<=0.f) continue;   // wave-uniform skip
      float r[16];
#pragma unroll
      for(int d=0;d<16;++d) r[d]=em[rr][dq*16+d];
      float pd0=0.f, pd1=0.f;
#pragma unroll
      for(int d=0;d<16;++d){ pd0+=r[d]*gk0[d]; pd1+=r[d]*gk1[d]; }
      pd0+=__shfl_xor(pd0,1); pd0+=__shfl_xor(pd0,2);
      pd1+=__shfl_xor(pd1,1); pd1+=__shfl_xor(pd1,2);
      float w0=__expf(pd0*0.125f), w1=__expf(pd1*0.125f);
      den0+=w0; den1+=w1;
#pragma unroll
      for(int d=0;d<16;++d){ acc0[d]+=w0*r[d]; acc1[d]+=w1*r[d]; }
    }
  }
  size_t pi=(size_t)b*256+chunk;
  float* np=Npart + pi*128*cDE;
#pragma unroll
  for(int d=0;d<16;++d){
    np[(size_t)kk*cDE + dq*16+d]=acc0[d];
    np[(size_t)(kk+64)*cDE + dq*16+d]=acc1[d];
  }
  if(dq==0){
    Dpart[pi*128+kk]=den0;
    Dpart[pi*128+kk+64]=den1;
  }
}

// ---------------- combine partials -> Genc[b, k*64+d] ----------------
__global__ void k_Gcombine(const float* Npart, const float* Dpart, float* Genc){
  int bk=blockIdx.x; int b=bk>>7; int k=bk&127;
  int d=threadIdx.x; // 64
  float n=0.f, dd=0.f;
  for(int pi=0;pi<256;++pi){
    size_t base=((size_t)b*256+pi)*128+k;
    n += Npart[base*cDE+d];
    dd += Dpart[base];
  }
  Genc[(size_t)b*8192 + k*cDE + d]=n/dd;
}

// ---------------- aX softmax + X_enc[b, k*256+d] ----------------
__global__ void k_Xenc(const float* X, const int* nm, const float* X_kernel, float* Xenc){
  int k=blockIdx.x;  // 64
  int b=blockIdx.y;  // 4
  int n=threadIdx.x; // 256
  float m=(float)nm[b*cN+n];
  const float* xr=X+((size_t)b*cN+n)*cDX;
  float acc=0.f;
  for(int c=0;c<cDX;++c) acc += xr[c]*X_kernel[c*64+k];
  float lg=(m>0.f)?acc*(1.f/16.f):-1e9f;
  __shared__ float red[256];
  red[n]=lg; __syncthreads();
  for(int st=128;st>0;st>>=1){ if(n<st) red[n]=fmaxf(red[n],red[n+st]); __syncthreads(); }
  float mx=red[0]; __syncthreads();
  float e=__expf(lg-mx);
  red[n]=e; __syncthreads();
  for(int st=128;st>0;st>>=1){ if(n<st) red[n]+=red[n+st]; __syncthreads(); }
  float denom=red[0]; __syncthreads();
  __shared__ float ps[256];
  ps[n]=e/denom;  // exactly 0 for masked rows
  __syncthreads();
  int d=n;
  float s=0.f;
  for(int nn=0;nn<cN;++nn) s += ps[nn]*X[((size_t)b*cN+nn)*cDX+d];
  Xenc[(size_t)b*16384 + k*cDX + d]=s;
}

// ---------------- head weight-streaming partials ----------------
__global__ void __launch_bounds__(256) k_headA(const float* Genc, const float* Xenc,
                        const float* W_Gtrans, const float* W_Xtrans,
                        float* Gp, float* Xp){
  int blk=blockIdx.x;
  int t=threadIdx.x;
  int o=t&127, sub=t>>7;
  int b0=sub*2, b1=sub*2+1;
  __shared__ float ash[4][128];
  if(blk<64){
    int ch=blk;
    for(int l=t;l<512;l+=256){
      int b=l>>7, q=l&127;
      ash[b][q]=Genc[(size_t)b*8192 + ch*128 + q];
    }
    __syncthreads();
    const float* wbase=W_Gtrans + (size_t)ch*128*cDY + o;
    float a0=0.f, a1=0.f;
#pragma unroll 4
    for(int qq=0;qq<128;++qq){
      float w=wbase[(size_t)qq*cDY];
      a0+=ash[b0][qq]*w; a1+=ash[b1][qq]*w;
    }
    Gp[((size_t)b0*64+ch)*cDY+o]=a0;
    Gp[((size_t)b1*64+ch)*cDY+o]=a1;
  } else {
    int ch=blk-64;
    for(int l=t;l<512;l+=256){
      int b=l>>7, q=l&127;
      ash[b][q]=Xenc[(size_t)b*16384 + ch*128 + q];
    }
    __syncthreads();
    const float* wbase=W_Xtrans + (size_t)ch*128*cDY + o;
    float a0=0.f, a1=0.f;
#pragma unroll 4
    for(int qq=0;qq<128;++qq){
      float w=wbase[(size_t)qq*cDY];
      a0+=ash[b0][qq]*w; a1+=ash[b1][qq]*w;
    }
    Xp[((size_t)b0*128+ch)*cDY+o]=a0;
    Xp[((size_t)b1*128+ch)*cDY+o]=a1;
  }
}

// ---------------- head final -> new_y (f32) ----------------
__global__ void k_headB(const float* Gp, const float* Xp, const float* W_yout,
                        const float* y, const float* gy, const float* by, float* newy){
  int b=blockIdx.x; int o=threadIdx.x; // 128
  float g=0.f,x=0.f;
  for(int ch=0;ch<64;++ch)  g+=Gp[((size_t)b*64+ch)*cDY+o];
  for(int ch=0;ch<128;++ch) x+=Xp[((size_t)b*128+ch)*cDY+o];
  __shared__ float srow[cDY];
  srow[o]=fmaxf(g,0.f)+fmaxf(x,0.f);
  __syncthreads();
  float h=0.f;
  for(int r=0;r<cDY;++r) h += srow[r]*W_yout[r*cDY+o];
  float v=fmaxf(h,0.f)+y[b*cDY+o];
  __shared__ float red[cDY];
  red[o]=v; __syncthreads();
  for(int st=64;st>0;st>>=1){ if(o<st) red[o]+=red[o+st]; __syncthreads(); }
  float mean=red[0]*(1.f/cDY); __syncthreads();
  float dv=v-mean;
  red[o]=dv*dv; __syncthreads();
  for(int st=64;st>0;st>>=1){ if(o<st) red[o]+=red[o+st]; __syncthreads(); }
  float var=red[0]*(1.f/cDY);
  newy[b*cDY+o]=dv*rsqrtf(var+1e-6f)*gy[o]+by[o];
}

extern "C" void kernel_launch(void* const* d_in, const int* in_sizes, int n_in,
                              void* d_out, int out_size, void* d_ws, size_t ws_size,
                              hipStream_t stream){
  const float* X     =(const float*)d_in[0];
  const float* E     =(const float*)d_in[1];
  const float* y     =(const float*)d_in[2];
  const int*   nm    =(const int*)  d_in[3];
  const float* W_emax=(const float*)d_in[4];
  const float* W_x1  =(const float*)d_in[5];
  const float* Wq    =(const float*)d_in[6];
  const float* Wk    =(const float*)d_in[7];
  const float* Wv    =(const float*)d_in[8];
  const float* Wo    =(const float*)d_in[9];
  const float* W_y2  =(const float*)d_in[10];
  const float* W_x2  =(const float*)d_in[11];
  const float* Wc    =(const float*)d_in[12];
  const float* bc    =(const float*)d_in[13];
  const float* salpha=(const float*)d_in[14];
  const float* W_Eout=(const float*)d_in[15];
  const float* G_kern=(const float*)d_in[16];
  const float* X_kern=(const float*)d_in[17];
  const float* W_Gtr =(const float*)d_in[18];
  const float* W_Xtr =(const float*)d_in[19];
  const float* W_yout=(const float*)d_in[20];
  const float* gx    =(const float*)d_in[21];
  const float* bx    =(const float*)d_in[22];
  const float* ge    =(const float*)d_in[23];
  const float* be    =(const float*)d_in[24];
  const float* gy    =(const float*)d_in[25];
  const float* by    =(const float*)d_in[26];

  char* wsb=(char*)d_ws;
  bf16* Gbf=(bf16*)wsb;
  bf16* Bbf=(bf16*)(wsb+33554432);
  float* Npart=(float*)(wsb+33554432);   // aliases Bbf (dead after poly2); 33.5 MB exact
  float* f32=(float*)(wsb+67108864);
  float* sim  = f32+F_SIM;
  float* P    = f32+F_P;
  float* Dpart= f32+F_NP;                // 131072 floats used
  float* Gp   = f32+F_GP;
  float* Xp   = f32+F_XP;
  float* S    = f32+F_S;
  float* eenc = f32+F_EENC;
  float* xplus= f32+F_XPL;
  float* qb   = f32+F_QB;
  float* kb   = f32+F_KB;
  float* vb   = f32+F_VB;
  float* yw   = f32+F_YW;
  float* xpy  = f32+F_XPY;
  float* coeff= f32+F_COEF;
  float* Genc = f32+F_GENC;
  float* Xenc = f32+F_XENC;

  float* out=(float*)d_out;          // reference outputs are float32
  float* newX=out;                   // [0, 262144)
  float* newE_out=out+262144;        // [262144, 17039360) — also stages pre-Eout NEWE
  float* newy=out+17039360;          // [17039360, 17039872)

  k_coeff_yw<<<cB,256,0,stream>>>(y,Wc,bc,W_y2,coeff,yw);
  k_reduceE<<<cB*cN,dim3(64,4),0,stream>>>(E,nm,S);
  k_eenc<<<cB*cN,256,0,stream>>>(S,W_emax,nm,eenc);
  k_xplus<<<cB*cN,256,0,stream>>>(X,eenc,W_x1,nm,xplus);
  k_qkv<<<cB*cN,256,0,stream>>>(xplus,Wq,Wk,Wv,qb,kb,vb);
  k_attn_softmax<<<cB*cNH*cN,256,0,stream>>>(qb,kb,nm,P);
  k_attn_out<<<cB*cN,256,0,stream>>>(P,vb,Wo,X,nm,gx,bx,newX);
  k_xplusy<<<cB*cN,256,0,stream>>>(X,yw,W_x2,xpy);
  k_sim<<<dim3(16,16,cB),dim3(16,16),0,stream>>>(xpy,sim);
  k_G<<<cB*cN,256,0,stream>>>(E,sim,nm,salpha,Gbf);
  // Bbf = c0*(G@G) + c1*G ; NEWE = G@Bbf + c2*G  (staged f32 in d_out new_E slot)
  k_bmm_mfma<bf16><<<dim3(2,2,cB*cDE),256,0,stream>>>(Gbf,Gbf,Bbf,coeff,0,1);
  k_bmm_mfma<float><<<dim3(2,2,cB*cDE),256,0,stream>>>(Gbf,Bbf,newE_out,coeff,-1,2);
  k_Eout<<<65536,256,0,stream>>>(newE_out,E,nm,W_Eout,ge,be,newE_out);
  k_Gaccum<<<dim3(256,cB),256,0,stream>>>(E,nm,G_kern,Npart,Dpart);
  k_Gcombine<<<cB*128,64,0,stream>>>(Npart,Dpart,Genc);
  k_Xenc<<<dim3(64,cB),256,0,stream>>>(X,nm,X_kern,Xenc);
  k_headA<<<192,256,0,stream>>>(Genc,Xenc,W_Gtr,W_Xtr,Gp,Xp);
  k_headB<<<cB,128,0,stream>>>(Gp,Xp,W_yout,y,gy,by,newy);
}

// Round 7
// 612.797 us; speedup vs baseline: 2.7209x; 1.0185x over previous
//
#include <hip/hip_runtime.h>
#include <hip/hip_bf16.h>

typedef __hip_bfloat16 bf16;
__device__ __forceinline__ bf16 tobf(float v){ return __float2bfloat16(v); }
__device__ __forceinline__ float frombf(bf16 v){ return __bfloat162float(v); }

typedef __attribute__((ext_vector_type(8))) short bf16x8;
typedef __attribute__((ext_vector_type(4))) float f32x4;
typedef __attribute__((ext_vector_type(4))) int int4v;

static constexpr int cB=4, cN=256, cDX=256, cDE=64, cDY=128, cNH=8, cDF=32;

// ---- workspace layout (bytes) ----
// [0, 33554432)           Gbf   (bf16, 16.7M elems)
// [33554432, 67108864)    Bbf   (bf16, 16.7M elems)  -- after poly2: Npart f32 (8388608 floats, exact fit)
// [67108864, ...)         f32 region, offsets below in floats:
static constexpr size_t F_SIM  = 0;        // 262144
static constexpr size_t F_P    = 262144;   // 2097152
static constexpr size_t F_NP   = 2359296;  // region: Dpart [0,131072), Gp/Xp at +1048576
static constexpr size_t F_GP   = F_NP + 1048576;          // 32768 floats
static constexpr size_t F_XP   = F_NP + 1048576 + 32768;  // 65536 floats
static constexpr size_t F_S    = 6619136;  // 65536
static constexpr size_t F_EENC = 6684672;  // 262144
static constexpr size_t F_XPL  = 6946816;  // 262144
static constexpr size_t F_QB   = 7208960;  // 262144
static constexpr size_t F_KB   = 7471104;  // 262144
static constexpr size_t F_VB   = 7733248;  // 262144
static constexpr size_t F_YW   = 7995392;  // 1024
static constexpr size_t F_XPY  = 7996416;  // 262144
static constexpr size_t F_COEF = 8258560;  // 16
static constexpr size_t F_GENC = 8258576;  // 32768
static constexpr size_t F_XENC = 8291344;  // 65536

// ---------------- coeff = y@Wc+bc ; yw = relu(y@W_y2) ----------------
__global__ void k_coeff_yw(const float* y, const float* Wc, const float* bc,
                           const float* W_y2, float* coeff, float* yw){
  int b = blockIdx.x; int f = threadIdx.x; // 256
  float acc = 0.f;
  for(int r=0;r<cDY;++r) acc += y[b*cDY+r]*W_y2[r*cDX+f];
  yw[b*cDX+f] = fmaxf(acc,0.f);
  if (f < 3){
    float c = bc[f];
    for(int r=0;r<cDY;++r) c += y[b*cDY+r]*Wc[r*3+f];
    coeff[b*3+f] = c;
  }
}

// ---------------- S[b,i,d] = sum_j E[b,i,j,d]*m_j ----------------
__global__ void k_reduceE(const float* E, const int* nm, float* S){
  int bi = blockIdx.x; int b = bi / cN;
  int d = threadIdx.x;  // 64
  int jy = threadIdx.y; // 4
  const float* Eb = E + (size_t)bi*cN*cDE;
  float acc = 0.f;
  for(int j=jy;j<cN;j+=4){
    acc += Eb[j*cDE+d] * (float)nm[b*cN+j];
  }
  __shared__ float red[4][64];
  red[jy][d]=acc; __syncthreads();
  if (jy==0) S[(size_t)bi*cDE+d] = red[0][d]+red[1][d]+red[2][d]+red[3][d];
}

// ---------------- e_enc[b,i,f] = relu(m_i/N * S[b,i,:]@W_emax[:,f]) ----------------
__global__ void k_eenc(const float* S, const float* W_emax, const int* nm, float* eenc){
  int bi = blockIdx.x; int b = bi/cN; int i = bi%cN;
  int f = threadIdx.x;
  __shared__ float s[cDE];
  if (f<cDE) s[f]=S[(size_t)bi*cDE+f];
  __syncthreads();
  float acc=0.f;
  for(int d=0;d<cDE;++d) acc += s[d]*W_emax[d*cDX+f];
  float mi=(float)nm[b*cN+i];
  eenc[(size_t)bi*cDX+f] = fmaxf(acc*mi*(1.f/cN), 0.f);
}

// ---------------- xplus = (X + relu(eenc@W_x1)) * m_i ----------------
__global__ void k_xplus(const float* X, const float* eenc, const float* W_x1,
                        const int* nm, float* xplus){
  int bi=blockIdx.x; int b=bi/cN; int i=bi%cN;
  int f=threadIdx.x;
  __shared__ float row[cDX];
  row[f]=eenc[(size_t)bi*cDX+f];
  __syncthreads();
  float acc=0.f;
  for(int c=0;c<cDX;++c) acc += row[c]*W_x1[c*cDX+f];
  float mi=(float)nm[b*cN+i];
  xplus[(size_t)bi*cDX+f] = (X[(size_t)bi*cDX+f] + fmaxf(acc,0.f))*mi;
}

// ---------------- q,k,v projections ----------------
__global__ void k_qkv(const float* xplus, const float* Wq, const float* Wk, const float* Wv,
                      float* qb, float* kb, float* vb){
  int bi=blockIdx.x; int f=threadIdx.x;
  __shared__ float row[cDX];
  row[f]=xplus[(size_t)bi*cDX+f];
  __syncthreads();
  float aq=0,ak=0,av=0;
  for(int c=0;c<cDX;++c){ float r=row[c]; aq+=r*Wq[c*cDX+f]; ak+=r*Wk[c*cDX+f]; av+=r*Wv[c*cDX+f]; }
  qb[(size_t)bi*cDX+f]=aq; kb[(size_t)bi*cDX+f]=ak; vb[(size_t)bi*cDX+f]=av;
}

// ---------------- attention softmax rows -> P[b,h,i,j] ----------------
__global__ void k_attn_softmax(const float* qb, const float* kb, const int* nm, float* P){
  int id=blockIdx.x; int b=id/(cNH*cN); int rem=id%(cNH*cN); int h=rem/cN; int i=rem%cN;
  int j=threadIdx.x;
  __shared__ float qrow[cDF];
  if (j<cDF) qrow[j]=qb[((size_t)b*cN+i)*cDX + h*cDF + j];
  __syncthreads();
  const float* krow = kb + ((size_t)b*cN+j)*cDX + h*cDF;
  float s=0.f;
  for(int c=0;c<cDF;++c) s += qrow[c]*krow[c];
  s *= 0.17677669529663687f; // 1/sqrt(32)
  float val = (nm[b*cN+j]>0) ? s : -1e9f;
  __shared__ float red[256];
  red[j]=val; __syncthreads();
  for(int st=128;st>0;st>>=1){ if(j<st) red[j]=fmaxf(red[j],red[j+st]); __syncthreads(); }
  float mx=red[0]; __syncthreads();
  float e=__expf(val-mx);
  red[j]=e; __syncthreads();
  for(int st=128;st>0;st>>=1){ if(j<st) red[j]+=red[j+st]; __syncthreads(); }
  float denom=red[0];
  P[(size_t)id*cN + j] = e/denom;
}

// ---------------- P@V, @Wo, *mask, +X, LayerNorm -> new_X (f32) ----------------
__global__ void k_attn_out(const float* P, const float* vb, const float* Wo,
                           const float* X, const int* nm, const float* gx, const float* bx,
                           float* newX){
  int bi=blockIdx.x; int b=bi/cN; int i=bi%cN;
  int t=threadIdx.x;
  __shared__ float p8[cNH][cN];
  for(int h=0;h<cNH;++h) p8[h][t]=P[(((size_t)b*cNH+h)*cN+i)*cN + t];
  __syncthreads();
  int h=t/cDF;
  float acc=0.f;
  for(int j=0;j<cN;++j) acc += p8[h][j]*vb[((size_t)b*cN+j)*cDX + t];
  __shared__ float arow[cDX];
  arow[t]=acc; __syncthreads();
  float o=0.f;
  for(int c=0;c<cDX;++c) o += arow[c]*Wo[c*cDX+t];
  float mi=(float)nm[b*cN+i];
  float v = o*mi + X[(size_t)bi*cDX+t];
  __shared__ float red[256];
  red[t]=v; __syncthreads();
  for(int st=128;st>0;st>>=1){ if(t<st) red[t]+=red[t+st]; __syncthreads(); }
  float mean=red[0]*(1.f/cDX); __syncthreads();
  float dv=v-mean;
  red[t]=dv*dv; __syncthreads();
  for(int st=128;st>0;st>>=1){ if(t<st) red[t]+=red[t+st]; __syncthreads(); }
  float var=red[0]*(1.f/cDX);
  newX[(size_t)bi*cDX+t]=dv*rsqrtf(var+1e-6f)*gx[t]+bx[t];
}

// ---------------- xplusy = relu((X + yw)@W_x2) ----------------
__global__ void k_xplusy(const float* X, const float* yw, const float* W_x2, float* xpy){
  int bi=blockIdx.x; int b=bi/cN;
  int f=threadIdx.x;
  __shared__ float row[cDX];
  row[f]=X[(size_t)bi*cDX+f]+yw[b*cDX+f];
  __syncthreads();
  float acc=0.f;
  for(int c=0;c<cDX;++c) acc += row[c]*W_x2[c*cDX+f];
  xpy[(size_t)bi*cDX+f]=fmaxf(acc,0.f);
}

// ---------------- sim = xpy @ xpy^T / 16 ----------------
__global__ void k_sim(const float* xp, float* sim){
  int b=blockIdx.z;
  int tx=threadIdx.x, ty=threadIdx.y;
  __shared__ float Aa[16][17], Bb[16][17];
  const float* base = xp + (size_t)b*cN*cDX;
  float acc=0.f;
  for(int kt=0;kt<cDX;kt+=16){
    Aa[ty][tx]=base[(size_t)(blockIdx.y*16+ty)*cDX + kt+tx];
    Bb[ty][tx]=base[(size_t)(blockIdx.x*16+ty)*cDX + kt+tx];
    __syncthreads();
    for(int c=0;c<16;++c) acc += Aa[ty][c]*Bb[tx][c];
    __syncthreads();
  }
  sim[((size_t)b*cN + blockIdx.y*16+ty)*cN + blockIdx.x*16+tx] = acc*(1.f/16.f);
}

// ---------------- G = (alpha*sim + E) * emask  (bf16 out) ----------------
__global__ void k_G(const float* E, const float* sim, const int* nm, const float* alpha_p,
                    bf16* G){
  int bi=blockIdx.x; int b=bi/cN; int i=bi%cN;
  float mi=(float)nm[b*cN+i];
  float alpha=alpha_p[0];
  size_t base=(size_t)bi*cN*cDE;
  for(int t=threadIdx.x;t<cN*cDE;t+=blockDim.x){
    int j=t>>6;
    float mj=(float)nm[b*cN+j];
    G[base+t]=tobf((alpha*sim[(size_t)bi*cN+j]+E[base+t])*mi*mj);
  }
}

__device__ __forceinline__ void store_out(bf16* p, float v){ *p = tobf(v); }
__device__ __forceinline__ void store_out(float* p, float v){ *p = v; }

// ---------------- batched 256x256 MFMA GEMM (bf16 in, f32 accum):
//                  C = alpha*(A@B) + beta*A ----------------
template<typename OT>
__global__ void __launch_bounds__(256) k_bmm_mfma(const bf16* A, const bf16* Bm, OT* C,
                                                  const float* coeff, int ia, int ib){
  int bc=blockIdx.z; int b=bc>>6;
  float alpha=(ia>=0)?coeff[b*3+ia]:1.0f;
  float beta=coeff[b*3+ib];
  const short* Ab=(const short*)(A+(size_t)bc*65536);
  const short* Bb=(const short*)(Bm+(size_t)bc*65536);
  OT* Cb=C+(size_t)bc*65536;
  const int row0=blockIdx.y*128, col0=blockIdx.x*128;
  const int t=threadIdx.x;
  const int lane=t&63, w=t>>6;
  const int wr=w>>1, wc=w&1;
  const int l15=lane&15, l4=lane>>4;
  __shared__ short A_s[128][72];
  __shared__ short B_s[128][72];   // B transposed: [n][k]
  f32x4 acc[4][4];
#pragma unroll
  for(int m=0;m<4;++m)
#pragma unroll
    for(int n=0;n<4;++n) acc[m][n]=(f32x4){0.f,0.f,0.f,0.f};

  const int kh=t>>7;          // 0..1 (wave-uniform)
  const int nB=t&127;
  for(int kt=0;kt<256;kt+=64){
#pragma unroll
    for(int l=0;l<4;++l){
      int idx=t+l*256;
      int r=idx>>3, seg=idx&7;
      *(int4v*)&A_s[r][seg*8] = *(const int4v*)&Ab[(size_t)(row0+r)*256 + kt + seg*8];
    }
#pragma unroll 8
    for(int kk=0;kk<32;++kk){
      int k=kh*32+kk;
      B_s[nB][k]=Bb[(size_t)(kt+k)*256 + col0 + nB];
    }
    __syncthreads();
#pragma unroll
    for(int ks=0;ks<64;ks+=32){
      bf16x8 am[4], bn[4];
#pragma unroll
      for(int m=0;m<4;++m) am[m]=*(const bf16x8*)&A_s[wr*64+m*16+l15][ks+l4*8];
#pragma unroll
      for(int n=0;n<4;++n) bn[n]=*(const bf16x8*)&B_s[wc*64+n*16+l15][ks+l4*8];
#pragma unroll
      for(int m=0;m<4;++m)
#pragma unroll
        for(int n=0;n<4;++n)
          acc[m][n]=__builtin_amdgcn_mfma_f32_16x16x32_bf16(am[m],bn[n],acc[m][n],0,0,0);
    }
    __syncthreads();
  }
#pragma unroll
  for(int m=0;m<4;++m){
#pragma unroll
    for(int n=0;n<4;++n){
#pragma unroll
      for(int r=0;r<4;++r){
        int row=row0+wr*64+m*16+l4*4+r;
        int col=col0+wc*64+n*16+l15;
        size_t off=(size_t)row*256+col;
        float a0; { unsigned short u=(unsigned short)Ab[off]; unsigned int v=((unsigned int)u)<<16; a0=__int_as_float((int)v); }
        store_out(&Cb[off], alpha*acc[m][n][r]+beta*a0);
      }
    }
  }
}

// ---------------- newE(f32, staged in-place) -> relu(@W_Eout)*emask + E -> LN -> new_E (f32) ----------------
__global__ void k_Eout(const float* newE_in, const float* E, const int* nm,
                       const float* W_Eout, const float* ge, const float* be, float* outE){
  int wav=threadIdx.x>>6; int lane=threadIdx.x&63;
  size_t row=(size_t)blockIdx.x*4+wav;
  int b=(int)(row>>16); int ij=(int)(row&65535); int i=ij>>8; int j=ij&255;
  float mij=(float)(nm[b*cN+i]*nm[b*cN+j]);
  __shared__ float lds[4][cDE];
  size_t off=row*cDE;
  lds[wav][lane]=newE_in[off+lane];
  __syncthreads();
  float acc=0.f;
  for(int d=0;d<cDE;++d) acc += lds[wav][d]*W_Eout[d*cDE+lane];
  float v=fmaxf(acc,0.f)*mij + E[off+lane];
  float s=v;
  for(int m=32;m>0;m>>=1) s += __shfl_xor(s,m,64);
  float mean=s*(1.f/cDE);
  float dv=v-mean; float q=dv*dv;
  for(int m=32;m>0;m>>=1) q += __shfl_xor(q,m,64);
  float var=q*(1.f/cDE);
  outE[off+lane]=dv*rsqrtf(var+1e-6f)*ge[lane]+be[lane];
}

// ---------------- fused aG-softmax partials (2-way k-split, no spills) ----------------
// grid (256 chunks, 2 k-halves, 4 b); thread owns ONE k column:
//   dq=t&3 -> d range [dq*16, dq*16+16); kk=t>>2 -> k = kh*64 + kk.
// 64-d logit dot from 16-d partials via shfl_xor(1,2) within 4-lane groups.
__global__ void __launch_bounds__(256) k_Gaccum(const float* E, const int* nm,
                                                const float* G_kernel,
                                                float* Npart, float* Dpart){
  int chunk=blockIdx.x; // 256 chunks of 256 p-rows
  int kh=blockIdx.y;    // 2
  int b=blockIdx.z;     // 4
  int t=threadIdx.x;    // 256
  int dq=t&3;
  int kk=t>>2;          // 0..63
  int k=kh*64+kk;
  float gk[16];
#pragma unroll
  for(int d=0;d<16;++d) gk[d]=G_kernel[(dq*16+d)*128 + k];
  float acc[16];
#pragma unroll
  for(int d=0;d<16;++d) acc[d]=0.f;
  float den=0.f;
  __shared__ float em[16][cDE];
  __shared__ float mrow[16];
  const size_t ebase=((size_t)b)<<16;
  int base=chunk*256;
  const int srr=t>>4;   // staging row 0..15
  const int sds=t&15;   // staging float4 segment
  for(int s=0;s<16;++s){
    int p0=base+16*s;
    __syncthreads();
    {
      int pp=p0+srr;
      float m=(float)(nm[b*cN+(pp>>8)]*nm[b*cN+(pp&255)]);
      float4 v=*(const float4*)&E[(ebase+pp)*cDE + sds*4];
      v.x*=m; v.y*=m; v.z*=m; v.w*=m;
      *(float4*)&em[srr][sds*4]=v;
      if(sds==0) mrow[srr]=m;
    }
    __syncthreads();
#pragma unroll
    for(int rr=0;rr<16;++rr){
      if(mrow[rr]<=0.f) continue;   // wave-uniform skip
      float r[16];
#pragma unroll
      for(int d=0;d<16;++d) r[d]=em[rr][dq*16+d];
      float pd=0.f;
#pragma unroll
      for(int d=0;d<16;++d) pd+=r[d]*gk[d];
      pd+=__shfl_xor(pd,1); pd+=__shfl_xor(pd,2);
      float w=__expf(pd*0.125f);
      den+=w;
#pragma unroll
      for(int d=0;d<16;++d) acc[d]+=w*r[d];
    }
  }
  size_t pi=(size_t)b*256+chunk;
  float* np=Npart + pi*128*cDE;
#pragma unroll
  for(int d=0;d<16;++d) np[(size_t)k*cDE + dq*16+d]=acc[d];
  if(dq==0) Dpart[pi*128+k]=den;
}

// ---------------- combine partials -> Genc[b, k*64+d] ----------------
__global__ void k_Gcombine(const float* Npart, const float* Dpart, float* Genc){
  int bk=blockIdx.x; int b=bk>>7; int k=bk&127;
  int d=threadIdx.x; // 64
  float n=0.f, dd=0.f;
  for(int pi=0;pi<256;++pi){
    size_t base=((size_t)b*256+pi)*128+k;
    n += Npart[base*cDE+d];
    dd += Dpart[base];
  }
  Genc[(size_t)b*8192 + k*cDE + d]=n/dd;
}

// ---------------- aX softmax + X_enc[b, k*256+d] ----------------
__global__ void k_Xenc(const float* X, const int* nm, const float* X_kernel, float* Xenc){
  int k=blockIdx.x;  // 64
  int b=blockIdx.y;  // 4
  int n=threadIdx.x; // 256
  float m=(float)nm[b*cN+n];
  const float* xr=X+((size_t)b*cN+n)*cDX;
  float acc=0.f;
  for(int c=0;c<cDX;++c) acc += xr[c]*X_kernel[c*64+k];
  float lg=(m>0.f)?acc*(1.f/16.f):-1e9f;
  __shared__ float red[256];
  red[n]=lg; __syncthreads();
  for(int st=128;st>0;st>>=1){ if(n<st) red[n]=fmaxf(red[n],red[n+st]); __syncthreads(); }
  float mx=red[0]; __syncthreads();
  float e=__expf(lg-mx);
  red[n]=e; __syncthreads();
  for(int st=128;st>0;st>>=1){ if(n<st) red[n]+=red[n+st]; __syncthreads(); }
  float denom=red[0]; __syncthreads();
  __shared__ float ps[256];
  ps[n]=e/denom;  // exactly 0 for masked rows
  __syncthreads();
  int d=n;
  float s=0.f;
  for(int nn=0;nn<cN;++nn) s += ps[nn]*X[((size_t)b*cN+nn)*cDX+d];
  Xenc[(size_t)b*16384 + k*cDX + d]=s;
}

// ---------------- head weight-streaming partials ----------------
__global__ void __launch_bounds__(256) k_headA(const float* Genc, const float* Xenc,
                        const float* W_Gtrans, const float* W_Xtrans,
                        float* Gp, float* Xp){
  int blk=blockIdx.x;
  int t=threadIdx.x;
  int o=t&127, sub=t>>7;
  int b0=sub*2, b1=sub*2+1;
  __shared__ float ash[4][128];
  if(blk<64){
    int ch=blk;
    for(int l=t;l<512;l+=256){
      int b=l>>7, q=l&127;
      ash[b][q]=Genc[(size_t)b*8192 + ch*128 + q];
    }
    __syncthreads();
    const float* wbase=W_Gtrans + (size_t)ch*128*cDY + o;
    float a0=0.f, a1=0.f;
#pragma unroll 4
    for(int qq=0;qq<128;++qq){
      float w=wbase[(size_t)qq*cDY];
      a0+=ash[b0][qq]*w; a1+=ash[b1][qq]*w;
    }
    Gp[((size_t)b0*64+ch)*cDY+o]=a0;
    Gp[((size_t)b1*64+ch)*cDY+o]=a1;
  } else {
    int ch=blk-64;
    for(int l=t;l<512;l+=256){
      int b=l>>7, q=l&127;
      ash[b][q]=Xenc[(size_t)b*16384 + ch*128 + q];
    }
    __syncthreads();
    const float* wbase=W_Xtrans + (size_t)ch*128*cDY + o;
    float a0=0.f, a1=0.f;
#pragma unroll 4
    for(int qq=0;qq<128;++qq){
      float w=wbase[(size_t)qq*cDY];
      a0+=ash[b0][qq]*w; a1+=ash[b1][qq]*w;
    }
    Xp[((size_t)b0*128+ch)*cDY+o]=a0;
    Xp[((size_t)b1*128+ch)*cDY+o]=a1;
  }
}

// ---------------- head final -> new_y (f32) ----------------
__global__ void k_headB(const float* Gp, const float* Xp, const float* W_yout,
                        const float* y, const float* gy, const float* by, float* newy){
  int b=blockIdx.x; int o=threadIdx.x; // 128
  float g=0.f,x=0.f;
  for(int ch=0;ch<64;++ch)  g+=Gp[((size_t)b*64+ch)*cDY+o];
  for(int ch=0;ch<128;++ch) x+=Xp[((size_t)b*128+ch)*cDY+o];
  __shared__ float srow[cDY];
  srow[o]=fmaxf(g,0.f)+fmaxf(x,0.f);
  __syncthreads();
  float h=0.f;
  for(int r=0;r<cDY;++r) h += srow[r]*W_yout[r*cDY+o];
  float v=fmaxf(h,0.f)+y[b*cDY+o];
  __shared__ float red[cDY];
  red[o]=v; __syncthreads();
  for(int st=64;st>0;st>>=1){ if(o<st) red[o]+=red[o+st]; __syncthreads(); }
  float mean=red[0]*(1.f/cDY); __syncthreads();
  float dv=v-mean;
  red[o]=dv*dv; __syncthreads();
  for(int st=64;st>0;st>>=1){ if(o<st) red[o]+=red[o+st]; __syncthreads(); }
  float var=red[0]*(1.f/cDY);
  newy[b*cDY+o]=dv*rsqrtf(var+1e-6f)*gy[o]+by[o];
}

extern "C" void kernel_launch(void* const* d_in, const int* in_sizes, int n_in,
                              void* d_out, int out_size, void* d_ws, size_t ws_size,
                              hipStream_t stream){
  const float* X     =(const float*)d_in[0];
  const float* E     =(const float*)d_in[1];
  const float* y     =(const float*)d_in[2];
  const int*   nm    =(const int*)  d_in[3];
  const float* W_emax=(const float*)d_in[4];
  const float* W_x1  =(const float*)d_in[5];
  const float* Wq    =(const float*)d_in[6];
  const float* Wk    =(const float*)d_in[7];
  const float* Wv    =(const float*)d_in[8];
  const float* Wo    =(const float*)d_in[9];
  const float* W_y2  =(const float*)d_in[10];
  const float* W_x2  =(const float*)d_in[11];
  const float* Wc    =(const float*)d_in[12];
  const float* bc    =(const float*)d_in[13];
  const float* salpha=(const float*)d_in[14];
  const float* W_Eout=(const float*)d_in[15];
  const float* G_kern=(const float*)d_in[16];
  const float* X_kern=(const float*)d_in[17];
  const float* W_Gtr =(const float*)d_in[18];
  const float* W_Xtr =(const float*)d_in[19];
  const float* W_yout=(const float*)d_in[20];
  const float* gx    =(const float*)d_in[21];
  const float* bx    =(const float*)d_in[22];
  const float* ge    =(const float*)d_in[23];
  const float* be    =(const float*)d_in[24];
  const float* gy    =(const float*)d_in[25];
  const float* by    =(const float*)d_in[26];

  char* wsb=(char*)d_ws;
  bf16* Gbf=(bf16*)wsb;
  bf16* Bbf=(bf16*)(wsb+33554432);
  float* Npart=(float*)(wsb+33554432);   // aliases Bbf (dead after poly2); 33.5 MB exact
  float* f32=(float*)(wsb+67108864);
  float* sim  = f32+F_SIM;
  float* P    = f32+F_P;
  float* Dpart= f32+F_NP;                // 131072 floats used
  float* Gp   = f32+F_GP;
  float* Xp   = f32+F_XP;
  float* S    = f32+F_S;
  float* eenc = f32+F_EENC;
  float* xplus= f32+F_XPL;
  float* qb   = f32+F_QB;
  float* kb   = f32+F_KB;
  float* vb   = f32+F_VB;
  float* yw   = f32+F_YW;
  float* xpy  = f32+F_XPY;
  float* coeff= f32+F_COEF;
  float* Genc = f32+F_GENC;
  float* Xenc = f32+F_XENC;

  float* out=(float*)d_out;          // reference outputs are float32
  float* newX=out;                   // [0, 262144)
  float* newE_out=out+262144;        // [262144, 17039360) — also stages pre-Eout NEWE
  float* newy=out+17039360;          // [17039360, 17039872)

  k_coeff_yw<<<cB,256,0,stream>>>(y,Wc,bc,W_y2,coeff,yw);
  k_reduceE<<<cB*cN,dim3(64,4),0,stream>>>(E,nm,S);
  k_eenc<<<cB*cN,256,0,stream>>>(S,W_emax,nm,eenc);
  k_xplus<<<cB*cN,256,0,stream>>>(X,eenc,W_x1,nm,xplus);
  k_qkv<<<cB*cN,256,0,stream>>>(xplus,Wq,Wk,Wv,qb,kb,vb);
  k_attn_softmax<<<cB*cNH*cN,256,0,stream>>>(qb,kb,nm,P);
  k_attn_out<<<cB*cN,256,0,stream>>>(P,vb,Wo,X,nm,gx,bx,newX);
  k_xplusy<<<cB*cN,256,0,stream>>>(X,yw,W_x2,xpy);
  k_sim<<<dim3(16,16,cB),dim3(16,16),0,stream>>>(xpy,sim);
  k_G<<<cB*cN,256,0,stream>>>(E,sim,nm,salpha,Gbf);
  // Bbf = c0*(G@G) + c1*G ; NEWE = G@Bbf + c2*G  (staged f32 in d_out new_E slot)
  k_bmm_mfma<bf16><<<dim3(2,2,cB*cDE),256,0,stream>>>(Gbf,Gbf,Bbf,coeff,0,1);
  k_bmm_mfma<float><<<dim3(2,2,cB*cDE),256,0,stream>>>(Gbf,Bbf,newE_out,coeff,-1,2);
  k_Eout<<<65536,256,0,stream>>>(newE_out,E,nm,W_Eout,ge,be,newE_out);
  k_Gaccum<<<dim3(256,2,cB),256,0,stream>>>(E,nm,G_kern,Npart,Dpart);
  k_Gcombine<<<cB*128,64,0,stream>>>(Npart,Dpart,Genc);
  k_Xenc<<<dim3(64,cB),256,0,stream>>>(X,nm,X_kern,Xenc);
  k_headA<<<192,256,0,stream>>>(Genc,Xenc,W_Gtr,W_Xtr,Gp,Xp);
  k_headB<<<cB,128,0,stream>>>(Gp,Xp,W_yout,y,gy,by,newy);
}

// Round 8
// 513.115 us; speedup vs baseline: 3.2495x; 1.1943x over previous
//
#include <hip/hip_runtime.h>
#include <hip/hip_bf16.h>

typedef __hip_bfloat16 bf16;
__device__ __forceinline__ bf16 tobf(float v){ return __float2bfloat16(v); }
__device__ __forceinline__ float frombf(bf16 v){ return __bfloat162float(v); }
__device__ __forceinline__ short f2bs(float x){ bf16 h=tobf(x); return *reinterpret_cast<short*>(&h); }

typedef __attribute__((ext_vector_type(8))) short bf16x8;
typedef __attribute__((ext_vector_type(4))) float f32x4;
typedef __attribute__((ext_vector_type(4))) int int4v;

static constexpr int cB=4, cN=256, cDX=256, cDE=64, cDY=128, cNH=8, cDF=32;

// ---- workspace layout (bytes) ----
static constexpr size_t F_SIM  = 0;        // 262144
static constexpr size_t F_P    = 262144;   // 2097152
static constexpr size_t F_NP   = 2359296;  // region: Dpart [0,131072), Gp/Xp at +1048576
static constexpr size_t F_GP   = F_NP + 1048576;
static constexpr size_t F_XP   = F_NP + 1048576 + 32768;
static constexpr size_t F_S    = 6619136;
static constexpr size_t F_EENC = 6684672;
static constexpr size_t F_XPL  = 6946816;
static constexpr size_t F_QB   = 7208960;
static constexpr size_t F_KB   = 7471104;
static constexpr size_t F_VB   = 7733248;
static constexpr size_t F_YW   = 7995392;
static constexpr size_t F_XPY  = 7996416;
static constexpr size_t F_COEF = 8258560;
static constexpr size_t F_GENC = 8258576;
static constexpr size_t F_XENC = 8291344;

// ---------------- coeff = y@Wc+bc ; yw = relu(y@W_y2) ----------------
__global__ void k_coeff_yw(const float* y, const float* Wc, const float* bc,
                           const float* W_y2, float* coeff, float* yw){
  int b = blockIdx.x; int f = threadIdx.x; // 256
  float acc = 0.f;
  for(int r=0;r<cDY;++r) acc += y[b*cDY+r]*W_y2[r*cDX+f];
  yw[b*cDX+f] = fmaxf(acc,0.f);
  if (f < 3){
    float c = bc[f];
    for(int r=0;r<cDY;++r) c += y[b*cDY+r]*Wc[r*3+f];
    coeff[b*3+f] = c;
  }
}

// ---------------- S[b,i,d] = sum_j E[b,i,j,d]*m_j ----------------
__global__ void k_reduceE(const float* E, const int* nm, float* S){
  int bi = blockIdx.x; int b = bi / cN;
  int d = threadIdx.x;  // 64
  int jy = threadIdx.y; // 4
  const float* Eb = E + (size_t)bi*cN*cDE;
  float acc = 0.f;
  for(int j=jy;j<cN;j+=4){
    acc += Eb[j*cDE+d] * (float)nm[b*cN+j];
  }
  __shared__ float red[4][64];
  red[jy][d]=acc; __syncthreads();
  if (jy==0) S[(size_t)bi*cDE+d] = red[0][d]+red[1][d]+red[2][d]+red[3][d];
}

// ---------------- e_enc[b,i,f] = relu(m_i/N * S[b,i,:]@W_emax[:,f]) ----------------
__global__ void k_eenc(const float* S, const float* W_emax, const int* nm, float* eenc){
  int bi = blockIdx.x; int b = bi/cN; int i = bi%cN;
  int f = threadIdx.x;
  __shared__ float s[cDE];
  if (f<cDE) s[f]=S[(size_t)bi*cDE+f];
  __syncthreads();
  float acc=0.f;
  for(int d=0;d<cDE;++d) acc += s[d]*W_emax[d*cDX+f];
  float mi=(float)nm[b*cN+i];
  eenc[(size_t)bi*cDX+f] = fmaxf(acc*mi*(1.f/cN), 0.f);
}

// ---------------- xplus = (X + relu(eenc@W_x1)) * m_i ----------------
__global__ void k_xplus(const float* X, const float* eenc, const float* W_x1,
                        const int* nm, float* xplus){
  int bi=blockIdx.x; int b=bi/cN; int i=bi%cN;
  int f=threadIdx.x;
  __shared__ float row[cDX];
  row[f]=eenc[(size_t)bi*cDX+f];
  __syncthreads();
  float acc=0.f;
  for(int c=0;c<cDX;++c) acc += row[c]*W_x1[c*cDX+f];
  float mi=(float)nm[b*cN+i];
  xplus[(size_t)bi*cDX+f] = (X[(size_t)bi*cDX+f] + fmaxf(acc,0.f))*mi;
}

// ---------------- q,k,v projections ----------------
__global__ void k_qkv(const float* xplus, const float* Wq, const float* Wk, const float* Wv,
                      float* qb, float* kb, float* vb){
  int bi=blockIdx.x; int f=threadIdx.x;
  __shared__ float row[cDX];
  row[f]=xplus[(size_t)bi*cDX+f];
  __syncthreads();
  float aq=0,ak=0,av=0;
  for(int c=0;c<cDX;++c){ float r=row[c]; aq+=r*Wq[c*cDX+f]; ak+=r*Wk[c*cDX+f]; av+=r*Wv[c*cDX+f]; }
  qb[(size_t)bi*cDX+f]=aq; kb[(size_t)bi*cDX+f]=ak; vb[(size_t)bi*cDX+f]=av;
}

// ---------------- attention softmax rows -> P[b,h,i,j] ----------------
__global__ void k_attn_softmax(const float* qb, const float* kb, const int* nm, float* P){
  int id=blockIdx.x; int b=id/(cNH*cN); int rem=id%(cNH*cN); int h=rem/cN; int i=rem%cN;
  int j=threadIdx.x;
  __shared__ float qrow[cDF];
  if (j<cDF) qrow[j]=qb[((size_t)b*cN+i)*cDX + h*cDF + j];
  __syncthreads();
  const float* krow = kb + ((size_t)b*cN+j)*cDX + h*cDF;
  float s=0.f;
  for(int c=0;c<cDF;++c) s += qrow[c]*krow[c];
  s *= 0.17677669529663687f; // 1/sqrt(32)
  float val = (nm[b*cN+j]>0) ? s : -1e9f;
  __shared__ float red[256];
  red[j]=val; __syncthreads();
  for(int st=128;st>0;st>>=1){ if(j<st) red[j]=fmaxf(red[j],red[j+st]); __syncthreads(); }
  float mx=red[0]; __syncthreads();
  float e=__expf(val-mx);
  red[j]=e; __syncthreads();
  for(int st=128;st>0;st>>=1){ if(j<st) red[j]+=red[j+st]; __syncthreads(); }
  float denom=red[0];
  P[(size_t)id*cN + j] = e/denom;
}

// ---------------- P@V, @Wo, *mask, +X, LayerNorm -> new_X (f32) ----------------
__global__ void k_attn_out(const float* P, const float* vb, const float* Wo,
                           const float* X, const int* nm, const float* gx, const float* bx,
                           float* newX){
  int bi=blockIdx.x; int b=bi/cN; int i=bi%cN;
  int t=threadIdx.x;
  __shared__ float p8[cNH][cN];
  for(int h=0;h<cNH;++h) p8[h][t]=P[(((size_t)b*cNH+h)*cN+i)*cN + t];
  __syncthreads();
  int h=t/cDF;
  float acc=0.f;
  for(int j=0;j<cN;++j) acc += p8[h][j]*vb[((size_t)b*cN+j)*cDX + t];
  __shared__ float arow[cDX];
  arow[t]=acc; __syncthreads();
  float o=0.f;
  for(int c=0;c<cDX;++c) o += arow[c]*Wo[c*cDX+t];
  float mi=(float)nm[b*cN+i];
  float v = o*mi + X[(size_t)bi*cDX+t];
  __shared__ float red[256];
  red[t]=v; __syncthreads();
  for(int st=128;st>0;st>>=1){ if(t<st) red[t]+=red[t+st]; __syncthreads(); }
  float mean=red[0]*(1.f/cDX); __syncthreads();
  float dv=v-mean;
  red[t]=dv*dv; __syncthreads();
  for(int st=128;st>0;st>>=1){ if(t<st) red[t]+=red[t+st]; __syncthreads(); }
  float var=red[0]*(1.f/cDX);
  newX[(size_t)bi*cDX+t]=dv*rsqrtf(var+1e-6f)*gx[t]+bx[t];
}

// ---------------- xplusy = relu((X + yw)@W_x2) ----------------
__global__ void k_xplusy(const float* X, const float* yw, const float* W_x2, float* xpy){
  int bi=blockIdx.x; int b=bi/cN;
  int f=threadIdx.x;
  __shared__ float row[cDX];
  row[f]=X[(size_t)bi*cDX+f]+yw[b*cDX+f];
  __syncthreads();
  float acc=0.f;
  for(int c=0;c<cDX;++c) acc += row[c]*W_x2[c*cDX+f];
  xpy[(size_t)bi*cDX+f]=fmaxf(acc,0.f);
}

// ---------------- sim = xpy @ xpy^T / 16 ----------------
__global__ void k_sim(const float* xp, float* sim){
  int b=blockIdx.z;
  int tx=threadIdx.x, ty=threadIdx.y;
  __shared__ float Aa[16][17], Bb[16][17];
  const float* base = xp + (size_t)b*cN*cDX;
  float acc=0.f;
  for(int kt=0;kt<cDX;kt+=16){
    Aa[ty][tx]=base[(size_t)(blockIdx.y*16+ty)*cDX + kt+tx];
    Bb[ty][tx]=base[(size_t)(blockIdx.x*16+ty)*cDX + kt+tx];
    __syncthreads();
    for(int c=0;c<16;++c) acc += Aa[ty][c]*Bb[tx][c];
    __syncthreads();
  }
  sim[((size_t)b*cN + blockIdx.y*16+ty)*cN + blockIdx.x*16+tx] = acc*(1.f/16.f);
}

// ---------------- G = (alpha*sim + E) * emask  (bf16 out) ----------------
__global__ void k_G(const float* E, const float* sim, const int* nm, const float* alpha_p,
                    bf16* G){
  int bi=blockIdx.x; int b=bi/cN; int i=bi%cN;
  float mi=(float)nm[b*cN+i];
  float alpha=alpha_p[0];
  size_t base=(size_t)bi*cN*cDE;
  for(int t=threadIdx.x;t<cN*cDE;t+=blockDim.x){
    int j=t>>6;
    float mj=(float)nm[b*cN+j];
    G[base+t]=tobf((alpha*sim[(size_t)bi*cN+j]+E[base+t])*mi*mj);
  }
}

__device__ __forceinline__ void store_out(bf16* p, float v){ *p = tobf(v); }
__device__ __forceinline__ void store_out(float* p, float v){ *p = v; }

// ---------------- batched 256x256 MFMA GEMM (bf16 in, f32 accum):
//                  C = alpha*(A@B) + beta*A ----------------
template<typename OT>
__global__ void __launch_bounds__(256) k_bmm_mfma(const bf16* A, const bf16* Bm, OT* C,
                                                  const float* coeff, int ia, int ib){
  int bc=blockIdx.z; int b=bc>>6;
  float alpha=(ia>=0)?coeff[b*3+ia]:1.0f;
  float beta=coeff[b*3+ib];
  const short* Ab=(const short*)(A+(size_t)bc*65536);
  const short* Bb=(const short*)(Bm+(size_t)bc*65536);
  OT* Cb=C+(size_t)bc*65536;
  const int row0=blockIdx.y*128, col0=blockIdx.x*128;
  const int t=threadIdx.x;
  const int lane=t&63, w=t>>6;
  const int wr=w>>1, wc=w&1;
  const int l15=lane&15, l4=lane>>4;
  __shared__ short A_s[128][72];
  __shared__ short B_s[128][72];   // B transposed: [n][k]
  f32x4 acc[4][4];
#pragma unroll
  for(int m=0;m<4;++m)
#pragma unroll
    for(int n=0;n<4;++n) acc[m][n]=(f32x4){0.f,0.f,0.f,0.f};

  const int kh=t>>7;          // 0..1 (wave-uniform)
  const int nB=t&127;
  for(int kt=0;kt<256;kt+=64){
#pragma unroll
    for(int l=0;l<4;++l){
      int idx=t+l*256;
      int r=idx>>3, seg=idx&7;
      *(int4v*)&A_s[r][seg*8] = *(const int4v*)&Ab[(size_t)(row0+r)*256 + kt + seg*8];
    }
#pragma unroll 8
    for(int kk=0;kk<32;++kk){
      int k=kh*32+kk;
      B_s[nB][k]=Bb[(size_t)(kt+k)*256 + col0 + nB];
    }
    __syncthreads();
#pragma unroll
    for(int ks=0;ks<64;ks+=32){
      bf16x8 am[4], bn[4];
#pragma unroll
      for(int m=0;m<4;++m) am[m]=*(const bf16x8*)&A_s[wr*64+m*16+l15][ks+l4*8];
#pragma unroll
      for(int n=0;n<4;++n) bn[n]=*(const bf16x8*)&B_s[wc*64+n*16+l15][ks+l4*8];
#pragma unroll
      for(int m=0;m<4;++m)
#pragma unroll
        for(int n=0;n<4;++n)
          acc[m][n]=__builtin_amdgcn_mfma_f32_16x16x32_bf16(am[m],bn[n],acc[m][n],0,0,0);
    }
    __syncthreads();
  }
#pragma unroll
  for(int m=0;m<4;++m){
#pragma unroll
    for(int n=0;n<4;++n){
#pragma unroll
      for(int r=0;r<4;++r){
        int row=row0+wr*64+m*16+l4*4+r;
        int col=col0+wc*64+n*16+l15;
        size_t off=(size_t)row*256+col;
        float a0; { unsigned short u=(unsigned short)Ab[off]; unsigned int v=((unsigned int)u)<<16; a0=__int_as_float((int)v); }
        store_out(&Cb[off], alpha*acc[m][n][r]+beta*a0);
      }
    }
  }
}

// ---------------- k_Eout_mfma: newE(f32) @ W_Eout (MFMA) -> relu*emask + E -> LN -> new_E ----------------
// grid 1024 blocks (b=blk>>8, i=blk&255; 256 rows each), 4 waves; wave does 16-row chunks.
// A-frag: lane(l15,l4) reads newE[(p0+l15)*64 + ks*32 + l4*8 .. +8] (f32 -> bf16).
// B-frag: W_Eout^T in registers (8 frags, loaded once). C/D: col=l15, row=l4*4+reg.
__global__ void __launch_bounds__(256) k_Eout_mfma(const float* newE_in, const float* E,
                       const int* nm, const float* W_Eout, const float* ge, const float* be,
                       float* outE){
  const int t=threadIdx.x;
  const int lane=t&63, w=t>>6;
  const int l15=lane&15, l4=lane>>4;
  const int blk=blockIdx.x;
  const int b=blk>>8, i=blk&255;
  const float mi=(float)nm[b*cN+i];
  // B fragments (W^T): lane holds col=n*16+l15, k=ks*32+l4*8+ii
  bf16x8 bnf[2][4];
#pragma unroll
  for(int ks=0;ks<2;++ks)
#pragma unroll
    for(int n=0;n<4;++n){
      bf16x8 v;
#pragma unroll
      for(int ii=0;ii<8;++ii)
        v[ii]=f2bs(W_Eout[(ks*32+l4*8+ii)*cDE + n*16+l15]);
      bnf[ks][n]=v;
    }
  float gev[4], bev[4];
#pragma unroll
  for(int n=0;n<4;++n){ gev[n]=ge[n*16+l15]; bev[n]=be[n*16+l15]; }

  for(int it=0;it<4;++it){
    const int j0=it*64+w*16;
    const int p0=blk*256 + j0;          // row = b*65536 + i*256 + j0
    f32x4 acc[4];
#pragma unroll
    for(int n=0;n<4;++n) acc[n]=(f32x4){0.f,0.f,0.f,0.f};
    if(mi>0.f){
#pragma unroll
      for(int ks=0;ks<2;++ks){
        const float* ap=&newE_in[(size_t)(p0+l15)*cDE + ks*32 + l4*8];
        float4 a0=*(const float4*)ap;
        float4 a1=*(const float4*)(ap+4);
        bf16x8 am;
        am[0]=f2bs(a0.x); am[1]=f2bs(a0.y); am[2]=f2bs(a0.z); am[3]=f2bs(a0.w);
        am[4]=f2bs(a1.x); am[5]=f2bs(a1.y); am[6]=f2bs(a1.z); am[7]=f2bs(a1.w);
#pragma unroll
        for(int n=0;n<4;++n)
          acc[n]=__builtin_amdgcn_mfma_f32_16x16x32_bf16(am,bnf[ks][n],acc[n],0,0,0);
      }
    }
    float mj[4];
#pragma unroll
    for(int r=0;r<4;++r) mj[r]=mi*(float)nm[b*cN + j0 + l4*4 + r];
#pragma unroll
    for(int reg=0;reg<4;++reg){
      size_t rowoff=(size_t)(p0 + l4*4 + reg)*cDE;
      float v0=fmaxf(acc[0][reg],0.f)*mj[reg]+E[rowoff + 0*16+l15];
      float v1=fmaxf(acc[1][reg],0.f)*mj[reg]+E[rowoff + 1*16+l15];
      float v2=fmaxf(acc[2][reg],0.f)*mj[reg]+E[rowoff + 2*16+l15];
      float v3=fmaxf(acc[3][reg],0.f)*mj[reg]+E[rowoff + 3*16+l15];
      float s=v0+v1+v2+v3;
      float q=v0*v0+v1*v1+v2*v2+v3*v3;
#pragma unroll
      for(int m=1;m<16;m<<=1){ s+=__shfl_xor(s,m); q+=__shfl_xor(q,m); }
      float mean=s*(1.f/cDE);
      float var=q*(1.f/cDE)-mean*mean;
      float inv=rsqrtf(var+1e-6f);
      outE[rowoff + 0*16+l15]=(v0-mean)*inv*gev[0]+bev[0];
      outE[rowoff + 1*16+l15]=(v1-mean)*inv*gev[1]+bev[1];
      outE[rowoff + 2*16+l15]=(v2-mean)*inv*gev[2]+bev[2];
      outE[rowoff + 3*16+l15]=(v3-mean)*inv*gev[3]+bev[3];
    }
  }
}

// ---------------- fused aG-softmax partials (2-way k-split, no spills) ----------------
__global__ void __launch_bounds__(256) k_Gaccum(const float* E, const int* nm,
                                                const float* G_kernel,
                                                float* Npart, float* Dpart){
  int chunk=blockIdx.x; // 256 chunks of 256 p-rows
  int kh=blockIdx.y;    // 2
  int b=blockIdx.z;     // 4
  int t=threadIdx.x;    // 256
  int dq=t&3;
  int kk=t>>2;          // 0..63
  int k=kh*64+kk;
  float gk[16];
#pragma unroll
  for(int d=0;d<16;++d) gk[d]=G_kernel[(dq*16+d)*128 + k];
  float acc[16];
#pragma unroll
  for(int d=0;d<16;++d) acc[d]=0.f;
  float den=0.f;
  __shared__ float em[16][cDE];
  __shared__ float mrow[16];
  const size_t ebase=((size_t)b)<<16;
  int base=chunk*256;
  const int srr=t>>4;   // staging row 0..15
  const int sds=t&15;   // staging float4 segment
  for(int s=0;s<16;++s){
    int p0=base+16*s;
    __syncthreads();
    {
      int pp=p0+srr;
      float m=(float)(nm[b*cN+(pp>>8)]*nm[b*cN+(pp&255)]);
      float4 v=*(const float4*)&E[(ebase+pp)*cDE + sds*4];
      v.x*=m; v.y*=m; v.z*=m; v.w*=m;
      *(float4*)&em[srr][sds*4]=v;
      if(sds==0) mrow[srr]=m;
    }
    __syncthreads();
#pragma unroll
    for(int rr=0;rr<16;++rr){
      if(mrow[rr]<=0.f) continue;   // wave-uniform skip
      float r[16];
#pragma unroll
      for(int d=0;d<16;++d) r[d]=em[rr][dq*16+d];
      float pd=0.f;
#pragma unroll
      for(int d=0;d<16;++d) pd+=r[d]*gk[d];
      pd+=__shfl_xor(pd,1); pd+=__shfl_xor(pd,2);
      float w=__expf(pd*0.125f);
      den+=w;
#pragma unroll
      for(int d=0;d<16;++d) acc[d]+=w*r[d];
    }
  }
  size_t pi=(size_t)b*256+chunk;
  float* np=Npart + pi*128*cDE;
#pragma unroll
  for(int d=0;d<16;++d) np[(size_t)k*cDE + dq*16+d]=acc[d];
  if(dq==0) Dpart[pi*128+k]=den;
}

// ---------------- combine partials -> Genc[b, k*64+d] ----------------
__global__ void k_Gcombine(const float* Npart, const float* Dpart, float* Genc){
  int bk=blockIdx.x; int b=bk>>7; int k=bk&127;
  int d=threadIdx.x; // 64
  float n=0.f, dd=0.f;
  for(int pi=0;pi<256;++pi){
    size_t base=((size_t)b*256+pi)*128+k;
    n += Npart[base*cDE+d];
    dd += Dpart[base];
  }
  Genc[(size_t)b*8192 + k*cDE + d]=n/dd;
}

// ---------------- aX softmax + X_enc[b, k*256+d] ----------------
__global__ void k_Xenc(const float* X, const int* nm, const float* X_kernel, float* Xenc){
  int k=blockIdx.x;  // 64
  int b=blockIdx.y;  // 4
  int n=threadIdx.x; // 256
  float m=(float)nm[b*cN+n];
  const float* xr=X+((size_t)b*cN+n)*cDX;
  float acc=0.f;
  for(int c=0;c<cDX;++c) acc += xr[c]*X_kernel[c*64+k];
  float lg=(m>0.f)?acc*(1.f/16.f):-1e9f;
  __shared__ float red[256];
  red[n]=lg; __syncthreads();
  for(int st=128;st>0;st>>=1){ if(n<st) red[n]=fmaxf(red[n],red[n+st]); __syncthreads(); }
  float mx=red[0]; __syncthreads();
  float e=__expf(lg-mx);
  red[n]=e; __syncthreads();
  for(int st=128;st>0;st>>=1){ if(n<st) red[n]+=red[n+st]; __syncthreads(); }
  float denom=red[0]; __syncthreads();
  __shared__ float ps[256];
  ps[n]=e/denom;  // exactly 0 for masked rows
  __syncthreads();
  int d=n;
  float s=0.f;
  for(int nn=0;nn<cN;++nn) s += ps[nn]*X[((size_t)b*cN+nn)*cDX+d];
  Xenc[(size_t)b*16384 + k*cDX + d]=s;
}

// ---------------- head weight-streaming partials ----------------
__global__ void __launch_bounds__(256) k_headA(const float* Genc, const float* Xenc,
                        const float* W_Gtrans, const float* W_Xtrans,
                        float* Gp, float* Xp){
  int blk=blockIdx.x;
  int t=threadIdx.x;
  int o=t&127, sub=t>>7;
  int b0=sub*2, b1=sub*2+1;
  __shared__ float ash[4][128];
  if(blk<64){
    int ch=blk;
    for(int l=t;l<512;l+=256){
      int b=l>>7, q=l&127;
      ash[b][q]=Genc[(size_t)b*8192 + ch*128 + q];
    }
    __syncthreads();
    const float* wbase=W_Gtrans + (size_t)ch*128*cDY + o;
    float a0=0.f, a1=0.f;
#pragma unroll 4
    for(int qq=0;qq<128;++qq){
      float w=wbase[(size_t)qq*cDY];
      a0+=ash[b0][qq]*w; a1+=ash[b1][qq]*w;
    }
    Gp[((size_t)b0*64+ch)*cDY+o]=a0;
    Gp[((size_t)b1*64+ch)*cDY+o]=a1;
  } else {
    int ch=blk-64;
    for(int l=t;l<512;l+=256){
      int b=l>>7, q=l&127;
      ash[b][q]=Xenc[(size_t)b*16384 + ch*128 + q];
    }
    __syncthreads();
    const float* wbase=W_Xtrans + (size_t)ch*128*cDY + o;
    float a0=0.f, a1=0.f;
#pragma unroll 4
    for(int qq=0;qq<128;++qq){
      float w=wbase[(size_t)qq*cDY];
      a0+=ash[b0][qq]*w; a1+=ash[b1][qq]*w;
    }
    Xp[((size_t)b0*128+ch)*cDY+o]=a0;
    Xp[((size_t)b1*128+ch)*cDY+o]=a1;
  }
}

// ---------------- head final -> new_y (f32) ----------------
__global__ void k_headB(const float* Gp, const float* Xp, const float* W_yout,
                        const float* y, const float* gy, const float* by, float* newy){
  int b=blockIdx.x; int o=threadIdx.x; // 128
  float g=0.f,x=0.f;
  for(int ch=0;ch<64;++ch)  g+=Gp[((size_t)b*64+ch)*cDY+o];
  for(int ch=0;ch<128;++ch) x+=Xp[((size_t)b*128+ch)*cDY+o];
  __shared__ float srow[cDY];
  srow[o]=fmaxf(g,0.f)+fmaxf(x,0.f);
  __syncthreads();
  float h=0.f;
  for(int r=0;r<cDY;++r) h += srow[r]*W_yout[r*cDY+o];
  float v=fmaxf(h,0.f)+y[b*cDY+o];
  __shared__ float red[cDY];
  red[o]=v; __syncthreads();
  for(int st=64;st>0;st>>=1){ if(o<st) red[o]+=red[o+st]; __syncthreads(); }
  float mean=red[0]*(1.f/cDY); __syncthreads();
  float dv=v-mean;
  red[o]=dv*dv; __syncthreads();
  for(int st=64;st>0;st>>=1){ if(o<st) red[o]+=red[o+st]; __syncthreads(); }
  float var=red[0]*(1.f/cDY);
  newy[b*cDY+o]=dv*rsqrtf(var+1e-6f)*gy[o]+by[o];
}

extern "C" void kernel_launch(void* const* d_in, const int* in_sizes, int n_in,
                              void* d_out, int out_size, void* d_ws, size_t ws_size,
                              hipStream_t stream){
  const float* X     =(const float*)d_in[0];
  const float* E     =(const float*)d_in[1];
  const float* y     =(const float*)d_in[2];
  const int*   nm    =(const int*)  d_in[3];
  const float* W_emax=(const float*)d_in[4];
  const float* W_x1  =(const float*)d_in[5];
  const float* Wq    =(const float*)d_in[6];
  const float* Wk    =(const float*)d_in[7];
  const float* Wv    =(const float*)d_in[8];
  const float* Wo    =(const float*)d_in[9];
  const float* W_y2  =(const float*)d_in[10];
  const float* W_x2  =(const float*)d_in[11];
  const float* Wc    =(const float*)d_in[12];
  const float* bc    =(const float*)d_in[13];
  const float* salpha=(const float*)d_in[14];
  const float* W_Eout=(const float*)d_in[15];
  const float* G_kern=(const float*)d_in[16];
  const float* X_kern=(const float*)d_in[17];
  const float* W_Gtr =(const float*)d_in[18];
  const float* W_Xtr =(const float*)d_in[19];
  const float* W_yout=(const float*)d_in[20];
  const float* gx    =(const float*)d_in[21];
  const float* bx    =(const float*)d_in[22];
  const float* ge    =(const float*)d_in[23];
  const float* be    =(const float*)d_in[24];
  const float* gy    =(const float*)d_in[25];
  const float* by    =(const float*)d_in[26];

  char* wsb=(char*)d_ws;
  bf16* Gbf=(bf16*)wsb;
  bf16* Bbf=(bf16*)(wsb+33554432);
  float* Npart=(float*)(wsb+33554432);   // aliases Bbf (dead after poly2); 33.5 MB exact
  float* f32=(float*)(wsb+67108864);
  float* sim  = f32+F_SIM;
  float* P    = f32+F_P;
  float* Dpart= f32+F_NP;
  float* Gp   = f32+F_GP;
  float* Xp   = f32+F_XP;
  float* S    = f32+F_S;
  float* eenc = f32+F_EENC;
  float* xplus= f32+F_XPL;
  float* qb   = f32+F_QB;
  float* kb   = f32+F_KB;
  float* vb   = f32+F_VB;
  float* yw   = f32+F_YW;
  float* xpy  = f32+F_XPY;
  float* coeff= f32+F_COEF;
  float* Genc = f32+F_GENC;
  float* Xenc = f32+F_XENC;

  float* out=(float*)d_out;          // reference outputs are float32
  float* newX=out;                   // [0, 262144)
  float* newE_out=out+262144;        // [262144, 17039360) — also stages pre-Eout NEWE
  float* newy=out+17039360;          // [17039360, 17039872)

  k_coeff_yw<<<cB,256,0,stream>>>(y,Wc,bc,W_y2,coeff,yw);
  k_reduceE<<<cB*cN,dim3(64,4),0,stream>>>(E,nm,S);
  k_eenc<<<cB*cN,256,0,stream>>>(S,W_emax,nm,eenc);
  k_xplus<<<cB*cN,256,0,stream>>>(X,eenc,W_x1,nm,xplus);
  k_qkv<<<cB*cN,256,0,stream>>>(xplus,Wq,Wk,Wv,qb,kb,vb);
  k_attn_softmax<<<cB*cNH*cN,256,0,stream>>>(qb,kb,nm,P);
  k_attn_out<<<cB*cN,256,0,stream>>>(P,vb,Wo,X,nm,gx,bx,newX);
  k_xplusy<<<cB*cN,256,0,stream>>>(X,yw,W_x2,xpy);
  k_sim<<<dim3(16,16,cB),dim3(16,16),0,stream>>>(xpy,sim);
  k_G<<<cB*cN,256,0,stream>>>(E,sim,nm,salpha,Gbf);
  // Bbf = c0*(G@G) + c1*G ; NEWE = G@Bbf + c2*G  (staged f32 in d_out new_E slot)
  k_bmm_mfma<bf16><<<dim3(2,2,cB*cDE),256,0,stream>>>(Gbf,Gbf,Bbf,coeff,0,1);
  k_bmm_mfma<float><<<dim3(2,2,cB*cDE),256,0,stream>>>(Gbf,Bbf,newE_out,coeff,-1,2);
  k_Eout_mfma<<<1024,256,0,stream>>>(newE_out,E,nm,W_Eout,ge,be,newE_out);
  k_Gaccum<<<dim3(256,2,cB),256,0,stream>>>(E,nm,G_kern,Npart,Dpart);
  k_Gcombine<<<cB*128,64,0,stream>>>(Npart,Dpart,Genc);
  k_Xenc<<<dim3(64,cB),256,0,stream>>>(X,nm,X_kern,Xenc);
  k_headA<<<192,256,0,stream>>>(Genc,Xenc,W_Gtr,W_Xtr,Gp,Xp);
  k_headB<<<cB,128,0,stream>>>(Gp,Xp,W_yout,y,gy,by,newy);
}

// Round 9
// 424.681 us; speedup vs baseline: 3.9261x; 1.2082x over previous
//
#include <hip/hip_runtime.h>
#include <hip/hip_bf16.h>

typedef __hip_bfloat16 bf16;
__device__ __forceinline__ bf16 tobf(float v){ return __float2bfloat16(v); }
__device__ __forceinline__ float frombf(bf16 v){ return __bfloat162float(v); }
__device__ __forceinline__ short f2bs(float x){ bf16 h=tobf(x); return *reinterpret_cast<short*>(&h); }

typedef __attribute__((ext_vector_type(8))) short bf16x8;
typedef __attribute__((ext_vector_type(4))) short short4v;
typedef __attribute__((ext_vector_type(4))) float f32x4;
typedef __attribute__((ext_vector_type(4))) int int4v;

static constexpr int cB=4, cN=256, cDX=256, cDE=64, cDY=128, cNH=8, cDF=32;

// ---- workspace layout ----
static constexpr size_t F_SIM  = 0;
static constexpr size_t F_P    = 262144;
static constexpr size_t F_NP   = 2359296;  // Dpart [0,65536), Gp/Xp at +1048576
static constexpr size_t F_GP   = F_NP + 1048576;
static constexpr size_t F_XP   = F_NP + 1048576 + 32768;
static constexpr size_t F_S    = 6619136;
static constexpr size_t F_EENC = 6684672;
static constexpr size_t F_XPL  = 6946816;
static constexpr size_t F_QB   = 7208960;
static constexpr size_t F_KB   = 7471104;
static constexpr size_t F_VB   = 7733248;
static constexpr size_t F_YW   = 7995392;
static constexpr size_t F_XPY  = 7996416;
static constexpr size_t F_COEF = 8258560;
static constexpr size_t F_GENC = 8258576;
static constexpr size_t F_XENC = 8291344;

// ---------------- coeff = y@Wc+bc ; yw = relu(y@W_y2) ----------------
__global__ void k_coeff_yw(const float* y, const float* Wc, const float* bc,
                           const float* W_y2, float* coeff, float* yw){
  int b = blockIdx.x; int f = threadIdx.x; // 256
  float acc = 0.f;
  for(int r=0;r<cDY;++r) acc += y[b*cDY+r]*W_y2[r*cDX+f];
  yw[b*cDX+f] = fmaxf(acc,0.f);
  if (f < 3){
    float c = bc[f];
    for(int r=0;r<cDY;++r) c += y[b*cDY+r]*Wc[r*3+f];
    coeff[b*3+f] = c;
  }
}

// ---------------- S[b,i,d] = sum_j E[b,i,j,d]*m_j ----------------
__global__ void k_reduceE(const float* E, const int* nm, float* S){
  int bi = blockIdx.x; int b = bi / cN;
  int d = threadIdx.x;  // 64
  int jy = threadIdx.y; // 4
  const float* Eb = E + (size_t)bi*cN*cDE;
  float acc = 0.f;
  for(int j=jy;j<cN;j+=4){
    acc += Eb[j*cDE+d] * (float)nm[b*cN+j];
  }
  __shared__ float red[4][64];
  red[jy][d]=acc; __syncthreads();
  if (jy==0) S[(size_t)bi*cDE+d] = red[0][d]+red[1][d]+red[2][d]+red[3][d];
}

// ---------------- e_enc[b,i,f] = relu(m_i/N * S[b,i,:]@W_emax[:,f]) ----------------
__global__ void k_eenc(const float* S, const float* W_emax, const int* nm, float* eenc){
  int bi = blockIdx.x; int b = bi/cN; int i = bi%cN;
  int f = threadIdx.x;
  __shared__ float s[cDE];
  if (f<cDE) s[f]=S[(size_t)bi*cDE+f];
  __syncthreads();
  float acc=0.f;
  for(int d=0;d<cDE;++d) acc += s[d]*W_emax[d*cDX+f];
  float mi=(float)nm[b*cN+i];
  eenc[(size_t)bi*cDX+f] = fmaxf(acc*mi*(1.f/cN), 0.f);
}

// ---------------- xplus = (X + relu(eenc@W_x1)) * m_i ----------------
__global__ void k_xplus(const float* X, const float* eenc, const float* W_x1,
                        const int* nm, float* xplus){
  int bi=blockIdx.x; int b=bi/cN; int i=bi%cN;
  int f=threadIdx.x;
  __shared__ float row[cDX];
  row[f]=eenc[(size_t)bi*cDX+f];
  __syncthreads();
  float acc=0.f;
  for(int c=0;c<cDX;++c) acc += row[c]*W_x1[c*cDX+f];
  float mi=(float)nm[b*cN+i];
  xplus[(size_t)bi*cDX+f] = (X[(size_t)bi*cDX+f] + fmaxf(acc,0.f))*mi;
}

// ---------------- q,k,v projections ----------------
__global__ void k_qkv(const float* xplus, const float* Wq, const float* Wk, const float* Wv,
                      float* qb, float* kb, float* vb){
  int bi=blockIdx.x; int f=threadIdx.x;
  __shared__ float row[cDX];
  row[f]=xplus[(size_t)bi*cDX+f];
  __syncthreads();
  float aq=0,ak=0,av=0;
  for(int c=0;c<cDX;++c){ float r=row[c]; aq+=r*Wq[c*cDX+f]; ak+=r*Wk[c*cDX+f]; av+=r*Wv[c*cDX+f]; }
  qb[(size_t)bi*cDX+f]=aq; kb[(size_t)bi*cDX+f]=ak; vb[(size_t)bi*cDX+f]=av;
}

// ---------------- attention softmax rows -> P[b,h,i,j] ----------------
__global__ void k_attn_softmax(const float* qb, const float* kb, const int* nm, float* P){
  int id=blockIdx.x; int b=id/(cNH*cN); int rem=id%(cNH*cN); int h=rem/cN; int i=rem%cN;
  int j=threadIdx.x;
  __shared__ float qrow[cDF];
  if (j<cDF) qrow[j]=qb[((size_t)b*cN+i)*cDX + h*cDF + j];
  __syncthreads();
  const float* krow = kb + ((size_t)b*cN+j)*cDX + h*cDF;
  float s=0.f;
  for(int c=0;c<cDF;++c) s += qrow[c]*krow[c];
  s *= 0.17677669529663687f; // 1/sqrt(32)
  float val = (nm[b*cN+j]>0) ? s : -1e9f;
  __shared__ float red[256];
  red[j]=val; __syncthreads();
  for(int st=128;st>0;st>>=1){ if(j<st) red[j]=fmaxf(red[j],red[j+st]); __syncthreads(); }
  float mx=red[0]; __syncthreads();
  float e=__expf(val-mx);
  red[j]=e; __syncthreads();
  for(int st=128;st>0;st>>=1){ if(j<st) red[j]+=red[j+st]; __syncthreads(); }
  float denom=red[0];
  P[(size_t)id*cN + j] = e/denom;
}

// ---------------- P@V, @Wo, *mask, +X, LayerNorm -> new_X (f32) ----------------
__global__ void k_attn_out(const float* P, const float* vb, const float* Wo,
                           const float* X, const int* nm, const float* gx, const float* bx,
                           float* newX){
  int bi=blockIdx.x; int b=bi/cN; int i=bi%cN;
  int t=threadIdx.x;
  __shared__ float p8[cNH][cN];
  for(int h=0;h<cNH;++h) p8[h][t]=P[(((size_t)b*cNH+h)*cN+i)*cN + t];
  __syncthreads();
  int h=t/cDF;
  float acc=0.f;
  for(int j=0;j<cN;++j) acc += p8[h][j]*vb[((size_t)b*cN+j)*cDX + t];
  __shared__ float arow[cDX];
  arow[t]=acc; __syncthreads();
  float o=0.f;
  for(int c=0;c<cDX;++c) o += arow[c]*Wo[c*cDX+t];
  float mi=(float)nm[b*cN+i];
  float v = o*mi + X[(size_t)bi*cDX+t];
  __shared__ float red[256];
  red[t]=v; __syncthreads();
  for(int st=128;st>0;st>>=1){ if(t<st) red[t]+=red[t+st]; __syncthreads(); }
  float mean=red[0]*(1.f/cDX); __syncthreads();
  float dv=v-mean;
  red[t]=dv*dv; __syncthreads();
  for(int st=128;st>0;st>>=1){ if(t<st) red[t]+=red[t+st]; __syncthreads(); }
  float var=red[0]*(1.f/cDX);
  newX[(size_t)bi*cDX+t]=dv*rsqrtf(var+1e-6f)*gx[t]+bx[t];
}

// ---------------- xplusy = relu((X + yw)@W_x2) ----------------
__global__ void k_xplusy(const float* X, const float* yw, const float* W_x2, float* xpy){
  int bi=blockIdx.x; int b=bi/cN;
  int f=threadIdx.x;
  __shared__ float row[cDX];
  row[f]=X[(size_t)bi*cDX+f]+yw[b*cDX+f];
  __syncthreads();
  float acc=0.f;
  for(int c=0;c<cDX;++c) acc += row[c]*W_x2[c*cDX+f];
  xpy[(size_t)bi*cDX+f]=fmaxf(acc,0.f);
}

// ---------------- sim = xpy @ xpy^T / 16 ----------------
__global__ void k_sim(const float* xp, float* sim){
  int b=blockIdx.z;
  int tx=threadIdx.x, ty=threadIdx.y;
  __shared__ float Aa[16][17], Bb[16][17];
  const float* base = xp + (size_t)b*cN*cDX;
  float acc=0.f;
  for(int kt=0;kt<cDX;kt+=16){
    Aa[ty][tx]=base[(size_t)(blockIdx.y*16+ty)*cDX + kt+tx];
    Bb[ty][tx]=base[(size_t)(blockIdx.x*16+ty)*cDX + kt+tx];
    __syncthreads();
    for(int c=0;c<16;++c) acc += Aa[ty][c]*Bb[tx][c];
    __syncthreads();
  }
  sim[((size_t)b*cN + blockIdx.y*16+ty)*cN + blockIdx.x*16+tx] = acc*(1.f/16.f);
}

// ---------------- G = (alpha*sim + E) * emask  (bf16 out) ----------------
__global__ void k_G(const float* E, const float* sim, const int* nm, const float* alpha_p,
                    bf16* G){
  int bi=blockIdx.x; int b=bi/cN; int i=bi%cN;
  float mi=(float)nm[b*cN+i];
  float alpha=alpha_p[0];
  size_t base=(size_t)bi*cN*cDE;
  for(int t=threadIdx.x;t<cN*cDE;t+=blockDim.x){
    int j=t>>6;
    float mj=(float)nm[b*cN+j];
    G[base+t]=tobf((alpha*sim[(size_t)bi*cN+j]+E[base+t])*mi*mj);
  }
}

__device__ __forceinline__ void store_out(bf16* p, float v){ *p = tobf(v); }
__device__ __forceinline__ void store_out(float* p, float v){ *p = v; }

// ---------------- batched 256x256 MFMA GEMM: C = alpha*(A@B) + beta*A ----------------
template<typename OT>
__global__ void __launch_bounds__(256) k_bmm_mfma(const bf16* A, const bf16* Bm, OT* C,
                                                  const float* coeff, int ia, int ib){
  int bc=blockIdx.z; int b=bc>>6;
  float alpha=(ia>=0)?coeff[b*3+ia]:1.0f;
  float beta=coeff[b*3+ib];
  const short* Ab=(const short*)(A+(size_t)bc*65536);
  const short* Bb=(const short*)(Bm+(size_t)bc*65536);
  OT* Cb=C+(size_t)bc*65536;
  const int row0=blockIdx.y*128, col0=blockIdx.x*128;
  const int t=threadIdx.x;
  const int lane=t&63, w=t>>6;
  const int wr=w>>1, wc=w&1;
  const int l15=lane&15, l4=lane>>4;
  __shared__ short A_s[128][72];
  __shared__ short B_s[128][72];   // B transposed: [n][k]
  f32x4 acc[4][4];
#pragma unroll
  for(int m=0;m<4;++m)
#pragma unroll
    for(int n=0;n<4;++n) acc[m][n]=(f32x4){0.f,0.f,0.f,0.f};

  const int kh=t>>7;
  const int nB=t&127;
  for(int kt=0;kt<256;kt+=64){
#pragma unroll
    for(int l=0;l<4;++l){
      int idx=t+l*256;
      int r=idx>>3, seg=idx&7;
      *(int4v*)&A_s[r][seg*8] = *(const int4v*)&Ab[(size_t)(row0+r)*256 + kt + seg*8];
    }
#pragma unroll 8
    for(int kk=0;kk<32;++kk){
      int k=kh*32+kk;
      B_s[nB][k]=Bb[(size_t)(kt+k)*256 + col0 + nB];
    }
    __syncthreads();
#pragma unroll
    for(int ks=0;ks<64;ks+=32){
      bf16x8 am[4], bn[4];
#pragma unroll
      for(int m=0;m<4;++m) am[m]=*(const bf16x8*)&A_s[wr*64+m*16+l15][ks+l4*8];
#pragma unroll
      for(int n=0;n<4;++n) bn[n]=*(const bf16x8*)&B_s[wc*64+n*16+l15][ks+l4*8];
#pragma unroll
      for(int m=0;m<4;++m)
#pragma unroll
        for(int n=0;n<4;++n)
          acc[m][n]=__builtin_amdgcn_mfma_f32_16x16x32_bf16(am[m],bn[n],acc[m][n],0,0,0);
    }
    __syncthreads();
  }
#pragma unroll
  for(int m=0;m<4;++m){
#pragma unroll
    for(int n=0;n<4;++n){
#pragma unroll
      for(int r=0;r<4;++r){
        int row=row0+wr*64+m*16+l4*4+r;
        int col=col0+wc*64+n*16+l15;
        size_t off=(size_t)row*256+col;
        float a0; { unsigned short u=(unsigned short)Ab[off]; unsigned int v=((unsigned int)u)<<16; a0=__int_as_float((int)v); }
        store_out(&Cb[off], alpha*acc[m][n][r]+beta*a0);
      }
    }
  }
}

// ---------------- k_Eout_mfma ----------------
__global__ void __launch_bounds__(256) k_Eout_mfma(const float* newE_in, const float* E,
                       const int* nm, const float* W_Eout, const float* ge, const float* be,
                       float* outE){
  const int t=threadIdx.x;
  const int lane=t&63, w=t>>6;
  const int l15=lane&15, l4=lane>>4;
  const int blk=blockIdx.x;
  const int b=blk>>8, i=blk&255;
  const float mi=(float)nm[b*cN+i];
  bf16x8 bnf[2][4];
#pragma unroll
  for(int ks=0;ks<2;++ks)
#pragma unroll
    for(int n=0;n<4;++n){
      bf16x8 v;
#pragma unroll
      for(int ii=0;ii<8;++ii)
        v[ii]=f2bs(W_Eout[(ks*32+l4*8+ii)*cDE + n*16+l15]);
      bnf[ks][n]=v;
    }
  float gev[4], bev[4];
#pragma unroll
  for(int n=0;n<4;++n){ gev[n]=ge[n*16+l15]; bev[n]=be[n*16+l15]; }

  for(int it=0;it<4;++it){
    const int j0=it*64+w*16;
    const int p0=blk*256 + j0;
    f32x4 acc[4];
#pragma unroll
    for(int n=0;n<4;++n) acc[n]=(f32x4){0.f,0.f,0.f,0.f};
    if(mi>0.f){
#pragma unroll
      for(int ks=0;ks<2;++ks){
        const float* ap=&newE_in[(size_t)(p0+l15)*cDE + ks*32 + l4*8];
        float4 a0=*(const float4*)ap;
        float4 a1=*(const float4*)(ap+4);
        bf16x8 am;
        am[0]=f2bs(a0.x); am[1]=f2bs(a0.y); am[2]=f2bs(a0.z); am[3]=f2bs(a0.w);
        am[4]=f2bs(a1.x); am[5]=f2bs(a1.y); am[6]=f2bs(a1.z); am[7]=f2bs(a1.w);
#pragma unroll
        for(int n=0;n<4;++n)
          acc[n]=__builtin_amdgcn_mfma_f32_16x16x32_bf16(am,bnf[ks][n],acc[n],0,0,0);
      }
    }
    float mj[4];
#pragma unroll
    for(int r=0;r<4;++r) mj[r]=mi*(float)nm[b*cN + j0 + l4*4 + r];
#pragma unroll
    for(int reg=0;reg<4;++reg){
      size_t rowoff=(size_t)(p0 + l4*4 + reg)*cDE;
      float v0=fmaxf(acc[0][reg],0.f)*mj[reg]+E[rowoff + 0*16+l15];
      float v1=fmaxf(acc[1][reg],0.f)*mj[reg]+E[rowoff + 1*16+l15];
      float v2=fmaxf(acc[2][reg],0.f)*mj[reg]+E[rowoff + 2*16+l15];
      float v3=fmaxf(acc[3][reg],0.f)*mj[reg]+E[rowoff + 3*16+l15];
      float s=v0+v1+v2+v3;
      float q=v0*v0+v1*v1+v2*v2+v3*v3;
#pragma unroll
      for(int m=1;m<16;m<<=1){ s+=__shfl_xor(s,m); q+=__shfl_xor(q,m); }
      float mean=s*(1.f/cDE);
      float var=q*(1.f/cDE)-mean*mean;
      float inv=rsqrtf(var+1e-6f);
      outE[rowoff + 0*16+l15]=(v0-mean)*inv*gev[0]+bev[0];
      outE[rowoff + 1*16+l15]=(v1-mean)*inv*gev[1]+bev[1];
      outE[rowoff + 2*16+l15]=(v2-mean)*inv*gev[2]+bev[2];
      outE[rowoff + 3*16+l15]=(v3-mean)*inv*gev[3]+bev[3];
    }
  }
}

// ---------------- k_Gaccum_mfma: aG-softmax partials via two MFMA GEMMs ----------------
// grid (128 chunks, 4 b); block loops 4 sub-chunks of 128 p-rows.
// GEMM1: logits[p][k] = Em[p][:]@(G_kernel/8)  (Gk as 16 register B-frags).
// exp+mask in C/D layout -> W^T staged to Wt LDS; per-wave D via shfl(16,32).
// GEMM2: wave owns 32-k slice of N over K=128 p; N-acc persists across sub-chunks.
__global__ void __launch_bounds__(256) k_Gaccum_mfma(const float* E, const int* nm,
                                                     const float* G_kernel,
                                                     float* Npart, float* Dpart){
  const int chunk=blockIdx.x; // 128 chunks x 512 rows
  const int b=blockIdx.y;
  const int t=threadIdx.x;
  const int lane=t&63, w=t>>6;
  const int l15=lane&15, l4=lane>>4;

  __shared__ short EmA[128][72];   // [p][d] bf16
  __shared__ short Wt[128][136];   // [k][p] bf16
  __shared__ float mrow[128];
  __shared__ float Dacc[128];
  __shared__ float Dpar[4][128];

  // Gk B-fragments: [kt(d-half)][n(k-tile)]
  bf16x8 gk[2][8];
#pragma unroll
  for(int kt=0;kt<2;++kt)
#pragma unroll
    for(int n=0;n<8;++n){
      bf16x8 v;
#pragma unroll
      for(int ii=0;ii<8;++ii)
        v[ii]=f2bs(G_kernel[(kt*32+l4*8+ii)*128 + n*16+l15]*0.125f);
      gk[kt][n]=v;
    }

  f32x4 nacc[2][4]; // [a: k-subtile of wave][dt]
#pragma unroll
  for(int a=0;a<2;++a)
#pragma unroll
    for(int d2=0;d2<4;++d2) nacc[a][d2]=(f32x4){0.f,0.f,0.f,0.f};

  if(t<128) Dacc[t]=0.f;
  __syncthreads();

  const size_t ebase=((size_t)b)<<16;
  for(int sub=0;sub<4;++sub){
    const int rowbase = chunk*512 + sub*128;
    // ---- stage EmA (bf16) + mrow ----
    {
      int pr=t>>1, hh=t&1;
      int p=rowbase+pr;
      const float* src=&E[(ebase+p)*cDE + hh*32];
#pragma unroll
      for(int q=0;q<8;++q){
        float4 v=*(const float4*)(src+q*4);
        short4v s4; s4[0]=f2bs(v.x); s4[1]=f2bs(v.y); s4[2]=f2bs(v.z); s4[3]=f2bs(v.w);
        *(short4v*)&EmA[pr][hh*32+q*4]=s4;
      }
      if(hh==0) mrow[pr]=(float)(nm[b*cN+(p>>8)]*nm[b*cN+(p&255)]);
    }
    __syncthreads();

    // ---- GEMM1: W-logits for wave's 32 p-rows x 128 k ----
    f32x4 wacc[2][8];
#pragma unroll
    for(int m=0;m<2;++m)
#pragma unroll
      for(int n=0;n<8;++n) wacc[m][n]=(f32x4){0.f,0.f,0.f,0.f};
#pragma unroll
    for(int kt=0;kt<2;++kt){
      bf16x8 am[2];
#pragma unroll
      for(int m=0;m<2;++m) am[m]=*(const bf16x8*)&EmA[w*32+m*16+l15][kt*32+l4*8];
#pragma unroll
      for(int m=0;m<2;++m)
#pragma unroll
        for(int n=0;n<8;++n)
          wacc[m][n]=__builtin_amdgcn_mfma_f32_16x16x32_bf16(am[m],gk[kt][n],wacc[m][n],0,0,0);
    }
    // ---- exp + mask, D partials, store W^T ----
    float dsum[8];
#pragma unroll
    for(int n=0;n<8;++n) dsum[n]=0.f;
#pragma unroll
    for(int m=0;m<2;++m){
#pragma unroll
      for(int r=0;r<4;++r){
        int pl=w*32+m*16+l4*4+r;
        float mv=mrow[pl];
#pragma unroll
        for(int n=0;n<8;++n){
          float wv=(mv>0.f)?__expf(wacc[m][n][r]):0.f;
          dsum[n]+=wv;
          Wt[n*16+l15][pl]=f2bs(wv);
        }
      }
    }
#pragma unroll
    for(int n=0;n<8;++n){
      float s=dsum[n];
      s+=__shfl_xor(s,16); s+=__shfl_xor(s,32);
      if(l4==0) Dpar[w][n*16+l15]=s;
    }
    __syncthreads();

    // ---- GEMM2: N[k-slice][d] += W^T @ Em over K=128 ----
#pragma unroll
    for(int ks=0;ks<4;++ks){
      bf16x8 aw[2];
#pragma unroll
      for(int a=0;a<2;++a) aw[a]=*(const bf16x8*)&Wt[w*32+a*16+l15][ks*32+l4*8];
      bf16x8 bm[4];
#pragma unroll
      for(int d2=0;d2<4;++d2){
        bf16x8 v;
#pragma unroll
        for(int ii=0;ii<8;++ii) v[ii]=EmA[ks*32+l4*8+ii][d2*16+l15];
        bm[d2]=v;
      }
#pragma unroll
      for(int a=0;a<2;++a)
#pragma unroll
        for(int d2=0;d2<4;++d2)
          nacc[a][d2]=__builtin_amdgcn_mfma_f32_16x16x32_bf16(aw[a],bm[d2],nacc[a][d2],0,0,0);
    }
    __syncthreads();
    if(t<128) Dacc[t]+=Dpar[0][t]+Dpar[1][t]+Dpar[2][t]+Dpar[3][t];
    __syncthreads();
  }

  // ---- write partials ----
  size_t pi=(size_t)b*128+chunk;
  float* np=Npart + pi*128*cDE;
#pragma unroll
  for(int a=0;a<2;++a){
#pragma unroll
    for(int d2=0;d2<4;++d2){
#pragma unroll
      for(int r=0;r<4;++r){
        int k=w*32+a*16+l4*4+r;
        int d=d2*16+l15;
        np[(size_t)k*cDE+d]=nacc[a][d2][r];
      }
    }
  }
  if(t<128) Dpart[pi*128+t]=Dacc[t];
}

// ---------------- combine partials -> Genc[b, k*64+d] ----------------
__global__ void k_Gcombine(const float* Npart, const float* Dpart, float* Genc){
  int bk=blockIdx.x; int b=bk>>7; int k=bk&127;
  int d=threadIdx.x; // 64
  float n=0.f, dd=0.f;
  for(int pi=0;pi<128;++pi){
    size_t base=((size_t)b*128+pi)*128+k;
    n += Npart[base*cDE+d];
    dd += Dpart[base];
  }
  Genc[(size_t)b*8192 + k*cDE + d]=n/dd;
}

// ---------------- aX softmax + X_enc[b, k*256+d] ----------------
__global__ void k_Xenc(const float* X, const int* nm, const float* X_kernel, float* Xenc){
  int k=blockIdx.x;  // 64
  int b=blockIdx.y;  // 4
  int n=threadIdx.x; // 256
  float m=(float)nm[b*cN+n];
  const float* xr=X+((size_t)b*cN+n)*cDX;
  float acc=0.f;
  for(int c=0;c<cDX;++c) acc += xr[c]*X_kernel[c*64+k];
  float lg=(m>0.f)?acc*(1.f/16.f):-1e9f;
  __shared__ float red[256];
  red[n]=lg; __syncthreads();
  for(int st=128;st>0;st>>=1){ if(n<st) red[n]=fmaxf(red[n],red[n+st]); __syncthreads(); }
  float mx=red[0]; __syncthreads();
  float e=__expf(lg-mx);
  red[n]=e; __syncthreads();
  for(int st=128;st>0;st>>=1){ if(n<st) red[n]+=red[n+st]; __syncthreads(); }
  float denom=red[0]; __syncthreads();
  __shared__ float ps[256];
  ps[n]=e/denom;
  __syncthreads();
  int d=n;
  float s=0.f;
  for(int nn=0;nn<cN;++nn) s += ps[nn]*X[((size_t)b*cN+nn)*cDX+d];
  Xenc[(size_t)b*16384 + k*cDX + d]=s;
}

// ---------------- head weight-streaming partials ----------------
__global__ void __launch_bounds__(256) k_headA(const float* Genc, const float* Xenc,
                        const float* W_Gtrans, const float* W_Xtrans,
                        float* Gp, float* Xp){
  int blk=blockIdx.x;
  int t=threadIdx.x;
  int o=t&127, sub=t>>7;
  int b0=sub*2, b1=sub*2+1;
  __shared__ float ash[4][128];
  if(blk<64){
    int ch=blk;
    for(int l=t;l<512;l+=256){
      int b=l>>7, q=l&127;
      ash[b][q]=Genc[(size_t)b*8192 + ch*128 + q];
    }
    __syncthreads();
    const float* wbase=W_Gtrans + (size_t)ch*128*cDY + o;
    float a0=0.f, a1=0.f;
#pragma unroll 4
    for(int qq=0;qq<128;++qq){
      float w=wbase[(size_t)qq*cDY];
      a0+=ash[b0][qq]*w; a1+=ash[b1][qq]*w;
    }
    Gp[((size_t)b0*64+ch)*cDY+o]=a0;
    Gp[((size_t)b1*64+ch)*cDY+o]=a1;
  } else {
    int ch=blk-64;
    for(int l=t;l<512;l+=256){
      int b=l>>7, q=l&127;
      ash[b][q]=Xenc[(size_t)b*16384 + ch*128 + q];
    }
    __syncthreads();
    const float* wbase=W_Xtrans + (size_t)ch*128*cDY + o;
    float a0=0.f, a1=0.f;
#pragma unroll 4
    for(int qq=0;qq<128;++qq){
      float w=wbase[(size_t)qq*cDY];
      a0+=ash[b0][qq]*w; a1+=ash[b1][qq]*w;
    }
    Xp[((size_t)b0*128+ch)*cDY+o]=a0;
    Xp[((size_t)b1*128+ch)*cDY+o]=a1;
  }
}

// ---------------- head final -> new_y (f32) ----------------
__global__ void k_headB(const float* Gp, const float* Xp, const float* W_yout,
                        const float* y, const float* gy, const float* by, float* newy){
  int b=blockIdx.x; int o=threadIdx.x; // 128
  float g=0.f,x=0.f;
  for(int ch=0;ch<64;++ch)  g+=Gp[((size_t)b*64+ch)*cDY+o];
  for(int ch=0;ch<128;++ch) x+=Xp[((size_t)b*128+ch)*cDY+o];
  __shared__ float srow[cDY];
  srow[o]=fmaxf(g,0.f)+fmaxf(x,0.f);
  __syncthreads();
  float h=0.f;
  for(int r=0;r<cDY;++r) h += srow[r]*W_yout[r*cDY+o];
  float v=fmaxf(h,0.f)+y[b*cDY+o];
  __shared__ float red[cDY];
  red[o]=v; __syncthreads();
  for(int st=64;st>0;st>>=1){ if(o<st) red[o]+=red[o+st]; __syncthreads(); }
  float mean=red[0]*(1.f/cDY); __syncthreads();
  float dv=v-mean;
  red[o]=dv*dv; __syncthreads();
  for(int st=64;st>0;st>>=1){ if(o<st) red[o]+=red[o+st]; __syncthreads(); }
  float var=red[0]*(1.f/cDY);
  newy[b*cDY+o]=dv*rsqrtf(var+1e-6f)*gy[o]+by[o];
}

extern "C" void kernel_launch(void* const* d_in, const int* in_sizes, int n_in,
                              void* d_out, int out_size, void* d_ws, size_t ws_size,
                              hipStream_t stream){
  const float* X     =(const float*)d_in[0];
  const float* E     =(const float*)d_in[1];
  const float* y     =(const float*)d_in[2];
  const int*   nm    =(const int*)  d_in[3];
  const float* W_emax=(const float*)d_in[4];
  const float* W_x1  =(const float*)d_in[5];
  const float* Wq    =(const float*)d_in[6];
  const float* Wk    =(const float*)d_in[7];
  const float* Wv    =(const float*)d_in[8];
  const float* Wo    =(const float*)d_in[9];
  const float* W_y2  =(const float*)d_in[10];
  const float* W_x2  =(const float*)d_in[11];
  const float* Wc    =(const float*)d_in[12];
  const float* bc    =(const float*)d_in[13];
  const float* salpha=(const float*)d_in[14];
  const float* W_Eout=(const float*)d_in[15];
  const float* G_kern=(const float*)d_in[16];
  const float* X_kern=(const float*)d_in[17];
  const float* W_Gtr =(const float*)d_in[18];
  const float* W_Xtr =(const float*)d_in[19];
  const float* W_yout=(const float*)d_in[20];
  const float* gx    =(const float*)d_in[21];
  const float* bx    =(const float*)d_in[22];
  const float* ge    =(const float*)d_in[23];
  const float* be    =(const float*)d_in[24];
  const float* gy    =(const float*)d_in[25];
  const float* by    =(const float*)d_in[26];

  char* wsb=(char*)d_ws;
  bf16* Gbf=(bf16*)wsb;
  bf16* Bbf=(bf16*)(wsb+33554432);
  float* Npart=(float*)(wsb+33554432);   // aliases Bbf (dead after poly2); 16.8 MB used
  float* f32=(float*)(wsb+67108864);
  float* sim  = f32+F_SIM;
  float* P    = f32+F_P;
  float* Dpart= f32+F_NP;                // 65536 floats used
  float* Gp   = f32+F_GP;
  float* Xp   = f32+F_XP;
  float* S    = f32+F_S;
  float* eenc = f32+F_EENC;
  float* xplus= f32+F_XPL;
  float* qb   = f32+F_QB;
  float* kb   = f32+F_KB;
  float* vb   = f32+F_VB;
  float* yw   = f32+F_YW;
  float* xpy  = f32+F_XPY;
  float* coeff= f32+F_COEF;
  float* Genc = f32+F_GENC;
  float* Xenc = f32+F_XENC;

  float* out=(float*)d_out;
  float* newX=out;
  float* newE_out=out+262144;
  float* newy=out+17039360;

  k_coeff_yw<<<cB,256,0,stream>>>(y,Wc,bc,W_y2,coeff,yw);
  k_reduceE<<<cB*cN,dim3(64,4),0,stream>>>(E,nm,S);
  k_eenc<<<cB*cN,256,0,stream>>>(S,W_emax,nm,eenc);
  k_xplus<<<cB*cN,256,0,stream>>>(X,eenc,W_x1,nm,xplus);
  k_qkv<<<cB*cN,256,0,stream>>>(xplus,Wq,Wk,Wv,qb,kb,vb);
  k_attn_softmax<<<cB*cNH*cN,256,0,stream>>>(qb,kb,nm,P);
  k_attn_out<<<cB*cN,256,0,stream>>>(P,vb,Wo,X,nm,gx,bx,newX);
  k_xplusy<<<cB*cN,256,0,stream>>>(X,yw,W_x2,xpy);
  k_sim<<<dim3(16,16,cB),dim3(16,16),0,stream>>>(xpy,sim);
  k_G<<<cB*cN,256,0,stream>>>(E,sim,nm,salpha,Gbf);
  k_bmm_mfma<bf16><<<dim3(2,2,cB*cDE),256,0,stream>>>(Gbf,Gbf,Bbf,coeff,0,1);
  k_bmm_mfma<float><<<dim3(2,2,cB*cDE),256,0,stream>>>(Gbf,Bbf,newE_out,coeff,-1,2);
  k_Eout_mfma<<<1024,256,0,stream>>>(newE_out,E,nm,W_Eout,ge,be,newE_out);
  k_Gaccum_mfma<<<dim3(128,cB),256,0,stream>>>(E,nm,G_kern,Npart,Dpart);
  k_Gcombine<<<cB*128,64,0,stream>>>(Npart,Dpart,Genc);
  k_Xenc<<<dim3(64,cB),256,0,stream>>>(X,nm,X_kern,Xenc);
  k_headA<<<192,256,0,stream>>>(Genc,Xenc,W_Gtr,W_Xtr,Gp,Xp);
  k_headB<<<cB,128,0,stream>>>(Gp,Xp,W_yout,y,gy,by,newy);
}

// Round 11
// 416.533 us; speedup vs baseline: 4.0029x; 1.0196x over previous
//
#include <hip/hip_runtime.h>
#include <hip/hip_bf16.h>

typedef __hip_bfloat16 bf16;
__device__ __forceinline__ bf16 tobf(float v){ return __float2bfloat16(v); }
__device__ __forceinline__ float frombf(bf16 v){ return __bfloat162float(v); }
__device__ __forceinline__ short f2bs(float x){ bf16 h=tobf(x); return *reinterpret_cast<short*>(&h); }
__device__ __forceinline__ float bs2f(short s){ unsigned int v=((unsigned int)(unsigned short)s)<<16; return __int_as_float((int)v); }

typedef __attribute__((ext_vector_type(8))) short bf16x8;
typedef __attribute__((ext_vector_type(4))) short short4v;
typedef __attribute__((ext_vector_type(4))) float f32x4;
typedef __attribute__((ext_vector_type(4))) int int4v;

static constexpr int cB=4, cN=256, cDX=256, cDE=64, cDY=128, cNH=8, cDF=32;

// ---- workspace layout (bytes) ----
// [0,   32M)  G    bf16
// [32M, 64M)  Bt2  bf16 (poly1 out, transposed)  -- after poly2: Npart f32 (16.8MB)
// [64M, 96M)  Gt   bf16 (G transposed per slice)
// [96M, ...)  f32 region (offsets in floats below)
static constexpr size_t F_SIM  = 0;
static constexpr size_t F_P    = 262144;
static constexpr size_t F_NP   = 2359296;  // Dpart [0,65536), Gp/Xp at +1048576
static constexpr size_t F_GP   = F_NP + 1048576;
static constexpr size_t F_XP   = F_NP + 1048576 + 32768;
static constexpr size_t F_S    = 6619136;
static constexpr size_t F_EENC = 6684672;
static constexpr size_t F_XPL  = 6946816;
static constexpr size_t F_QB   = 7208960;
static constexpr size_t F_KB   = 7471104;
static constexpr size_t F_VB   = 7733248;
static constexpr size_t F_YW   = 7995392;
static constexpr size_t F_XPY  = 7996416;
static constexpr size_t F_COEF = 8258560;
static constexpr size_t F_GENC = 8258576;
static constexpr size_t F_XENC = 8291344;

// ---------------- coeff = y@Wc+bc ; yw = relu(y@W_y2) ----------------
__global__ void k_coeff_yw(const float* y, const float* Wc, const float* bc,
                           const float* W_y2, float* coeff, float* yw){
  int b = blockIdx.x; int f = threadIdx.x;
  float acc = 0.f;
  for(int r=0;r<cDY;++r) acc += y[b*cDY+r]*W_y2[r*cDX+f];
  yw[b*cDX+f] = fmaxf(acc,0.f);
  if (f < 3){
    float c = bc[f];
    for(int r=0;r<cDY;++r) c += y[b*cDY+r]*Wc[r*3+f];
    coeff[b*3+f] = c;
  }
}

// ---------------- S[b,i,d] = sum_j E[b,i,j,d]*m_j ----------------
__global__ void k_reduceE(const float* E, const int* nm, float* S){
  int bi = blockIdx.x; int b = bi / cN;
  int d = threadIdx.x;
  int jy = threadIdx.y;
  const float* Eb = E + (size_t)bi*cN*cDE;
  float acc = 0.f;
  for(int j=jy;j<cN;j+=4){
    acc += Eb[j*cDE+d] * (float)nm[b*cN+j];
  }
  __shared__ float red[4][64];
  red[jy][d]=acc; __syncthreads();
  if (jy==0) S[(size_t)bi*cDE+d] = red[0][d]+red[1][d]+red[2][d]+red[3][d];
}

// ---------------- e_enc ----------------
__global__ void k_eenc(const float* S, const float* W_emax, const int* nm, float* eenc){
  int bi = blockIdx.x; int b = bi/cN; int i = bi%cN;
  int f = threadIdx.x;
  __shared__ float s[cDE];
  if (f<cDE) s[f]=S[(size_t)bi*cDE+f];
  __syncthreads();
  float acc=0.f;
  for(int d=0;d<cDE;++d) acc += s[d]*W_emax[d*cDX+f];
  float mi=(float)nm[b*cN+i];
  eenc[(size_t)bi*cDX+f] = fmaxf(acc*mi*(1.f/cN), 0.f);
}

// ---------------- xplus ----------------
__global__ void k_xplus(const float* X, const float* eenc, const float* W_x1,
                        const int* nm, float* xplus){
  int bi=blockIdx.x; int b=bi/cN; int i=bi%cN;
  int f=threadIdx.x;
  __shared__ float row[cDX];
  row[f]=eenc[(size_t)bi*cDX+f];
  __syncthreads();
  float acc=0.f;
  for(int c=0;c<cDX;++c) acc += row[c]*W_x1[c*cDX+f];
  float mi=(float)nm[b*cN+i];
  xplus[(size_t)bi*cDX+f] = (X[(size_t)bi*cDX+f] + fmaxf(acc,0.f))*mi;
}

// ---------------- q,k,v ----------------
__global__ void k_qkv(const float* xplus, const float* Wq, const float* Wk, const float* Wv,
                      float* qb, float* kb, float* vb){
  int bi=blockIdx.x; int f=threadIdx.x;
  __shared__ float row[cDX];
  row[f]=xplus[(size_t)bi*cDX+f];
  __syncthreads();
  float aq=0,ak=0,av=0;
  for(int c=0;c<cDX;++c){ float r=row[c]; aq+=r*Wq[c*cDX+f]; ak+=r*Wk[c*cDX+f]; av+=r*Wv[c*cDX+f]; }
  qb[(size_t)bi*cDX+f]=aq; kb[(size_t)bi*cDX+f]=ak; vb[(size_t)bi*cDX+f]=av;
}

// ---------------- attention softmax ----------------
__global__ void k_attn_softmax(const float* qb, const float* kb, const int* nm, float* P){
  int id=blockIdx.x; int b=id/(cNH*cN); int rem=id%(cNH*cN); int h=rem/cN; int i=rem%cN;
  int j=threadIdx.x;
  __shared__ float qrow[cDF];
  if (j<cDF) qrow[j]=qb[((size_t)b*cN+i)*cDX + h*cDF + j];
  __syncthreads();
  const float* krow = kb + ((size_t)b*cN+j)*cDX + h*cDF;
  float s=0.f;
  for(int c=0;c<cDF;++c) s += qrow[c]*krow[c];
  s *= 0.17677669529663687f;
  float val = (nm[b*cN+j]>0) ? s : -1e9f;
  __shared__ float red[256];
  red[j]=val; __syncthreads();
  for(int st=128;st>0;st>>=1){ if(j<st) red[j]=fmaxf(red[j],red[j+st]); __syncthreads(); }
  float mx=red[0]; __syncthreads();
  float e=__expf(val-mx);
  red[j]=e; __syncthreads();
  for(int st=128;st>0;st>>=1){ if(j<st) red[j]+=red[j+st]; __syncthreads(); }
  float denom=red[0];
  P[(size_t)id*cN + j] = e/denom;
}

// ---------------- attn out + LN -> new_X ----------------
__global__ void k_attn_out(const float* P, const float* vb, const float* Wo,
                           const float* X, const int* nm, const float* gx, const float* bx,
                           float* newX){
  int bi=blockIdx.x; int b=bi/cN; int i=bi%cN;
  int t=threadIdx.x;
  __shared__ float p8[cNH][cN];
  for(int h=0;h<cNH;++h) p8[h][t]=P[(((size_t)b*cNH+h)*cN+i)*cN + t];
  __syncthreads();
  int h=t/cDF;
  float acc=0.f;
  for(int j=0;j<cN;++j) acc += p8[h][j]*vb[((size_t)b*cN+j)*cDX + t];
  __shared__ float arow[cDX];
  arow[t]=acc; __syncthreads();
  float o=0.f;
  for(int c=0;c<cDX;++c) o += arow[c]*Wo[c*cDX+t];
  float mi=(float)nm[b*cN+i];
  float v = o*mi + X[(size_t)bi*cDX+t];
  __shared__ float red[256];
  red[t]=v; __syncthreads();
  for(int st=128;st>0;st>>=1){ if(t<st) red[t]+=red[t+st]; __syncthreads(); }
  float mean=red[0]*(1.f/cDX); __syncthreads();
  float dv=v-mean;
  red[t]=dv*dv; __syncthreads();
  for(int st=128;st>0;st>>=1){ if(t<st) red[t]+=red[t+st]; __syncthreads(); }
  float var=red[0]*(1.f/cDX);
  newX[(size_t)bi*cDX+t]=dv*rsqrtf(var+1e-6f)*gx[t]+bx[t];
}

// ---------------- xplusy ----------------
__global__ void k_xplusy(const float* X, const float* yw, const float* W_x2, float* xpy){
  int bi=blockIdx.x; int b=bi/cN;
  int f=threadIdx.x;
  __shared__ float row[cDX];
  row[f]=X[(size_t)bi*cDX+f]+yw[b*cDX+f];
  __syncthreads();
  float acc=0.f;
  for(int c=0;c<cDX;++c) acc += row[c]*W_x2[c*cDX+f];
  xpy[(size_t)bi*cDX+f]=fmaxf(acc,0.f);
}

// ---------------- sim ----------------
__global__ void k_sim(const float* xp, float* sim){
  int b=blockIdx.z;
  int tx=threadIdx.x, ty=threadIdx.y;
  __shared__ float Aa[16][17], Bb[16][17];
  const float* base = xp + (size_t)b*cN*cDX;
  float acc=0.f;
  for(int kt=0;kt<cDX;kt+=16){
    Aa[ty][tx]=base[(size_t)(blockIdx.y*16+ty)*cDX + kt+tx];
    Bb[ty][tx]=base[(size_t)(blockIdx.x*16+ty)*cDX + kt+tx];
    __syncthreads();
    for(int c=0;c<16;++c) acc += Aa[ty][c]*Bb[tx][c];
    __syncthreads();
  }
  sim[((size_t)b*cN + blockIdx.y*16+ty)*cN + blockIdx.x*16+tx] = acc*(1.f/16.f);
}

// ---------------- G = (alpha*sim + E)*emask (bf16) ----------------
__global__ void k_G(const float* E, const float* sim, const int* nm, const float* alpha_p,
                    bf16* G){
  int bi=blockIdx.x; int b=bi/cN; int i=bi%cN;
  float mi=(float)nm[b*cN+i];
  float alpha=alpha_p[0];
  size_t base=(size_t)bi*cN*cDE;
  for(int t=threadIdx.x;t<cN*cDE;t+=blockDim.x){
    int j=t>>6;
    float mj=(float)nm[b*cN+j];
    G[base+t]=tobf((alpha*sim[(size_t)bi*cN+j]+E[base+t])*mi*mj);
  }
}

// ---------------- per-slice transpose: Gt[bc][q][p] = G[bc][p][q] ----------------
// Stages the FULL 128x128 tile (8 passes of 256x8 shorts) into T[128][136].
__global__ void __launch_bounds__(256) k_transp(const short* G, short* Gt){
  const int bc=blockIdx.z;
  const int p0=blockIdx.y*128, q0=blockIdx.x*128;
  const int t=threadIdx.x;
  __shared__ short T[128][136];
  const short* src=G+(size_t)bc*65536;
  short* dst=Gt+(size_t)bc*65536;
#pragma unroll
  for(int l=0;l<8;++l){
    int idx=t+l*256;               // 0..2047
    int r=idx>>4, seg=idx&15;      // r 0..127, seg 0..15 (8 shorts each)
    *(int4v*)&T[r][seg*8]=*(const int4v*)&src[(size_t)(p0+r)*256 + q0 + seg*8];
  }
  __syncthreads();
  int qq=t&127, hf=t>>7;
#pragma unroll
  for(int ss=0;ss<8;++ss){
    bf16x8 v;
#pragma unroll
    for(int ii=0;ii<8;++ii) v[ii]=T[hf*64+ss*8+ii][qq];
    *(bf16x8*)&dst[(size_t)(q0+qq)*256 + p0 + hf*64 + ss*8]=v;
  }
}

// ---------------- poly1: Bt2 = (c0*(G@G) + c1*G)^T ----------------
// A from G rows; B staged from Gt rows. Epilogue: 8 slices of 16 rows repacked
// through Cf[16][132] (8.4 KB), transposed bf16x8 stores; beta*G from Gt rows.
__global__ void __launch_bounds__(256) k_bmm_t(const short* G, const short* Gt, short* Bt2,
                                               const float* coeff){
  const int bc=blockIdx.z; const int b=bc>>6;
  const float alpha=coeff[b*3+0];
  const float beta=coeff[b*3+1];
  const short* Ag=G+(size_t)bc*65536;
  const short* At=Gt+(size_t)bc*65536;
  short* Ct=Bt2+(size_t)bc*65536;
  const int row0=blockIdx.y*128, col0=blockIdx.x*128;
  const int t=threadIdx.x;
  const int lane=t&63, w=t>>6;
  const int wr=w>>1, wc=w&1;
  const int l15=lane&15, l4=lane>>4;
  __shared__ char smem[36864];
  short (*A_s)[72]=(short(*)[72])smem;
  short (*B_s)[72]=(short(*)[72])(smem+18432);
  float (*Cf)[132]=(float(*)[132])smem;   // 16x132 floats = 8448 B, aliased after compute
  f32x4 acc[4][4];
#pragma unroll
  for(int m=0;m<4;++m)
#pragma unroll
    for(int n=0;n<4;++n) acc[m][n]=(f32x4){0.f,0.f,0.f,0.f};

  for(int kt=0;kt<256;kt+=64){
#pragma unroll
    for(int l=0;l<4;++l){
      int idx=t+l*256;
      int r=idx>>3, seg=idx&7;
      *(int4v*)&A_s[r][seg*8]=*(const int4v*)&Ag[(size_t)(row0+r)*256 + kt + seg*8];
      *(int4v*)&B_s[r][seg*8]=*(const int4v*)&At[(size_t)(col0+r)*256 + kt + seg*8];
    }
    __syncthreads();
#pragma unroll
    for(int ks=0;ks<64;ks+=32){
      bf16x8 am[4], bn[4];
#pragma unroll
      for(int m=0;m<4;++m) am[m]=*(const bf16x8*)&A_s[wr*64+m*16+l15][ks+l4*8];
#pragma unroll
      for(int n=0;n<4;++n) bn[n]=*(const bf16x8*)&B_s[wc*64+n*16+l15][ks+l4*8];
#pragma unroll
      for(int m=0;m<4;++m)
#pragma unroll
        for(int n=0;n<4;++n)
          acc[m][n]=__builtin_amdgcn_mfma_f32_16x16x32_bf16(am[m],bn[n],acc[m][n],0,0,0);
    }
    __syncthreads();
  }
  // epilogue: 8 slices of 16 rows
  for(int rs=0;rs<8;++rs){
    if(rs) __syncthreads();
    int m=rs&3;
    if(wr==(rs>>2)){
#pragma unroll
      for(int n=0;n<4;++n)
#pragma unroll
        for(int r=0;r<4;++r)
          Cf[l4*4+r][wc*64+n*16+l15]=acc[m][n][r];
    }
    __syncthreads();
    int c=t&127, hf=t>>7;
    const short* gsrc=&At[(size_t)(col0+c)*256 + row0 + rs*16 + hf*8];
    short* dst=&Ct[(size_t)(col0+c)*256 + row0 + rs*16 + hf*8];
    bf16x8 a8=*(const bf16x8*)gsrc;
    bf16x8 o8;
#pragma unroll
    for(int ii=0;ii<8;++ii)
      o8[ii]=f2bs(alpha*Cf[hf*8+ii][c] + beta*bs2f(a8[ii]));
    *(bf16x8*)dst=o8;
  }
}

// ---------------- poly2: newE = G@Bbuf + c2*G  (B from Bt2 rows; f32 row-major out) ----------------
__global__ void __launch_bounds__(256) k_bmm_f(const short* G, const short* Bt2, float* C,
                                               const float* coeff){
  const int bc=blockIdx.z; const int b=bc>>6;
  const float beta=coeff[b*3+2];
  const short* Ag=G+(size_t)bc*65536;
  const short* Bt=Bt2+(size_t)bc*65536;
  float* Cb=C+(size_t)bc*65536;
  const int row0=blockIdx.y*128, col0=blockIdx.x*128;
  const int t=threadIdx.x;
  const int lane=t&63, w=t>>6;
  const int wr=w>>1, wc=w&1;
  const int l15=lane&15, l4=lane>>4;
  __shared__ char smem[36864];
  short (*A_s)[72]=(short(*)[72])smem;
  short (*B_s)[72]=(short(*)[72])(smem+18432);
  float (*Cf)[132]=(float(*)[132])smem;
  f32x4 acc[4][4];
#pragma unroll
  for(int m=0;m<4;++m)
#pragma unroll
    for(int n=0;n<4;++n) acc[m][n]=(f32x4){0.f,0.f,0.f,0.f};

  for(int kt=0;kt<256;kt+=64){
#pragma unroll
    for(int l=0;l<4;++l){
      int idx=t+l*256;
      int r=idx>>3, seg=idx&7;
      *(int4v*)&A_s[r][seg*8]=*(const int4v*)&Ag[(size_t)(row0+r)*256 + kt + seg*8];
      *(int4v*)&B_s[r][seg*8]=*(const int4v*)&Bt[(size_t)(col0+r)*256 + kt + seg*8];
    }
    __syncthreads();
#pragma unroll
    for(int ks=0;ks<64;ks+=32){
      bf16x8 am[4], bn[4];
#pragma unroll
      for(int m=0;m<4;++m) am[m]=*(const bf16x8*)&A_s[wr*64+m*16+l15][ks+l4*8];
#pragma unroll
      for(int n=0;n<4;++n) bn[n]=*(const bf16x8*)&B_s[wc*64+n*16+l15][ks+l4*8];
#pragma unroll
      for(int m=0;m<4;++m)
#pragma unroll
        for(int n=0;n<4;++n)
          acc[m][n]=__builtin_amdgcn_mfma_f32_16x16x32_bf16(am[m],bn[n],acc[m][n],0,0,0);
    }
    __syncthreads();
  }
  for(int rs=0;rs<8;++rs){
    if(rs) __syncthreads();
    int m=rs&3;
    if(wr==(rs>>2)){
#pragma unroll
      for(int n=0;n<4;++n)
#pragma unroll
        for(int r=0;r<4;++r)
          Cf[l4*4+r][wc*64+n*16+l15]=acc[m][n][r];
    }
    __syncthreads();
    int r=t>>4, cs=t&15;
    int row=row0+rs*16+r;
    const short* asrc=&Ag[(size_t)row*256 + col0 + cs*8];
    float* dst=&Cb[(size_t)row*256 + col0 + cs*8];
    bf16x8 a8=*(const bf16x8*)asrc;
    f32x4 o0,o1;
#pragma unroll
    for(int ii=0;ii<4;++ii) o0[ii]=Cf[r][cs*8+ii]   + beta*bs2f(a8[ii]);
#pragma unroll
    for(int ii=0;ii<4;++ii) o1[ii]=Cf[r][cs*8+4+ii] + beta*bs2f(a8[4+ii]);
    *(f32x4*)&dst[0]=o0;
    *(f32x4*)&dst[4]=o1;
  }
}

// ---------------- k_Eout_mfma ----------------
__global__ void __launch_bounds__(256) k_Eout_mfma(const float* newE_in, const float* E,
                       const int* nm, const float* W_Eout, const float* ge, const float* be,
                       float* outE){
  const int t=threadIdx.x;
  const int lane=t&63, w=t>>6;
  const int l15=lane&15, l4=lane>>4;
  const int blk=blockIdx.x;
  const int b=blk>>8, i=blk&255;
  const float mi=(float)nm[b*cN+i];
  bf16x8 bnf[2][4];
#pragma unroll
  for(int ks=0;ks<2;++ks)
#pragma unroll
    for(int n=0;n<4;++n){
      bf16x8 v;
#pragma unroll
      for(int ii=0;ii<8;++ii)
        v[ii]=f2bs(W_Eout[(ks*32+l4*8+ii)*cDE + n*16+l15]);
      bnf[ks][n]=v;
    }
  float gev[4], bev[4];
#pragma unroll
  for(int n=0;n<4;++n){ gev[n]=ge[n*16+l15]; bev[n]=be[n*16+l15]; }

  for(int it=0;it<4;++it){
    const int j0=it*64+w*16;
    const int p0=blk*256 + j0;
    f32x4 acc[4];
#pragma unroll
    for(int n=0;n<4;++n) acc[n]=(f32x4){0.f,0.f,0.f,0.f};
    if(mi>0.f){
#pragma unroll
      for(int ks=0;ks<2;++ks){
        const float* ap=&newE_in[(size_t)(p0+l15)*cDE + ks*32 + l4*8];
        float4 a0=*(const float4*)ap;
        float4 a1=*(const float4*)(ap+4);
        bf16x8 am;
        am[0]=f2bs(a0.x); am[1]=f2bs(a0.y); am[2]=f2bs(a0.z); am[3]=f2bs(a0.w);
        am[4]=f2bs(a1.x); am[5]=f2bs(a1.y); am[6]=f2bs(a1.z); am[7]=f2bs(a1.w);
#pragma unroll
        for(int n=0;n<4;++n)
          acc[n]=__builtin_amdgcn_mfma_f32_16x16x32_bf16(am,bnf[ks][n],acc[n],0,0,0);
      }
    }
    float mj[4];
#pragma unroll
    for(int r=0;r<4;++r) mj[r]=mi*(float)nm[b*cN + j0 + l4*4 + r];
#pragma unroll
    for(int reg=0;reg<4;++reg){
      size_t rowoff=(size_t)(p0 + l4*4 + reg)*cDE;
      float v0=fmaxf(acc[0][reg],0.f)*mj[reg]+E[rowoff + 0*16+l15];
      float v1=fmaxf(acc[1][reg],0.f)*mj[reg]+E[rowoff + 1*16+l15];
      float v2=fmaxf(acc[2][reg],0.f)*mj[reg]+E[rowoff + 2*16+l15];
      float v3=fmaxf(acc[3][reg],0.f)*mj[reg]+E[rowoff + 3*16+l15];
      float s=v0+v1+v2+v3;
      float q=v0*v0+v1*v1+v2*v2+v3*v3;
#pragma unroll
      for(int m=1;m<16;m<<=1){ s+=__shfl_xor(s,m); q+=__shfl_xor(q,m); }
      float mean=s*(1.f/cDE);
      float var=q*(1.f/cDE)-mean*mean;
      float inv=rsqrtf(var+1e-6f);
      outE[rowoff + 0*16+l15]=(v0-mean)*inv*gev[0]+bev[0];
      outE[rowoff + 1*16+l15]=(v1-mean)*inv*gev[1]+bev[1];
      outE[rowoff + 2*16+l15]=(v2-mean)*inv*gev[2]+bev[2];
      outE[rowoff + 3*16+l15]=(v3-mean)*inv*gev[3]+bev[3];
    }
  }
}

// ---------------- k_Gaccum_mfma ----------------
__global__ void __launch_bounds__(256) k_Gaccum_mfma(const float* E, const int* nm,
                                                     const float* G_kernel,
                                                     float* Npart, float* Dpart){
  const int chunk=blockIdx.x;
  const int b=blockIdx.y;
  const int t=threadIdx.x;
  const int lane=t&63, w=t>>6;
  const int l15=lane&15, l4=lane>>4;

  __shared__ short EmA[128][72];
  __shared__ short Wt[128][136];
  __shared__ float mrow[128];
  __shared__ float Dacc[128];
  __shared__ float Dpar[4][128];

  bf16x8 gk[2][8];
#pragma unroll
  for(int kt=0;kt<2;++kt)
#pragma unroll
    for(int n=0;n<8;++n){
      bf16x8 v;
#pragma unroll
      for(int ii=0;ii<8;++ii)
        v[ii]=f2bs(G_kernel[(kt*32+l4*8+ii)*128 + n*16+l15]*0.125f);
      gk[kt][n]=v;
    }

  f32x4 nacc[2][4];
#pragma unroll
  for(int a=0;a<2;++a)
#pragma unroll
    for(int d2=0;d2<4;++d2) nacc[a][d2]=(f32x4){0.f,0.f,0.f,0.f};

  if(t<128) Dacc[t]=0.f;
  __syncthreads();

  const size_t ebase=((size_t)b)<<16;
  for(int sub=0;sub<4;++sub){
    const int rowbase = chunk*512 + sub*128;
    {
      int pr=t>>1, hh=t&1;
      int p=rowbase+pr;
      const float* src=&E[(ebase+p)*cDE + hh*32];
#pragma unroll
      for(int q=0;q<8;++q){
        float4 v=*(const float4*)(src+q*4);
        short4v s4; s4[0]=f2bs(v.x); s4[1]=f2bs(v.y); s4[2]=f2bs(v.z); s4[3]=f2bs(v.w);
        *(short4v*)&EmA[pr][hh*32+q*4]=s4;
      }
      if(hh==0) mrow[pr]=(float)(nm[b*cN+(p>>8)]*nm[b*cN+(p&255)]);
    }
    __syncthreads();

    f32x4 wacc[2][8];
#pragma unroll
    for(int m=0;m<2;++m)
#pragma unroll
      for(int n=0;n<8;++n) wacc[m][n]=(f32x4){0.f,0.f,0.f,0.f};
#pragma unroll
    for(int kt=0;kt<2;++kt){
      bf16x8 am[2];
#pragma unroll
      for(int m=0;m<2;++m) am[m]=*(const bf16x8*)&EmA[w*32+m*16+l15][kt*32+l4*8];
#pragma unroll
      for(int m=0;m<2;++m)
#pragma unroll
        for(int n=0;n<8;++n)
          wacc[m][n]=__builtin_amdgcn_mfma_f32_16x16x32_bf16(am[m],gk[kt][n],wacc[m][n],0,0,0);
    }
    float dsum[8];
#pragma unroll
    for(int n=0;n<8;++n) dsum[n]=0.f;
#pragma unroll
    for(int m=0;m<2;++m){
#pragma unroll
      for(int r=0;r<4;++r){
        int pl=w*32+m*16+l4*4+r;
        float mv=mrow[pl];
#pragma unroll
        for(int n=0;n<8;++n){
          float wv=(mv>0.f)?__expf(wacc[m][n][r]):0.f;
          dsum[n]+=wv;
          Wt[n*16+l15][pl]=f2bs(wv);
        }
      }
    }
#pragma unroll
    for(int n=0;n<8;++n){
      float s=dsum[n];
      s+=__shfl_xor(s,16); s+=__shfl_xor(s,32);
      if(l4==0) Dpar[w][n*16+l15]=s;
    }
    __syncthreads();

#pragma unroll
    for(int ks=0;ks<4;++ks){
      bf16x8 aw[2];
#pragma unroll
      for(int a=0;a<2;++a) aw[a]=*(const bf16x8*)&Wt[w*32+a*16+l15][ks*32+l4*8];
      bf16x8 bm[4];
#pragma unroll
      for(int d2=0;d2<4;++d2){
        bf16x8 v;
#pragma unroll
        for(int ii=0;ii<8;++ii) v[ii]=EmA[ks*32+l4*8+ii][d2*16+l15];
        bm[d2]=v;
      }
#pragma unroll
      for(int a=0;a<2;++a)
#pragma unroll
        for(int d2=0;d2<4;++d2)
          nacc[a][d2]=__builtin_amdgcn_mfma_f32_16x16x32_bf16(aw[a],bm[d2],nacc[a][d2],0,0,0);
    }
    __syncthreads();
    if(t<128) Dacc[t]+=Dpar[0][t]+Dpar[1][t]+Dpar[2][t]+Dpar[3][t];
    __syncthreads();
  }

  size_t pi=(size_t)b*128+chunk;
  float* np=Npart + pi*128*cDE;
#pragma unroll
  for(int a=0;a<2;++a){
#pragma unroll
    for(int d2=0;d2<4;++d2){
#pragma unroll
      for(int r=0;r<4;++r){
        int k=w*32+a*16+l4*4+r;
        int d=d2*16+l15;
        np[(size_t)k*cDE+d]=nacc[a][d2][r];
      }
    }
  }
  if(t<128) Dpart[pi*128+t]=Dacc[t];
}

// ---------------- combine partials -> Genc ----------------
__global__ void k_Gcombine(const float* Npart, const float* Dpart, float* Genc){
  int bk=blockIdx.x; int b=bk>>7; int k=bk&127;
  int d=threadIdx.x;
  float n=0.f, dd=0.f;
  for(int pi=0;pi<128;++pi){
    size_t base=((size_t)b*128+pi)*128+k;
    n += Npart[base*cDE+d];
    dd += Dpart[base];
  }
  Genc[(size_t)b*8192 + k*cDE + d]=n/dd;
}

// ---------------- aX softmax + X_enc ----------------
__global__ void k_Xenc(const float* X, const int* nm, const float* X_kernel, float* Xenc){
  int k=blockIdx.x;
  int b=blockIdx.y;
  int n=threadIdx.x;
  float m=(float)nm[b*cN+n];
  const float* xr=X+((size_t)b*cN+n)*cDX;
  float acc=0.f;
  for(int c=0;c<cDX;++c) acc += xr[c]*X_kernel[c*64+k];
  float lg=(m>0.f)?acc*(1.f/16.f):-1e9f;
  __shared__ float red[256];
  red[n]=lg; __syncthreads();
  for(int st=128;st>0;st>>=1){ if(n<st) red[n]=fmaxf(red[n],red[n+st]); __syncthreads(); }
  float mx=red[0]; __syncthreads();
  float e=__expf(lg-mx);
  red[n]=e; __syncthreads();
  for(int st=128;st>0;st>>=1){ if(n<st) red[n]+=red[n+st]; __syncthreads(); }
  float denom=red[0]; __syncthreads();
  __shared__ float ps[256];
  ps[n]=e/denom;
  __syncthreads();
  int d=n;
  float s=0.f;
  for(int nn=0;nn<cN;++nn) s += ps[nn]*X[((size_t)b*cN+nn)*cDX+d];
  Xenc[(size_t)b*16384 + k*cDX + d]=s;
}

// ---------------- head partials ----------------
__global__ void __launch_bounds__(256) k_headA(const float* Genc, const float* Xenc,
                        const float* W_Gtrans, const float* W_Xtrans,
                        float* Gp, float* Xp){
  int blk=blockIdx.x;
  int t=threadIdx.x;
  int o=t&127, sub=t>>7;
  int b0=sub*2, b1=sub*2+1;
  __shared__ float ash[4][128];
  if(blk<64){
    int ch=blk;
    for(int l=t;l<512;l+=256){
      int b=l>>7, q=l&127;
      ash[b][q]=Genc[(size_t)b*8192 + ch*128 + q];
    }
    __syncthreads();
    const float* wbase=W_Gtrans + (size_t)ch*128*cDY + o;
    float a0=0.f, a1=0.f;
#pragma unroll 4
    for(int qq=0;qq<128;++qq){
      float w=wbase[(size_t)qq*cDY];
      a0+=ash[b0][qq]*w; a1+=ash[b1][qq]*w;
    }
    Gp[((size_t)b0*64+ch)*cDY+o]=a0;
    Gp[((size_t)b1*64+ch)*cDY+o]=a1;
  } else {
    int ch=blk-64;
    for(int l=t;l<512;l+=256){
      int b=l>>7, q=l&127;
      ash[b][q]=Xenc[(size_t)b*16384 + ch*128 + q];
    }
    __syncthreads();
    const float* wbase=W_Xtrans + (size_t)ch*128*cDY + o;
    float a0=0.f, a1=0.f;
#pragma unroll 4
    for(int qq=0;qq<128;++qq){
      float w=wbase[(size_t)qq*cDY];
      a0+=ash[b0][qq]*w; a1+=ash[b1][qq]*w;
    }
    Xp[((size_t)b0*128+ch)*cDY+o]=a0;
    Xp[((size_t)b1*128+ch)*cDY+o]=a1;
  }
}

// ---------------- head final -> new_y ----------------
__global__ void k_headB(const float* Gp, const float* Xp, const float* W_yout,
                        const float* y, const float* gy, const float* by, float* newy){
  int b=blockIdx.x; int o=threadIdx.x;
  float g=0.f,x=0.f;
  for(int ch=0;ch<64;++ch)  g+=Gp[((size_t)b*64+ch)*cDY+o];
  for(int ch=0;ch<128;++ch) x+=Xp[((size_t)b*128+ch)*cDY+o];
  __shared__ float srow[cDY];
  srow[o]=fmaxf(g,0.f)+fmaxf(x,0.f);
  __syncthreads();
  float h=0.f;
  for(int r=0;r<cDY;++r) h += srow[r]*W_yout[r*cDY+o];
  float v=fmaxf(h,0.f)+y[b*cDY+o];
  __shared__ float red[cDY];
  red[o]=v; __syncthreads();
  for(int st=64;st>0;st>>=1){ if(o<st) red[o]+=red[o+st]; __syncthreads(); }
  float mean=red[0]*(1.f/cDY); __syncthreads();
  float dv=v-mean;
  red[o]=dv*dv; __syncthreads();
  for(int st=64;st>0;st>>=1){ if(o<st) red[o]+=red[o+st]; __syncthreads(); }
  float var=red[0]*(1.f/cDY);
  newy[b*cDY+o]=dv*rsqrtf(var+1e-6f)*gy[o]+by[o];
}

extern "C" void kernel_launch(void* const* d_in, const int* in_sizes, int n_in,
                              void* d_out, int out_size, void* d_ws, size_t ws_size,
                              hipStream_t stream){
  const float* X     =(const float*)d_in[0];
  const float* E     =(const float*)d_in[1];
  const float* y     =(const float*)d_in[2];
  const int*   nm    =(const int*)  d_in[3];
  const float* W_emax=(const float*)d_in[4];
  const float* W_x1  =(const float*)d_in[5];
  const float* Wq    =(const float*)d_in[6];
  const float* Wk    =(const float*)d_in[7];
  const float* Wv    =(const float*)d_in[8];
  const float* Wo    =(const float*)d_in[9];
  const float* W_y2  =(const float*)d_in[10];
  const float* W_x2  =(const float*)d_in[11];
  const float* Wc    =(const float*)d_in[12];
  const float* bc    =(const float*)d_in[13];
  const float* salpha=(const float*)d_in[14];
  const float* W_Eout=(const float*)d_in[15];
  const float* G_kern=(const float*)d_in[16];
  const float* X_kern=(const float*)d_in[17];
  const float* W_Gtr =(const float*)d_in[18];
  const float* W_Xtr =(const float*)d_in[19];
  const float* W_yout=(const float*)d_in[20];
  const float* gx    =(const float*)d_in[21];
  const float* bx    =(const float*)d_in[22];
  const float* ge    =(const float*)d_in[23];
  const float* be    =(const float*)d_in[24];
  const float* gy    =(const float*)d_in[25];
  const float* by    =(const float*)d_in[26];

  char* wsb=(char*)d_ws;
  bf16* Gbf=(bf16*)wsb;                        // [0,32M)
  short* Gs=(short*)wsb;
  short* Bt2=(short*)(wsb+33554432);           // [32M,64M)
  short* Gts=(short*)(wsb+67108864);           // [64M,96M)
  float* Npart=(float*)(wsb+33554432);         // aliases Bt2 (dead after poly2)
  float* f32=(float*)(wsb+100663296);          // [96M,...)
  float* sim  = f32+F_SIM;
  float* P    = f32+F_P;
  float* Dpart= f32+F_NP;
  float* Gp   = f32+F_GP;
  float* Xp   = f32+F_XP;
  float* S    = f32+F_S;
  float* eenc = f32+F_EENC;
  float* xplus= f32+F_XPL;
  float* qb   = f32+F_QB;
  float* kb   = f32+F_KB;
  float* vb   = f32+F_VB;
  float* yw   = f32+F_YW;
  float* xpy  = f32+F_XPY;
  float* coeff= f32+F_COEF;
  float* Genc = f32+F_GENC;
  float* Xenc = f32+F_XENC;

  float* out=(float*)d_out;
  float* newX=out;
  float* newE_out=out+262144;
  float* newy=out+17039360;

  k_coeff_yw<<<cB,256,0,stream>>>(y,Wc,bc,W_y2,coeff,yw);
  k_reduceE<<<cB*cN,dim3(64,4),0,stream>>>(E,nm,S);
  k_eenc<<<cB*cN,256,0,stream>>>(S,W_emax,nm,eenc);
  k_xplus<<<cB*cN,256,0,stream>>>(X,eenc,W_x1,nm,xplus);
  k_qkv<<<cB*cN,256,0,stream>>>(xplus,Wq,Wk,Wv,qb,kb,vb);
  k_attn_softmax<<<cB*cNH*cN,256,0,stream>>>(qb,kb,nm,P);
  k_attn_out<<<cB*cN,256,0,stream>>>(P,vb,Wo,X,nm,gx,bx,newX);
  k_xplusy<<<cB*cN,256,0,stream>>>(X,yw,W_x2,xpy);
  k_sim<<<dim3(16,16,cB),dim3(16,16),0,stream>>>(xpy,sim);
  k_G<<<cB*cN,256,0,stream>>>(E,sim,nm,salpha,Gbf);
  k_transp<<<dim3(2,2,cB*cDE),256,0,stream>>>(Gs,Gts);
  k_bmm_t<<<dim3(2,2,cB*cDE),256,0,stream>>>(Gs,Gts,Bt2,coeff);
  k_bmm_f<<<dim3(2,2,cB*cDE),256,0,stream>>>(Gs,Bt2,newE_out,coeff);
  k_Eout_mfma<<<1024,256,0,stream>>>(newE_out,E,nm,W_Eout,ge,be,newE_out);
  k_Gaccum_mfma<<<dim3(128,cB),256,0,stream>>>(E,nm,G_kern,Npart,Dpart);
  k_Gcombine<<<cB*128,64,0,stream>>>(Npart,Dpart,Genc);
  k_Xenc<<<dim3(64,cB),256,0,stream>>>(X,nm,X_kern,Xenc);
  k_headA<<<192,256,0,stream>>>(Genc,Xenc,W_Gtr,W_Xtr,Gp,Xp);
  k_headB<<<cB,128,0,stream>>>(Gp,Xp,W_yout,y,gy,by,newy);
}

// Round 13
// 413.093 us; speedup vs baseline: 4.0363x; 1.0083x over previous
//
#include <hip/hip_runtime.h>
#include <hip/hip_bf16.h>

typedef __hip_bfloat16 bf16;
__device__ __forceinline__ bf16 tobf(float v){ return __float2bfloat16(v); }
__device__ __forceinline__ float frombf(bf16 v){ return __bfloat162float(v); }
__device__ __forceinline__ short f2bs(float x){ bf16 h=tobf(x); return *reinterpret_cast<short*>(&h); }
__device__ __forceinline__ float bs2f(short s){ unsigned int v=((unsigned int)(unsigned short)s)<<16; return __int_as_float((int)v); }

typedef __attribute__((ext_vector_type(8))) short bf16x8;
typedef __attribute__((ext_vector_type(4))) short short4v;
typedef __attribute__((ext_vector_type(4))) float f32x4;
typedef __attribute__((ext_vector_type(4))) int int4v;

static constexpr int cB=4, cN=256, cDX=256, cDE=64, cDY=128, cNH=8, cDF=32;

// ---- workspace layout (bytes) ----
// [0,   32M)  G    bf16
// [32M, 64M)  Bt2  bf16 (poly1 out, transposed)  -- after poly2: Npart f32 (16.8MB)
// [64M, 96M)  Gt   bf16 (G transposed per slice)
// [96M, ...)  f32 region (offsets in floats below)
static constexpr size_t F_SIM  = 0;
static constexpr size_t F_P    = 262144;
static constexpr size_t F_NP   = 2359296;  // Dpart [0,65536), Gp/Xp at +1048576
static constexpr size_t F_GP   = F_NP + 1048576;
static constexpr size_t F_XP   = F_NP + 1048576 + 32768;
static constexpr size_t F_S    = 6619136;
static constexpr size_t F_EENC = 6684672;
static constexpr size_t F_XPL  = 6946816;
static constexpr size_t F_QB   = 7208960;
static constexpr size_t F_KB   = 7471104;
static constexpr size_t F_VB   = 7733248;
static constexpr size_t F_YW   = 7995392;
static constexpr size_t F_XPY  = 7996416;
static constexpr size_t F_COEF = 8258560;
static constexpr size_t F_GENC = 8258576;
static constexpr size_t F_XENC = 8291344;

// ---------------- coeff = y@Wc+bc ; yw = relu(y@W_y2) ----------------
__global__ void k_coeff_yw(const float* y, const float* Wc, const float* bc,
                           const float* W_y2, float* coeff, float* yw){
  int b = blockIdx.x; int f = threadIdx.x;
  float acc = 0.f;
  for(int r=0;r<cDY;++r) acc += y[b*cDY+r]*W_y2[r*cDX+f];
  yw[b*cDX+f] = fmaxf(acc,0.f);
  if (f < 3){
    float c = bc[f];
    for(int r=0;r<cDY;++r) c += y[b*cDY+r]*Wc[r*3+f];
    coeff[b*3+f] = c;
  }
}

// ---------------- S[b,i,d] = sum_j E[b,i,j,d]*m_j ----------------
__global__ void k_reduceE(const float* E, const int* nm, float* S){
  int bi = blockIdx.x; int b = bi / cN;
  int d = threadIdx.x;
  int jy = threadIdx.y;
  const float* Eb = E + (size_t)bi*cN*cDE;
  float acc = 0.f;
  for(int j=jy;j<cN;j+=4){
    acc += Eb[j*cDE+d] * (float)nm[b*cN+j];
  }
  __shared__ float red[4][64];
  red[jy][d]=acc; __syncthreads();
  if (jy==0) S[(size_t)bi*cDE+d] = red[0][d]+red[1][d]+red[2][d]+red[3][d];
}

// ---------------- e_enc ----------------
__global__ void k_eenc(const float* S, const float* W_emax, const int* nm, float* eenc){
  int bi = blockIdx.x; int b = bi/cN; int i = bi%cN;
  int f = threadIdx.x;
  __shared__ float s[cDE];
  if (f<cDE) s[f]=S[(size_t)bi*cDE+f];
  __syncthreads();
  float acc=0.f;
  for(int d=0;d<cDE;++d) acc += s[d]*W_emax[d*cDX+f];
  float mi=(float)nm[b*cN+i];
  eenc[(size_t)bi*cDX+f] = fmaxf(acc*mi*(1.f/cN), 0.f);
}

// ---------------- xplus ----------------
__global__ void k_xplus(const float* X, const float* eenc, const float* W_x1,
                        const int* nm, float* xplus){
  int bi=blockIdx.x; int b=bi/cN; int i=bi%cN;
  int f=threadIdx.x;
  __shared__ float row[cDX];
  row[f]=eenc[(size_t)bi*cDX+f];
  __syncthreads();
  float acc=0.f;
  for(int c=0;c<cDX;++c) acc += row[c]*W_x1[c*cDX+f];
  float mi=(float)nm[b*cN+i];
  xplus[(size_t)bi*cDX+f] = (X[(size_t)bi*cDX+f] + fmaxf(acc,0.f))*mi;
}

// ---------------- q,k,v ----------------
__global__ void k_qkv(const float* xplus, const float* Wq, const float* Wk, const float* Wv,
                      float* qb, float* kb, float* vb){
  int bi=blockIdx.x; int f=threadIdx.x;
  __shared__ float row[cDX];
  row[f]=xplus[(size_t)bi*cDX+f];
  __syncthreads();
  float aq=0,ak=0,av=0;
  for(int c=0;c<cDX;++c){ float r=row[c]; aq+=r*Wq[c*cDX+f]; ak+=r*Wk[c*cDX+f]; av+=r*Wv[c*cDX+f]; }
  qb[(size_t)bi*cDX+f]=aq; kb[(size_t)bi*cDX+f]=ak; vb[(size_t)bi*cDX+f]=av;
}

// ---------------- attention softmax ----------------
__global__ void k_attn_softmax(const float* qb, const float* kb, const int* nm, float* P){
  int id=blockIdx.x; int b=id/(cNH*cN); int rem=id%(cNH*cN); int h=rem/cN; int i=rem%cN;
  int j=threadIdx.x;
  __shared__ float qrow[cDF];
  if (j<cDF) qrow[j]=qb[((size_t)b*cN+i)*cDX + h*cDF + j];
  __syncthreads();
  const float* krow = kb + ((size_t)b*cN+j)*cDX + h*cDF;
  float s=0.f;
  for(int c=0;c<cDF;++c) s += qrow[c]*krow[c];
  s *= 0.17677669529663687f;
  float val = (nm[b*cN+j]>0) ? s : -1e9f;
  __shared__ float red[256];
  red[j]=val; __syncthreads();
  for(int st=128;st>0;st>>=1){ if(j<st) red[j]=fmaxf(red[j],red[j+st]); __syncthreads(); }
  float mx=red[0]; __syncthreads();
  float e=__expf(val-mx);
  red[j]=e; __syncthreads();
  for(int st=128;st>0;st>>=1){ if(j<st) red[j]+=red[j+st]; __syncthreads(); }
  float denom=red[0];
  P[(size_t)id*cN + j] = e/denom;
}

// ---------------- attn out + LN -> new_X ----------------
__global__ void k_attn_out(const float* P, const float* vb, const float* Wo,
                           const float* X, const int* nm, const float* gx, const float* bx,
                           float* newX){
  int bi=blockIdx.x; int b=bi/cN; int i=bi%cN;
  int t=threadIdx.x;
  __shared__ float p8[cNH][cN];
  for(int h=0;h<cNH;++h) p8[h][t]=P[(((size_t)b*cNH+h)*cN+i)*cN + t];
  __syncthreads();
  int h=t/cDF;
  float acc=0.f;
  for(int j=0;j<cN;++j) acc += p8[h][j]*vb[((size_t)b*cN+j)*cDX + t];
  __shared__ float arow[cDX];
  arow[t]=acc; __syncthreads();
  float o=0.f;
  for(int c=0;c<cDX;++c) o += arow[c]*Wo[c*cDX+t];
  float mi=(float)nm[b*cN+i];
  float v = o*mi + X[(size_t)bi*cDX+t];
  __shared__ float red[256];
  red[t]=v; __syncthreads();
  for(int st=128;st>0;st>>=1){ if(t<st) red[t]+=red[t+st]; __syncthreads(); }
  float mean=red[0]*(1.f/cDX); __syncthreads();
  float dv=v-mean;
  red[t]=dv*dv; __syncthreads();
  for(int st=128;st>0;st>>=1){ if(t<st) red[t]+=red[t+st]; __syncthreads(); }
  float var=red[0]*(1.f/cDX);
  newX[(size_t)bi*cDX+t]=dv*rsqrtf(var+1e-6f)*gx[t]+bx[t];
}

// ---------------- xplusy ----------------
__global__ void k_xplusy(const float* X, const float* yw, const float* W_x2, float* xpy){
  int bi=blockIdx.x; int b=bi/cN;
  int f=threadIdx.x;
  __shared__ float row[cDX];
  row[f]=X[(size_t)bi*cDX+f]+yw[b*cDX+f];
  __syncthreads();
  float acc=0.f;
  for(int c=0;c<cDX;++c) acc += row[c]*W_x2[c*cDX+f];
  xpy[(size_t)bi*cDX+f]=fmaxf(acc,0.f);
}

// ---------------- sim ----------------
__global__ void k_sim(const float* xp, float* sim){
  int b=blockIdx.z;
  int tx=threadIdx.x, ty=threadIdx.y;
  __shared__ float Aa[16][17], Bb[16][17];
  const float* base = xp + (size_t)b*cN*cDX;
  float acc=0.f;
  for(int kt=0;kt<cDX;kt+=16){
    Aa[ty][tx]=base[(size_t)(blockIdx.y*16+ty)*cDX + kt+tx];
    Bb[ty][tx]=base[(size_t)(blockIdx.x*16+ty)*cDX + kt+tx];
    __syncthreads();
    for(int c=0;c<16;++c) acc += Aa[ty][c]*Bb[tx][c];
    __syncthreads();
  }
  sim[((size_t)b*cN + blockIdx.y*16+ty)*cN + blockIdx.x*16+tx] = acc*(1.f/16.f);
}

// ---------------- G = (alpha*sim + E)*emask (bf16) ----------------
__global__ void k_G(const float* E, const float* sim, const int* nm, const float* alpha_p,
                    bf16* G){
  int bi=blockIdx.x; int b=bi/cN; int i=bi%cN;
  float mi=(float)nm[b*cN+i];
  float alpha=alpha_p[0];
  size_t base=(size_t)bi*cN*cDE;
  for(int t=threadIdx.x;t<cN*cDE;t+=blockDim.x){
    int j=t>>6;
    float mj=(float)nm[b*cN+j];
    G[base+t]=tobf((alpha*sim[(size_t)bi*cN+j]+E[base+t])*mi*mj);
  }
}

// ---------------- per-slice transpose: Gt[bc][q][p] = G[bc][p][q] ----------------
__global__ void __launch_bounds__(256) k_transp(const short* G, short* Gt){
  const int bc=blockIdx.z;
  const int p0=blockIdx.y*128, q0=blockIdx.x*128;
  const int t=threadIdx.x;
  __shared__ short T[128][136];
  const short* src=G+(size_t)bc*65536;
  short* dst=Gt+(size_t)bc*65536;
#pragma unroll
  for(int l=0;l<8;++l){
    int idx=t+l*256;
    int r=idx>>4, seg=idx&15;
    *(int4v*)&T[r][seg*8]=*(const int4v*)&src[(size_t)(p0+r)*256 + q0 + seg*8];
  }
  __syncthreads();
  int qq=t&127, hf=t>>7;
#pragma unroll
  for(int ss=0;ss<8;++ss){
    bf16x8 v;
#pragma unroll
    for(int ii=0;ii<8;++ii) v[ii]=T[hf*64+ss*8+ii][qq];
    *(bf16x8*)&dst[(size_t)(q0+qq)*256 + p0 + hf*64 + ss*8]=v;
  }
}

// ---------------- poly1: Bt2 = (c0*(G@G) + c1*G)^T  (round-11 epilogue, known good) ----------------
__global__ void __launch_bounds__(256) k_bmm_t(const short* G, const short* Gt, short* Bt2,
                                               const float* coeff){
  const int bc=blockIdx.z; const int b=bc>>6;
  const float alpha=coeff[b*3+0];
  const float beta=coeff[b*3+1];
  const short* Ag=G+(size_t)bc*65536;
  const short* At=Gt+(size_t)bc*65536;
  short* Ct=Bt2+(size_t)bc*65536;
  const int row0=blockIdx.y*128, col0=blockIdx.x*128;
  const int t=threadIdx.x;
  const int lane=t&63, w=t>>6;
  const int wr=w>>1, wc=w&1;
  const int l15=lane&15, l4=lane>>4;
  __shared__ char smem[36864];
  short (*A_s)[72]=(short(*)[72])smem;
  short (*B_s)[72]=(short(*)[72])(smem+18432);
  float (*Cf)[132]=(float(*)[132])smem;   // 16x132 floats = 8448 B, aliased after compute
  f32x4 acc[4][4];
#pragma unroll
  for(int m=0;m<4;++m)
#pragma unroll
    for(int n=0;n<4;++n) acc[m][n]=(f32x4){0.f,0.f,0.f,0.f};

  for(int kt=0;kt<256;kt+=64){
#pragma unroll
    for(int l=0;l<4;++l){
      int idx=t+l*256;
      int r=idx>>3, seg=idx&7;
      *(int4v*)&A_s[r][seg*8]=*(const int4v*)&Ag[(size_t)(row0+r)*256 + kt + seg*8];
      *(int4v*)&B_s[r][seg*8]=*(const int4v*)&At[(size_t)(col0+r)*256 + kt + seg*8];
    }
    __syncthreads();
#pragma unroll
    for(int ks=0;ks<64;ks+=32){
      bf16x8 am[4], bn[4];
#pragma unroll
      for(int m=0;m<4;++m) am[m]=*(const bf16x8*)&A_s[wr*64+m*16+l15][ks+l4*8];
#pragma unroll
      for(int n=0;n<4;++n) bn[n]=*(const bf16x8*)&B_s[wc*64+n*16+l15][ks+l4*8];
#pragma unroll
      for(int m=0;m<4;++m)
#pragma unroll
        for(int n=0;n<4;++n)
          acc[m][n]=__builtin_amdgcn_mfma_f32_16x16x32_bf16(am[m],bn[n],acc[m][n],0,0,0);
    }
    __syncthreads();
  }
  // epilogue: 8 slices of 16 rows
  for(int rs=0;rs<8;++rs){
    if(rs) __syncthreads();
    int m=rs&3;
    if(wr==(rs>>2)){
#pragma unroll
      for(int n=0;n<4;++n)
#pragma unroll
        for(int r=0;r<4;++r)
          Cf[l4*4+r][wc*64+n*16+l15]=acc[m][n][r];
    }
    __syncthreads();
    int c=t&127, hf=t>>7;
    const short* gsrc=&At[(size_t)(col0+c)*256 + row0 + rs*16 + hf*8];
    short* dst=&Ct[(size_t)(col0+c)*256 + row0 + rs*16 + hf*8];
    bf16x8 a8=*(const bf16x8*)gsrc;
    bf16x8 o8;
#pragma unroll
    for(int ii=0;ii<8;++ii)
      o8[ii]=f2bs(alpha*Cf[hf*8+ii][c] + beta*bs2f(a8[ii]));
    *(bf16x8*)dst=o8;
  }
}

// ---------------- poly2: newE = G@Bbuf + c2*G  (B from Bt2 rows; f32 row-major out) ----------------
__global__ void __launch_bounds__(256) k_bmm_f(const short* G, const short* Bt2, float* C,
                                               const float* coeff){
  const int bc=blockIdx.z; const int b=bc>>6;
  const float beta=coeff[b*3+2];
  const short* Ag=G+(size_t)bc*65536;
  const short* Bt=Bt2+(size_t)bc*65536;
  float* Cb=C+(size_t)bc*65536;
  const int row0=blockIdx.y*128, col0=blockIdx.x*128;
  const int t=threadIdx.x;
  const int lane=t&63, w=t>>6;
  const int wr=w>>1, wc=w&1;
  const int l15=lane&15, l4=lane>>4;
  __shared__ char smem[36864];
  short (*A_s)[72]=(short(*)[72])smem;
  short (*B_s)[72]=(short(*)[72])(smem+18432);
  float (*Cf)[132]=(float(*)[132])smem;
  f32x4 acc[4][4];
#pragma unroll
  for(int m=0;m<4;++m)
#pragma unroll
    for(int n=0;n<4;++n) acc[m][n]=(f32x4){0.f,0.f,0.f,0.f};

  for(int kt=0;kt<256;kt+=64){
#pragma unroll
    for(int l=0;l<4;++l){
      int idx=t+l*256;
      int r=idx>>3, seg=idx&7;
      *(int4v*)&A_s[r][seg*8]=*(const int4v*)&Ag[(size_t)(row0+r)*256 + kt + seg*8];
      *(int4v*)&B_s[r][seg*8]=*(const int4v*)&Bt[(size_t)(col0+r)*256 + kt + seg*8];
    }
    __syncthreads();
#pragma unroll
    for(int ks=0;ks<64;ks+=32){
      bf16x8 am[4], bn[4];
#pragma unroll
      for(int m=0;m<4;++m) am[m]=*(const bf16x8*)&A_s[wr*64+m*16+l15][ks+l4*8];
#pragma unroll
      for(int n=0;n<4;++n) bn[n]=*(const bf16x8*)&B_s[wc*64+n*16+l15][ks+l4*8];
#pragma unroll
      for(int m=0;m<4;++m)
#pragma unroll
        for(int n=0;n<4;++n)
          acc[m][n]=__builtin_amdgcn_mfma_f32_16x16x32_bf16(am[m],bn[n],acc[m][n],0,0,0);
    }
    __syncthreads();
  }
  for(int rs=0;rs<8;++rs){
    if(rs) __syncthreads();
    int m=rs&3;
    if(wr==(rs>>2)){
#pragma unroll
      for(int n=0;n<4;++n)
#pragma unroll
        for(int r=0;r<4;++r)
          Cf[l4*4+r][wc*64+n*16+l15]=acc[m][n][r];
    }
    __syncthreads();
    int r=t>>4, cs=t&15;
    int row=row0+rs*16+r;
    const short* asrc=&Ag[(size_t)row*256 + col0 + cs*8];
    float* dst=&Cb[(size_t)row*256 + col0 + cs*8];
    bf16x8 a8=*(const bf16x8*)asrc;
    f32x4 o0,o1;
#pragma unroll
    for(int ii=0;ii<4;++ii) o0[ii]=Cf[r][cs*8+ii]   + beta*bs2f(a8[ii]);
#pragma unroll
    for(int ii=0;ii<4;++ii) o1[ii]=Cf[r][cs*8+4+ii] + beta*bs2f(a8[4+ii]);
    *(f32x4*)&dst[0]=o0;
    *(f32x4*)&dst[4]=o1;
  }
}

// ---------------- k_Eout_mfma ----------------
__global__ void __launch_bounds__(256) k_Eout_mfma(const float* newE_in, const float* E,
                       const int* nm, const float* W_Eout, const float* ge, const float* be,
                       float* outE){
  const int t=threadIdx.x;
  const int lane=t&63, w=t>>6;
  const int l15=lane&15, l4=lane>>4;
  const int blk=blockIdx.x;
  const int b=blk>>8, i=blk&255;
  const float mi=(float)nm[b*cN+i];
  bf16x8 bnf[2][4];
#pragma unroll
  for(int ks=0;ks<2;++ks)
#pragma unroll
    for(int n=0;n<4;++n){
      bf16x8 v;
#pragma unroll
      for(int ii=0;ii<8;++ii)
        v[ii]=f2bs(W_Eout[(ks*32+l4*8+ii)*cDE + n*16+l15]);
      bnf[ks][n]=v;
    }
  float gev[4], bev[4];
#pragma unroll
  for(int n=0;n<4;++n){ gev[n]=ge[n*16+l15]; bev[n]=be[n*16+l15]; }

  for(int it=0;it<4;++it){
    const int j0=it*64+w*16;
    const int p0=blk*256 + j0;
    f32x4 acc[4];
#pragma unroll
    for(int n=0;n<4;++n) acc[n]=(f32x4){0.f,0.f,0.f,0.f};
    if(mi>0.f){
#pragma unroll
      for(int ks=0;ks<2;++ks){
        const float* ap=&newE_in[(size_t)(p0+l15)*cDE + ks*32 + l4*8];
        float4 a0=*(const float4*)ap;
        float4 a1=*(const float4*)(ap+4);
        bf16x8 am;
        am[0]=f2bs(a0.x); am[1]=f2bs(a0.y); am[2]=f2bs(a0.z); am[3]=f2bs(a0.w);
        am[4]=f2bs(a1.x); am[5]=f2bs(a1.y); am[6]=f2bs(a1.z); am[7]=f2bs(a1.w);
#pragma unroll
        for(int n=0;n<4;++n)
          acc[n]=__builtin_amdgcn_mfma_f32_16x16x32_bf16(am,bnf[ks][n],acc[n],0,0,0);
      }
    }
    float mj[4];
#pragma unroll
    for(int r=0;r<4;++r) mj[r]=mi*(float)nm[b*cN + j0 + l4*4 + r];
#pragma unroll
    for(int reg=0;reg<4;++reg){
      size_t rowoff=(size_t)(p0 + l4*4 + reg)*cDE;
      float v0=fmaxf(acc[0][reg],0.f)*mj[reg]+E[rowoff + 0*16+l15];
      float v1=fmaxf(acc[1][reg],0.f)*mj[reg]+E[rowoff + 1*16+l15];
      float v2=fmaxf(acc[2][reg],0.f)*mj[reg]+E[rowoff + 2*16+l15];
      float v3=fmaxf(acc[3][reg],0.f)*mj[reg]+E[rowoff + 3*16+l15];
      float s=v0+v1+v2+v3;
      float q=v0*v0+v1*v1+v2*v2+v3*v3;
#pragma unroll
      for(int m=1;m<16;m<<=1){ s+=__shfl_xor(s,m); q+=__shfl_xor(q,m); }
      float mean=s*(1.f/cDE);
      float var=q*(1.f/cDE)-mean*mean;
      float inv=rsqrtf(var+1e-6f);
      outE[rowoff + 0*16+l15]=(v0-mean)*inv*gev[0]+bev[0];
      outE[rowoff + 1*16+l15]=(v1-mean)*inv*gev[1]+bev[1];
      outE[rowoff + 2*16+l15]=(v2-mean)*inv*gev[2]+bev[2];
      outE[rowoff + 3*16+l15]=(v3-mean)*inv*gev[3]+bev[3];
    }
  }
}

// ---------------- k_Gaccum_mfma (GEMM2 B-frags b128 from EmT) ----------------
__global__ void __launch_bounds__(256) k_Gaccum_mfma(const float* E, const int* nm,
                                                     const float* G_kernel,
                                                     float* Npart, float* Dpart){
  const int chunk=blockIdx.x;
  const int b=blockIdx.y;
  const int t=threadIdx.x;
  const int lane=t&63, w=t>>6;
  const int l15=lane&15, l4=lane>>4;

  __shared__ short EmA[128][72];
  __shared__ short EmT[64][136];   // Em transposed: [d][p]
  __shared__ short Wt[128][136];
  __shared__ float mrow[128];
  __shared__ float Dacc[128];
  __shared__ float Dpar[4][128];

  bf16x8 gk[2][8];
#pragma unroll
  for(int kt=0;kt<2;++kt)
#pragma unroll
    for(int n=0;n<8;++n){
      bf16x8 v;
#pragma unroll
      for(int ii=0;ii<8;++ii)
        v[ii]=f2bs(G_kernel[(kt*32+l4*8+ii)*128 + n*16+l15]*0.125f);
      gk[kt][n]=v;
    }

  f32x4 nacc[2][4];
#pragma unroll
  for(int a=0;a<2;++a)
#pragma unroll
    for(int d2=0;d2<4;++d2) nacc[a][d2]=(f32x4){0.f,0.f,0.f,0.f};

  if(t<128) Dacc[t]=0.f;
  __syncthreads();

  const size_t ebase=((size_t)b)<<16;
  for(int sub=0;sub<4;++sub){
    const int rowbase = chunk*512 + sub*128;
    {
      int pr=t>>1, hh=t&1;
      int p=rowbase+pr;
      const float* src=&E[(ebase+p)*cDE + hh*32];
#pragma unroll
      for(int q=0;q<8;++q){
        float4 v=*(const float4*)(src+q*4);
        short4v s4; s4[0]=f2bs(v.x); s4[1]=f2bs(v.y); s4[2]=f2bs(v.z); s4[3]=f2bs(v.w);
        *(short4v*)&EmA[pr][hh*32+q*4]=s4;
        EmT[hh*32+q*4+0][pr]=s4[0];
        EmT[hh*32+q*4+1][pr]=s4[1];
        EmT[hh*32+q*4+2][pr]=s4[2];
        EmT[hh*32+q*4+3][pr]=s4[3];
      }
      if(hh==0) mrow[pr]=(float)(nm[b*cN+(p>>8)]*nm[b*cN+(p&255)]);
    }
    __syncthreads();

    f32x4 wacc[2][8];
#pragma unroll
    for(int m=0;m<2;++m)
#pragma unroll
      for(int n=0;n<8;++n) wacc[m][n]=(f32x4){0.f,0.f,0.f,0.f};
#pragma unroll
    for(int kt=0;kt<2;++kt){
      bf16x8 am[2];
#pragma unroll
      for(int m=0;m<2;++m) am[m]=*(const bf16x8*)&EmA[w*32+m*16+l15][kt*32+l4*8];
#pragma unroll
      for(int m=0;m<2;++m)
#pragma unroll
        for(int n=0;n<8;++n)
          wacc[m][n]=__builtin_amdgcn_mfma_f32_16x16x32_bf16(am[m],gk[kt][n],wacc[m][n],0,0,0);
    }
    float dsum[8];
#pragma unroll
    for(int n=0;n<8;++n) dsum[n]=0.f;
#pragma unroll
    for(int m=0;m<2;++m){
#pragma unroll
      for(int r=0;r<4;++r){
        int pl=w*32+m*16+l4*4+r;
        float mv=mrow[pl];
#pragma unroll
        for(int n=0;n<8;++n){
          float wv=(mv>0.f)?__expf(wacc[m][n][r]):0.f;
          dsum[n]+=wv;
          Wt[n*16+l15][pl]=f2bs(wv);
        }
      }
    }
#pragma unroll
    for(int n=0;n<8;++n){
      float s=dsum[n];
      s+=__shfl_xor(s,16); s+=__shfl_xor(s,32);
      if(l4==0) Dpar[w][n*16+l15]=s;
    }
    __syncthreads();

#pragma unroll
    for(int ks=0;ks<4;++ks){
      bf16x8 aw[2];
#pragma unroll
      for(int a=0;a<2;++a) aw[a]=*(const bf16x8*)&Wt[w*32+a*16+l15][ks*32+l4*8];
      bf16x8 bm[4];
#pragma unroll
      for(int d2=0;d2<4;++d2)
        bm[d2]=*(const bf16x8*)&EmT[d2*16+l15][ks*32+l4*8];
#pragma unroll
      for(int a=0;a<2;++a)
#pragma unroll
        for(int d2=0;d2<4;++d2)
          nacc[a][d2]=__builtin_amdgcn_mfma_f32_16x16x32_bf16(aw[a],bm[d2],nacc[a][d2],0,0,0);
    }
    __syncthreads();
    if(t<128) Dacc[t]+=Dpar[0][t]+Dpar[1][t]+Dpar[2][t]+Dpar[3][t];
    __syncthreads();
  }

  size_t pi=(size_t)b*128+chunk;
  float* np=Npart + pi*128*cDE;
#pragma unroll
  for(int a=0;a<2;++a){
#pragma unroll
    for(int d2=0;d2<4;++d2){
#pragma unroll
      for(int r=0;r<4;++r){
        int k=w*32+a*16+l4*4+r;
        int d=d2*16+l15;
        np[(size_t)k*cDE+d]=nacc[a][d2][r];
      }
    }
  }
  if(t<128) Dpart[pi*128+t]=Dacc[t];
}

// ---------------- combine partials -> Genc ----------------
__global__ void k_Gcombine(const float* Npart, const float* Dpart, float* Genc){
  int bk=blockIdx.x; int b=bk>>7; int k=bk&127;
  int d=threadIdx.x;
  float n=0.f, dd=0.f;
  for(int pi=0;pi<128;++pi){
    size_t base=((size_t)b*128+pi)*128+k;
    n += Npart[base*cDE+d];
    dd += Dpart[base];
  }
  Genc[(size_t)b*8192 + k*cDE + d]=n/dd;
}

// ---------------- aX softmax + X_enc ----------------
__global__ void k_Xenc(const float* X, const int* nm, const float* X_kernel, float* Xenc){
  int k=blockIdx.x;
  int b=blockIdx.y;
  int n=threadIdx.x;
  float m=(float)nm[b*cN+n];
  const float* xr=X+((size_t)b*cN+n)*cDX;
  float acc=0.f;
  for(int c=0;c<cDX;++c) acc += xr[c]*X_kernel[c*64+k];
  float lg=(m>0.f)?acc*(1.f/16.f):-1e9f;
  __shared__ float red[256];
  red[n]=lg; __syncthreads();
  for(int st=128;st>0;st>>=1){ if(n<st) red[n]=fmaxf(red[n],red[n+st]); __syncthreads(); }
  float mx=red[0]; __syncthreads();
  float e=__expf(lg-mx);
  red[n]=e; __syncthreads();
  for(int st=128;st>0;st>>=1){ if(n<st) red[n]+=red[n+st]; __syncthreads(); }
  float denom=red[0]; __syncthreads();
  __shared__ float ps[256];
  ps[n]=e/denom;
  __syncthreads();
  int d=n;
  float s=0.f;
  for(int nn=0;nn<cN;++nn) s += ps[nn]*X[((size_t)b*cN+nn)*cDX+d];
  Xenc[(size_t)b*16384 + k*cDX + d]=s;
}

// ---------------- head partials ----------------
__global__ void __launch_bounds__(256) k_headA(const float* Genc, const float* Xenc,
                        const float* W_Gtrans, const float* W_Xtrans,
                        float* Gp, float* Xp){
  int blk=blockIdx.x;
  int t=threadIdx.x;
  int o=t&127, sub=t>>7;
  int b0=sub*2, b1=sub*2+1;
  __shared__ float ash[4][128];
  if(blk<64){
    int ch=blk;
    for(int l=t;l<512;l+=256){
      int b=l>>7, q=l&127;
      ash[b][q]=Genc[(size_t)b*8192 + ch*128 + q];
    }
    __syncthreads();
    const float* wbase=W_Gtrans + (size_t)ch*128*cDY + o;
    float a0=0.f, a1=0.f;
#pragma unroll 4
    for(int qq=0;qq<128;++qq){
      float w=wbase[(size_t)qq*cDY];
      a0+=ash[b0][qq]*w; a1+=ash[b1][qq]*w;
    }
    Gp[((size_t)b0*64+ch)*cDY+o]=a0;
    Gp[((size_t)b1*64+ch)*cDY+o]=a1;
  } else {
    int ch=blk-64;
    for(int l=t;l<512;l+=256){
      int b=l>>7, q=l&127;
      ash[b][q]=Xenc[(size_t)b*16384 + ch*128 + q];
    }
    __syncthreads();
    const float* wbase=W_Xtrans + (size_t)ch*128*cDY + o;
    float a0=0.f, a1=0.f;
#pragma unroll 4
    for(int qq=0;qq<128;++qq){
      float w=wbase[(size_t)qq*cDY];
      a0+=ash[b0][qq]*w; a1+=ash[b1][qq]*w;
    }
    Xp[((size_t)b0*128+ch)*cDY+o]=a0;
    Xp[((size_t)b1*128+ch)*cDY+o]=a1;
  }
}

// ---------------- head final -> new_y ----------------
__global__ void k_headB(const float* Gp, const float* Xp, const float* W_yout,
                        const float* y, const float* gy, const float* by, float* newy){
  int b=blockIdx.x; int o=threadIdx.x;
  float g=0.f,x=0.f;
  for(int ch=0;ch<64;++ch)  g+=Gp[((size_t)b*64+ch)*cDY+o];
  for(int ch=0;ch<128;++ch) x+=Xp[((size_t)b*128+ch)*cDY+o];
  __shared__ float srow[cDY];
  srow[o]=fmaxf(g,0.f)+fmaxf(x,0.f);
  __syncthreads();
  float h=0.f;
  for(int r=0;r<cDY;++r) h += srow[r]*W_yout[r*cDY+o];
  float v=fmaxf(h,0.f)+y[b*cDY+o];
  __shared__ float red[cDY];
  red[o]=v; __syncthreads();
  for(int st=64;st>0;st>>=1){ if(o<st) red[o]+=red[o+st]; __syncthreads(); }
  float mean=red[0]*(1.f/cDY); __syncthreads();
  float dv=v-mean;
  red[o]=dv*dv; __syncthreads();
  for(int st=64;st>0;st>>=1){ if(o<st) red[o]+=red[o+st]; __syncthreads(); }
  float var=red[0]*(1.f/cDY);
  newy[b*cDY+o]=dv*rsqrtf(var+1e-6f)*gy[o]+by[o];
}

extern "C" void kernel_launch(void* const* d_in, const int* in_sizes, int n_in,
                              void* d_out, int out_size, void* d_ws, size_t ws_size,
                              hipStream_t stream){
  const float* X     =(const float*)d_in[0];
  const float* E     =(const float*)d_in[1];
  const float* y     =(const float*)d_in[2];
  const int*   nm    =(const int*)  d_in[3];
  const float* W_emax=(const float*)d_in[4];
  const float* W_x1  =(const float*)d_in[5];
  const float* Wq    =(const float*)d_in[6];
  const float* Wk    =(const float*)d_in[7];
  const float* Wv    =(const float*)d_in[8];
  const float* Wo    =(const float*)d_in[9];
  const float* W_y2  =(const float*)d_in[10];
  const float* W_x2  =(const float*)d_in[11];
  const float* Wc    =(const float*)d_in[12];
  const float* bc    =(const float*)d_in[13];
  const float* salpha=(const float*)d_in[14];
  const float* W_Eout=(const float*)d_in[15];
  const float* G_kern=(const float*)d_in[16];
  const float* X_kern=(const float*)d_in[17];
  const float* W_Gtr =(const float*)d_in[18];
  const float* W_Xtr =(const float*)d_in[19];
  const float* W_yout=(const float*)d_in[20];
  const float* gx    =(const float*)d_in[21];
  const float* bx    =(const float*)d_in[22];
  const float* ge    =(const float*)d_in[23];
  const float* be    =(const float*)d_in[24];
  const float* gy    =(const float*)d_in[25];
  const float* by    =(const float*)d_in[26];

  char* wsb=(char*)d_ws;
  bf16* Gbf=(bf16*)wsb;                        // [0,32M)
  short* Gs=(short*)wsb;
  short* Bt2=(short*)(wsb+33554432);           // [32M,64M)
  short* Gts=(short*)(wsb+67108864);           // [64M,96M)
  float* Npart=(float*)(wsb+33554432);         // aliases Bt2 (dead after poly2)
  float* f32=(float*)(wsb+100663296);          // [96M,...)
  float* sim  = f32+F_SIM;
  float* P    = f32+F_P;
  float* Dpart= f32+F_NP;
  float* Gp   = f32+F_GP;
  float* Xp   = f32+F_XP;
  float* S    = f32+F_S;
  float* eenc = f32+F_EENC;
  float* xplus= f32+F_XPL;
  float* qb   = f32+F_QB;
  float* kb   = f32+F_KB;
  float* vb   = f32+F_VB;
  float* yw   = f32+F_YW;
  float* xpy  = f32+F_XPY;
  float* coeff= f32+F_COEF;
  float* Genc = f32+F_GENC;
  float* Xenc = f32+F_XENC;

  float* out=(float*)d_out;
  float* newX=out;
  float* newE_out=out+262144;
  float* newy=out+17039360;

  k_coeff_yw<<<cB,256,0,stream>>>(y,Wc,bc,W_y2,coeff,yw);
  k_reduceE<<<cB*cN,dim3(64,4),0,stream>>>(E,nm,S);
  k_eenc<<<cB*cN,256,0,stream>>>(S,W_emax,nm,eenc);
  k_xplus<<<cB*cN,256,0,stream>>>(X,eenc,W_x1,nm,xplus);
  k_qkv<<<cB*cN,256,0,stream>>>(xplus,Wq,Wk,Wv,qb,kb,vb);
  k_attn_softmax<<<cB*cNH*cN,256,0,stream>>>(qb,kb,nm,P);
  k_attn_out<<<cB*cN,256,0,stream>>>(P,vb,Wo,X,nm,gx,bx,newX);
  k_xplusy<<<cB*cN,256,0,stream>>>(X,yw,W_x2,xpy);
  k_sim<<<dim3(16,16,cB),dim3(16,16),0,stream>>>(xpy,sim);
  k_G<<<cB*cN,256,0,stream>>>(E,sim,nm,salpha,Gbf);
  k_transp<<<dim3(2,2,cB*cDE),256,0,stream>>>(Gs,Gts);
  k_bmm_t<<<dim3(2,2,cB*cDE),256,0,stream>>>(Gs,Gts,Bt2,coeff);
  k_bmm_f<<<dim3(2,2,cB*cDE),256,0,stream>>>(Gs,Bt2,newE_out,coeff);
  k_Eout_mfma<<<1024,256,0,stream>>>(newE_out,E,nm,W_Eout,ge,be,newE_out);
  k_Gaccum_mfma<<<dim3(128,cB),256,0,stream>>>(E,nm,G_kern,Npart,Dpart);
  k_Gcombine<<<cB*128,64,0,stream>>>(Npart,Dpart,Genc);
  k_Xenc<<<dim3(64,cB),256,0,stream>>>(X,nm,X_kern,Xenc);
  k_headA<<<192,256,0,stream>>>(Genc,Xenc,W_Gtr,W_Xtr,Gp,Xp);
  k_headB<<<cB,128,0,stream>>>(Gp,Xp,W_yout,y,gy,by,newy);
}

// Round 14
// 390.078 us; speedup vs baseline: 4.2744x; 1.0590x over previous
//
#include <hip/hip_runtime.h>
#include <hip/hip_bf16.h>

typedef __hip_bfloat16 bf16;
__device__ __forceinline__ bf16 tobf(float v){ return __float2bfloat16(v); }
__device__ __forceinline__ float frombf(bf16 v){ return __bfloat162float(v); }
__device__ __forceinline__ short f2bs(float x){ bf16 h=tobf(x); return *reinterpret_cast<short*>(&h); }
__device__ __forceinline__ float bs2f(short s){ unsigned int v=((unsigned int)(unsigned short)s)<<16; return __int_as_float((int)v); }

typedef __attribute__((ext_vector_type(8))) short bf16x8;
typedef __attribute__((ext_vector_type(4))) short short4v;
typedef __attribute__((ext_vector_type(4))) float f32x4;
typedef __attribute__((ext_vector_type(4))) int int4v;

static constexpr int cB=4, cN=256, cDX=256, cDE=64, cDY=128, cNH=8, cDF=32;

// ---- workspace layout (bytes) ----
// [0,   32M)  G    bf16
// [32M, 64M)  Bt2  bf16 (poly1 out, transposed)  -- after poly2: Npart f32 (16.8MB)
// [64M, 96M)  Gt   bf16 (G transposed)  -- after bmm_t: NEWEbf bf16 (33.5MB, poly2 out)
// [96M, ...)  f32 region (offsets in floats below)
static constexpr size_t F_SIM  = 0;
static constexpr size_t F_P    = 262144;
static constexpr size_t F_NP   = 2359296;
static constexpr size_t F_GP   = F_NP + 1048576;
static constexpr size_t F_XP   = F_NP + 1048576 + 32768;
static constexpr size_t F_S    = 6619136;
static constexpr size_t F_EENC = 6684672;
static constexpr size_t F_XPL  = 6946816;
static constexpr size_t F_QB   = 7208960;
static constexpr size_t F_KB   = 7471104;
static constexpr size_t F_VB   = 7733248;
static constexpr size_t F_YW   = 7995392;
static constexpr size_t F_XPY  = 7996416;
static constexpr size_t F_COEF = 8258560;
static constexpr size_t F_GENC = 8258576;
static constexpr size_t F_XENC = 8291344;

// ---------------- coeff = y@Wc+bc ; yw = relu(y@W_y2) ----------------
__global__ void k_coeff_yw(const float* y, const float* Wc, const float* bc,
                           const float* W_y2, float* coeff, float* yw){
  int b = blockIdx.x; int f = threadIdx.x;
  float acc = 0.f;
  for(int r=0;r<cDY;++r) acc += y[b*cDY+r]*W_y2[r*cDX+f];
  yw[b*cDX+f] = fmaxf(acc,0.f);
  if (f < 3){
    float c = bc[f];
    for(int r=0;r<cDY;++r) c += y[b*cDY+r]*Wc[r*3+f];
    coeff[b*3+f] = c;
  }
}

// ---------------- S[b,i,d] = sum_j E[b,i,j,d]*m_j ----------------
__global__ void k_reduceE(const float* E, const int* nm, float* S){
  int bi = blockIdx.x; int b = bi / cN;
  int d = threadIdx.x;
  int jy = threadIdx.y;
  const float* Eb = E + (size_t)bi*cN*cDE;
  float acc = 0.f;
  for(int j=jy;j<cN;j+=4){
    acc += Eb[j*cDE+d] * (float)nm[b*cN+j];
  }
  __shared__ float red[4][64];
  red[jy][d]=acc; __syncthreads();
  if (jy==0) S[(size_t)bi*cDE+d] = red[0][d]+red[1][d]+red[2][d]+red[3][d];
}

// ---------------- e_enc ----------------
__global__ void k_eenc(const float* S, const float* W_emax, const int* nm, float* eenc){
  int bi = blockIdx.x; int b = bi/cN; int i = bi%cN;
  int f = threadIdx.x;
  __shared__ float s[cDE];
  if (f<cDE) s[f]=S[(size_t)bi*cDE+f];
  __syncthreads();
  float acc=0.f;
  for(int d=0;d<cDE;++d) acc += s[d]*W_emax[d*cDX+f];
  float mi=(float)nm[b*cN+i];
  eenc[(size_t)bi*cDX+f] = fmaxf(acc*mi*(1.f/cN), 0.f);
}

// ---------------- xplus ----------------
__global__ void k_xplus(const float* X, const float* eenc, const float* W_x1,
                        const int* nm, float* xplus){
  int bi=blockIdx.x; int b=bi/cN; int i=bi%cN;
  int f=threadIdx.x;
  __shared__ float row[cDX];
  row[f]=eenc[(size_t)bi*cDX+f];
  __syncthreads();
  float acc=0.f;
  for(int c=0;c<cDX;++c) acc += row[c]*W_x1[c*cDX+f];
  float mi=(float)nm[b*cN+i];
  xplus[(size_t)bi*cDX+f] = (X[(size_t)bi*cDX+f] + fmaxf(acc,0.f))*mi;
}

// ---------------- q,k,v ----------------
__global__ void k_qkv(const float* xplus, const float* Wq, const float* Wk, const float* Wv,
                      float* qb, float* kb, float* vb){
  int bi=blockIdx.x; int f=threadIdx.x;
  __shared__ float row[cDX];
  row[f]=xplus[(size_t)bi*cDX+f];
  __syncthreads();
  float aq=0,ak=0,av=0;
  for(int c=0;c<cDX;++c){ float r=row[c]; aq+=r*Wq[c*cDX+f]; ak+=r*Wk[c*cDX+f]; av+=r*Wv[c*cDX+f]; }
  qb[(size_t)bi*cDX+f]=aq; kb[(size_t)bi*cDX+f]=ak; vb[(size_t)bi*cDX+f]=av;
}

// ---------------- attention softmax ----------------
__global__ void k_attn_softmax(const float* qb, const float* kb, const int* nm, float* P){
  int id=blockIdx.x; int b=id/(cNH*cN); int rem=id%(cNH*cN); int h=rem/cN; int i=rem%cN;
  int j=threadIdx.x;
  __shared__ float qrow[cDF];
  if (j<cDF) qrow[j]=qb[((size_t)b*cN+i)*cDX + h*cDF + j];
  __syncthreads();
  const float* krow = kb + ((size_t)b*cN+j)*cDX + h*cDF;
  float s=0.f;
  for(int c=0;c<cDF;++c) s += qrow[c]*krow[c];
  s *= 0.17677669529663687f;
  float val = (nm[b*cN+j]>0) ? s : -1e9f;
  __shared__ float red[256];
  red[j]=val; __syncthreads();
  for(int st=128;st>0;st>>=1){ if(j<st) red[j]=fmaxf(red[j],red[j+st]); __syncthreads(); }
  float mx=red[0]; __syncthreads();
  float e=__expf(val-mx);
  red[j]=e; __syncthreads();
  for(int st=128;st>0;st>>=1){ if(j<st) red[j]+=red[j+st]; __syncthreads(); }
  float denom=red[0];
  P[(size_t)id*cN + j] = e/denom;
}

// ---------------- attn out + LN -> new_X ----------------
__global__ void k_attn_out(const float* P, const float* vb, const float* Wo,
                           const float* X, const int* nm, const float* gx, const float* bx,
                           float* newX){
  int bi=blockIdx.x; int b=bi/cN; int i=bi%cN;
  int t=threadIdx.x;
  __shared__ float p8[cNH][cN];
  for(int h=0;h<cNH;++h) p8[h][t]=P[(((size_t)b*cNH+h)*cN+i)*cN + t];
  __syncthreads();
  int h=t/cDF;
  float acc=0.f;
  for(int j=0;j<cN;++j) acc += p8[h][j]*vb[((size_t)b*cN+j)*cDX + t];
  __shared__ float arow[cDX];
  arow[t]=acc; __syncthreads();
  float o=0.f;
  for(int c=0;c<cDX;++c) o += arow[c]*Wo[c*cDX+t];
  float mi=(float)nm[b*cN+i];
  float v = o*mi + X[(size_t)bi*cDX+t];
  __shared__ float red[256];
  red[t]=v; __syncthreads();
  for(int st=128;st>0;st>>=1){ if(t<st) red[t]+=red[t+st]; __syncthreads(); }
  float mean=red[0]*(1.f/cDX); __syncthreads();
  float dv=v-mean;
  red[t]=dv*dv; __syncthreads();
  for(int st=128;st>0;st>>=1){ if(t<st) red[t]+=red[t+st]; __syncthreads(); }
  float var=red[0]*(1.f/cDX);
  newX[(size_t)bi*cDX+t]=dv*rsqrtf(var+1e-6f)*gx[t]+bx[t];
}

// ---------------- xplusy ----------------
__global__ void k_xplusy(const float* X, const float* yw, const float* W_x2, float* xpy){
  int bi=blockIdx.x; int b=bi/cN;
  int f=threadIdx.x;
  __shared__ float row[cDX];
  row[f]=X[(size_t)bi*cDX+f]+yw[b*cDX+f];
  __syncthreads();
  float acc=0.f;
  for(int c=0;c<cDX;++c) acc += row[c]*W_x2[c*cDX+f];
  xpy[(size_t)bi*cDX+f]=fmaxf(acc,0.f);
}

// ---------------- sim ----------------
__global__ void k_sim(const float* xp, float* sim){
  int b=blockIdx.z;
  int tx=threadIdx.x, ty=threadIdx.y;
  __shared__ float Aa[16][17], Bb[16][17];
  const float* base = xp + (size_t)b*cN*cDX;
  float acc=0.f;
  for(int kt=0;kt<cDX;kt+=16){
    Aa[ty][tx]=base[(size_t)(blockIdx.y*16+ty)*cDX + kt+tx];
    Bb[ty][tx]=base[(size_t)(blockIdx.x*16+ty)*cDX + kt+tx];
    __syncthreads();
    for(int c=0;c<16;++c) acc += Aa[ty][c]*Bb[tx][c];
    __syncthreads();
  }
  sim[((size_t)b*cN + blockIdx.y*16+ty)*cN + blockIdx.x*16+tx] = acc*(1.f/16.f);
}

// ---------------- G = (alpha*sim + E)*emask (bf16) ----------------
__global__ void k_G(const float* E, const float* sim, const int* nm, const float* alpha_p,
                    bf16* G){
  int bi=blockIdx.x; int b=bi/cN; int i=bi%cN;
  float mi=(float)nm[b*cN+i];
  float alpha=alpha_p[0];
  size_t base=(size_t)bi*cN*cDE;
  for(int t=threadIdx.x;t<cN*cDE;t+=blockDim.x){
    int j=t>>6;
    float mj=(float)nm[b*cN+j];
    G[base+t]=tobf((alpha*sim[(size_t)bi*cN+j]+E[base+t])*mi*mj);
  }
}

// ---------------- per-slice transpose: Gt[bc][q][p] = G[bc][p][q] ----------------
__global__ void __launch_bounds__(256) k_transp(const short* G, short* Gt){
  const int bc=blockIdx.z;
  const int p0=blockIdx.y*128, q0=blockIdx.x*128;
  const int t=threadIdx.x;
  __shared__ short T[128][136];
  const short* src=G+(size_t)bc*65536;
  short* dst=Gt+(size_t)bc*65536;
#pragma unroll
  for(int l=0;l<8;++l){
    int idx=t+l*256;
    int r=idx>>4, seg=idx&15;
    *(int4v*)&T[r][seg*8]=*(const int4v*)&src[(size_t)(p0+r)*256 + q0 + seg*8];
  }
  __syncthreads();
  int qq=t&127, hf=t>>7;
#pragma unroll
  for(int ss=0;ss<8;++ss){
    bf16x8 v;
#pragma unroll
    for(int ii=0;ii<8;++ii) v[ii]=T[hf*64+ss*8+ii][qq];
    *(bf16x8*)&dst[(size_t)(q0+qq)*256 + p0 + hf*64 + ss*8]=v;
  }
}

// ---------------- poly1: Bt2 = (c0*(G@G) + c1*G)^T ----------------
// Round-11 epilogue; writeback thread mapping permuted (c=t>>1, hf=t&1) so
// lane-pairs emit 32B-contiguous runs (same (c,hf) set, pure bijection).
__global__ void __launch_bounds__(256) k_bmm_t(const short* G, const short* Gt, short* Bt2,
                                               const float* coeff){
  const int bc=blockIdx.z; const int b=bc>>6;
  const float alpha=coeff[b*3+0];
  const float beta=coeff[b*3+1];
  const short* Ag=G+(size_t)bc*65536;
  const short* At=Gt+(size_t)bc*65536;
  short* Ct=Bt2+(size_t)bc*65536;
  const int row0=blockIdx.y*128, col0=blockIdx.x*128;
  const int t=threadIdx.x;
  const int lane=t&63, w=t>>6;
  const int wr=w>>1, wc=w&1;
  const int l15=lane&15, l4=lane>>4;
  __shared__ char smem[36864];
  short (*A_s)[72]=(short(*)[72])smem;
  short (*B_s)[72]=(short(*)[72])(smem+18432);
  float (*Cf)[132]=(float(*)[132])smem;   // 16x132 floats = 8448 B, aliased after compute
  f32x4 acc[4][4];
#pragma unroll
  for(int m=0;m<4;++m)
#pragma unroll
    for(int n=0;n<4;++n) acc[m][n]=(f32x4){0.f,0.f,0.f,0.f};

  for(int kt=0;kt<256;kt+=64){
#pragma unroll
    for(int l=0;l<4;++l){
      int idx=t+l*256;
      int r=idx>>3, seg=idx&7;
      *(int4v*)&A_s[r][seg*8]=*(const int4v*)&Ag[(size_t)(row0+r)*256 + kt + seg*8];
      *(int4v*)&B_s[r][seg*8]=*(const int4v*)&At[(size_t)(col0+r)*256 + kt + seg*8];
    }
    __syncthreads();
#pragma unroll
    for(int ks=0;ks<64;ks+=32){
      bf16x8 am[4], bn[4];
#pragma unroll
      for(int m=0;m<4;++m) am[m]=*(const bf16x8*)&A_s[wr*64+m*16+l15][ks+l4*8];
#pragma unroll
      for(int n=0;n<4;++n) bn[n]=*(const bf16x8*)&B_s[wc*64+n*16+l15][ks+l4*8];
#pragma unroll
      for(int m=0;m<4;++m)
#pragma unroll
        for(int n=0;n<4;++n)
          acc[m][n]=__builtin_amdgcn_mfma_f32_16x16x32_bf16(am[m],bn[n],acc[m][n],0,0,0);
    }
    __syncthreads();
  }
  // epilogue: 8 slices of 16 rows
  for(int rs=0;rs<8;++rs){
    if(rs) __syncthreads();
    int m=rs&3;
    if(wr==(rs>>2)){
#pragma unroll
      for(int n=0;n<4;++n)
#pragma unroll
        for(int r=0;r<4;++r)
          Cf[l4*4+r][wc*64+n*16+l15]=acc[m][n][r];
    }
    __syncthreads();
    int c=t>>1, hf=t&1;
    const short* gsrc=&At[(size_t)(col0+c)*256 + row0 + rs*16 + hf*8];
    short* dst=&Ct[(size_t)(col0+c)*256 + row0 + rs*16 + hf*8];
    bf16x8 a8=*(const bf16x8*)gsrc;
    bf16x8 o8;
#pragma unroll
    for(int ii=0;ii<8;++ii)
      o8[ii]=f2bs(alpha*Cf[hf*8+ii][c] + beta*bs2f(a8[ii]));
    *(bf16x8*)dst=o8;
  }
}

// ---------------- poly2: NEWEbf = bf16(G@Bbuf + c2*G)  (B from Bt2 rows) ----------------
__global__ void __launch_bounds__(256) k_bmm_f(const short* G, const short* Bt2, short* Cbf,
                                               const float* coeff){
  const int bc=blockIdx.z; const int b=bc>>6;
  const float beta=coeff[b*3+2];
  const short* Ag=G+(size_t)bc*65536;
  const short* Bt=Bt2+(size_t)bc*65536;
  short* Cb=Cbf+(size_t)bc*65536;
  const int row0=blockIdx.y*128, col0=blockIdx.x*128;
  const int t=threadIdx.x;
  const int lane=t&63, w=t>>6;
  const int wr=w>>1, wc=w&1;
  const int l15=lane&15, l4=lane>>4;
  __shared__ char smem[36864];
  short (*A_s)[72]=(short(*)[72])smem;
  short (*B_s)[72]=(short(*)[72])(smem+18432);
  float (*Cf)[132]=(float(*)[132])smem;
  f32x4 acc[4][4];
#pragma unroll
  for(int m=0;m<4;++m)
#pragma unroll
    for(int n=0;n<4;++n) acc[m][n]=(f32x4){0.f,0.f,0.f,0.f};

  for(int kt=0;kt<256;kt+=64){
#pragma unroll
    for(int l=0;l<4;++l){
      int idx=t+l*256;
      int r=idx>>3, seg=idx&7;
      *(int4v*)&A_s[r][seg*8]=*(const int4v*)&Ag[(size_t)(row0+r)*256 + kt + seg*8];
      *(int4v*)&B_s[r][seg*8]=*(const int4v*)&Bt[(size_t)(col0+r)*256 + kt + seg*8];
    }
    __syncthreads();
#pragma unroll
    for(int ks=0;ks<64;ks+=32){
      bf16x8 am[4], bn[4];
#pragma unroll
      for(int m=0;m<4;++m) am[m]=*(const bf16x8*)&A_s[wr*64+m*16+l15][ks+l4*8];
#pragma unroll
      for(int n=0;n<4;++n) bn[n]=*(const bf16x8*)&B_s[wc*64+n*16+l15][ks+l4*8];
#pragma unroll
      for(int m=0;m<4;++m)
#pragma unroll
        for(int n=0;n<4;++n)
          acc[m][n]=__builtin_amdgcn_mfma_f32_16x16x32_bf16(am[m],bn[n],acc[m][n],0,0,0);
    }
    __syncthreads();
  }
  for(int rs=0;rs<8;++rs){
    if(rs) __syncthreads();
    int m=rs&3;
    if(wr==(rs>>2)){
#pragma unroll
      for(int n=0;n<4;++n)
#pragma unroll
        for(int r=0;r<4;++r)
          Cf[l4*4+r][wc*64+n*16+l15]=acc[m][n][r];
    }
    __syncthreads();
    int r=t>>4, cs=t&15;
    int row=row0+rs*16+r;
    const short* asrc=&Ag[(size_t)row*256 + col0 + cs*8];
    short* dst=&Cb[(size_t)row*256 + col0 + cs*8];
    bf16x8 a8=*(const bf16x8*)asrc;
    bf16x8 o8;
#pragma unroll
    for(int ii=0;ii<8;++ii)
      o8[ii]=f2bs(Cf[r][cs*8+ii] + beta*bs2f(a8[ii]));
    *(bf16x8*)dst=o8;
  }
}

// ---------------- k_Eout_mfma (reads bf16 NEWE staging) ----------------
__global__ void __launch_bounds__(256) k_Eout_mfma(const short* newE_in, const float* E,
                       const int* nm, const float* W_Eout, const float* ge, const float* be,
                       float* outE){
  const int t=threadIdx.x;
  const int lane=t&63, w=t>>6;
  const int l15=lane&15, l4=lane>>4;
  const int blk=blockIdx.x;
  const int b=blk>>8, i=blk&255;
  const float mi=(float)nm[b*cN+i];
  bf16x8 bnf[2][4];
#pragma unroll
  for(int ks=0;ks<2;++ks)
#pragma unroll
    for(int n=0;n<4;++n){
      bf16x8 v;
#pragma unroll
      for(int ii=0;ii<8;++ii)
        v[ii]=f2bs(W_Eout[(ks*32+l4*8+ii)*cDE + n*16+l15]);
      bnf[ks][n]=v;
    }
  float gev[4], bev[4];
#pragma unroll
  for(int n=0;n<4;++n){ gev[n]=ge[n*16+l15]; bev[n]=be[n*16+l15]; }

  for(int it=0;it<4;++it){
    const int j0=it*64+w*16;
    const int p0=blk*256 + j0;
    f32x4 acc[4];
#pragma unroll
    for(int n=0;n<4;++n) acc[n]=(f32x4){0.f,0.f,0.f,0.f};
    if(mi>0.f){
#pragma unroll
      for(int ks=0;ks<2;++ks){
        bf16x8 am=*(const bf16x8*)&newE_in[(size_t)(p0+l15)*cDE + ks*32 + l4*8];
#pragma unroll
        for(int n=0;n<4;++n)
          acc[n]=__builtin_amdgcn_mfma_f32_16x16x32_bf16(am,bnf[ks][n],acc[n],0,0,0);
      }
    }
    float mj[4];
#pragma unroll
    for(int r=0;r<4;++r) mj[r]=mi*(float)nm[b*cN + j0 + l4*4 + r];
#pragma unroll
    for(int reg=0;reg<4;++reg){
      size_t rowoff=(size_t)(p0 + l4*4 + reg)*cDE;
      float v0=fmaxf(acc[0][reg],0.f)*mj[reg]+E[rowoff + 0*16+l15];
      float v1=fmaxf(acc[1][reg],0.f)*mj[reg]+E[rowoff + 1*16+l15];
      float v2=fmaxf(acc[2][reg],0.f)*mj[reg]+E[rowoff + 2*16+l15];
      float v3=fmaxf(acc[3][reg],0.f)*mj[reg]+E[rowoff + 3*16+l15];
      float s=v0+v1+v2+v3;
      float q=v0*v0+v1*v1+v2*v2+v3*v3;
#pragma unroll
      for(int m=1;m<16;m<<=1){ s+=__shfl_xor(s,m); q+=__shfl_xor(q,m); }
      float mean=s*(1.f/cDE);
      float var=q*(1.f/cDE)-mean*mean;
      float inv=rsqrtf(var+1e-6f);
      outE[rowoff + 0*16+l15]=(v0-mean)*inv*gev[0]+bev[0];
      outE[rowoff + 1*16+l15]=(v1-mean)*inv*gev[1]+bev[1];
      outE[rowoff + 2*16+l15]=(v2-mean)*inv*gev[2]+bev[2];
      outE[rowoff + 3*16+l15]=(v3-mean)*inv*gev[3]+bev[3];
    }
  }
}

// ---------------- k_Gaccum_mfma (GEMM2 B-frags b128 from EmT) ----------------
__global__ void __launch_bounds__(256) k_Gaccum_mfma(const float* E, const int* nm,
                                                     const float* G_kernel,
                                                     float* Npart, float* Dpart){
  const int chunk=blockIdx.x;
  const int b=blockIdx.y;
  const int t=threadIdx.x;
  const int lane=t&63, w=t>>6;
  const int l15=lane&15, l4=lane>>4;

  __shared__ short EmA[128][72];
  __shared__ short EmT[64][136];
  __shared__ short Wt[128][136];
  __shared__ float mrow[128];
  __shared__ float Dacc[128];
  __shared__ float Dpar[4][128];

  bf16x8 gk[2][8];
#pragma unroll
  for(int kt=0;kt<2;++kt)
#pragma unroll
    for(int n=0;n<8;++n){
      bf16x8 v;
#pragma unroll
      for(int ii=0;ii<8;++ii)
        v[ii]=f2bs(G_kernel[(kt*32+l4*8+ii)*128 + n*16+l15]*0.125f);
      gk[kt][n]=v;
    }

  f32x4 nacc[2][4];
#pragma unroll
  for(int a=0;a<2;++a)
#pragma unroll
    for(int d2=0;d2<4;++d2) nacc[a][d2]=(f32x4){0.f,0.f,0.f,0.f};

  if(t<128) Dacc[t]=0.f;
  __syncthreads();

  const size_t ebase=((size_t)b)<<16;
  for(int sub=0;sub<4;++sub){
    const int rowbase = chunk*512 + sub*128;
    {
      int pr=t>>1, hh=t&1;
      int p=rowbase+pr;
      const float* src=&E[(ebase+p)*cDE + hh*32];
#pragma unroll
      for(int q=0;q<8;++q){
        float4 v=*(const float4*)(src+q*4);
        short4v s4; s4[0]=f2bs(v.x); s4[1]=f2bs(v.y); s4[2]=f2bs(v.z); s4[3]=f2bs(v.w);
        *(short4v*)&EmA[pr][hh*32+q*4]=s4;
        EmT[hh*32+q*4+0][pr]=s4[0];
        EmT[hh*32+q*4+1][pr]=s4[1];
        EmT[hh*32+q*4+2][pr]=s4[2];
        EmT[hh*32+q*4+3][pr]=s4[3];
      }
      if(hh==0) mrow[pr]=(float)(nm[b*cN+(p>>8)]*nm[b*cN+(p&255)]);
    }
    __syncthreads();

    f32x4 wacc[2][8];
#pragma unroll
    for(int m=0;m<2;++m)
#pragma unroll
      for(int n=0;n<8;++n) wacc[m][n]=(f32x4){0.f,0.f,0.f,0.f};
#pragma unroll
    for(int kt=0;kt<2;++kt){
      bf16x8 am[2];
#pragma unroll
      for(int m=0;m<2;++m) am[m]=*(const bf16x8*)&EmA[w*32+m*16+l15][kt*32+l4*8];
#pragma unroll
      for(int m=0;m<2;++m)
#pragma unroll
        for(int n=0;n<8;++n)
          wacc[m][n]=__builtin_amdgcn_mfma_f32_16x16x32_bf16(am[m],gk[kt][n],wacc[m][n],0,0,0);
    }
    float dsum[8];
#pragma unroll
    for(int n=0;n<8;++n) dsum[n]=0.f;
#pragma unroll
    for(int m=0;m<2;++m){
#pragma unroll
      for(int r=0;r<4;++r){
        int pl=w*32+m*16+l4*4+r;
        float mv=mrow[pl];
#pragma unroll
        for(int n=0;n<8;++n){
          float wv=(mv>0.f)?__expf(wacc[m][n][r]):0.f;
          dsum[n]+=wv;
          Wt[n*16+l15][pl]=f2bs(wv);
        }
      }
    }
#pragma unroll
    for(int n=0;n<8;++n){
      float s=dsum[n];
      s+=__shfl_xor(s,16); s+=__shfl_xor(s,32);
      if(l4==0) Dpar[w][n*16+l15]=s;
    }
    __syncthreads();

#pragma unroll
    for(int ks=0;ks<4;++ks){
      bf16x8 aw[2];
#pragma unroll
      for(int a=0;a<2;++a) aw[a]=*(const bf16x8*)&Wt[w*32+a*16+l15][ks*32+l4*8];
      bf16x8 bm[4];
#pragma unroll
      for(int d2=0;d2<4;++d2)
        bm[d2]=*(const bf16x8*)&EmT[d2*16+l15][ks*32+l4*8];
#pragma unroll
      for(int a=0;a<2;++a)
#pragma unroll
        for(int d2=0;d2<4;++d2)
          nacc[a][d2]=__builtin_amdgcn_mfma_f32_16x16x32_bf16(aw[a],bm[d2],nacc[a][d2],0,0,0);
    }
    __syncthreads();
    if(t<128) Dacc[t]+=Dpar[0][t]+Dpar[1][t]+Dpar[2][t]+Dpar[3][t];
    __syncthreads();
  }

  size_t pi=(size_t)b*128+chunk;
  float* np=Npart + pi*128*cDE;
#pragma unroll
  for(int a=0;a<2;++a){
#pragma unroll
    for(int d2=0;d2<4;++d2){
#pragma unroll
      for(int r=0;r<4;++r){
        int k=w*32+a*16+l4*4+r;
        int d=d2*16+l15;
        np[(size_t)k*cDE+d]=nacc[a][d2][r];
      }
    }
  }
  if(t<128) Dpart[pi*128+t]=Dacc[t];
}

// ---------------- combine partials -> Genc ----------------
__global__ void k_Gcombine(const float* Npart, const float* Dpart, float* Genc){
  int bk=blockIdx.x; int b=bk>>7; int k=bk&127;
  int d=threadIdx.x;
  float n=0.f, dd=0.f;
  for(int pi=0;pi<128;++pi){
    size_t base=((size_t)b*128+pi)*128+k;
    n += Npart[base*cDE+d];
    dd += Dpart[base];
  }
  Genc[(size_t)b*8192 + k*cDE + d]=n/dd;
}

// ---------------- aX softmax + X_enc ----------------
__global__ void k_Xenc(const float* X, const int* nm, const float* X_kernel, float* Xenc){
  int k=blockIdx.x;
  int b=blockIdx.y;
  int n=threadIdx.x;
  float m=(float)nm[b*cN+n];
  const float* xr=X+((size_t)b*cN+n)*cDX;
  float acc=0.f;
  for(int c=0;c<cDX;++c) acc += xr[c]*X_kernel[c*64+k];
  float lg=(m>0.f)?acc*(1.f/16.f):-1e9f;
  __shared__ float red[256];
  red[n]=lg; __syncthreads();
  for(int st=128;st>0;st>>=1){ if(n<st) red[n]=fmaxf(red[n],red[n+st]); __syncthreads(); }
  float mx=red[0]; __syncthreads();
  float e=__expf(lg-mx);
  red[n]=e; __syncthreads();
  for(int st=128;st>0;st>>=1){ if(n<st) red[n]+=red[n+st]; __syncthreads(); }
  float denom=red[0]; __syncthreads();
  __shared__ float ps[256];
  ps[n]=e/denom;
  __syncthreads();
  int d=n;
  float s=0.f;
  for(int nn=0;nn<cN;++nn) s += ps[nn]*X[((size_t)b*cN+nn)*cDX+d];
  Xenc[(size_t)b*16384 + k*cDX + d]=s;
}

// ---------------- head partials ----------------
__global__ void __launch_bounds__(256) k_headA(const float* Genc, const float* Xenc,
                        const float* W_Gtrans, const float* W_Xtrans,
                        float* Gp, float* Xp){
  int blk=blockIdx.x;
  int t=threadIdx.x;
  int o=t&127, sub=t>>7;
  int b0=sub*2, b1=sub*2+1;
  __shared__ float ash[4][128];
  if(blk<64){
    int ch=blk;
    for(int l=t;l<512;l+=256){
      int b=l>>7, q=l&127;
      ash[b][q]=Genc[(size_t)b*8192 + ch*128 + q];
    }
    __syncthreads();
    const float* wbase=W_Gtrans + (size_t)ch*128*cDY + o;
    float a0=0.f, a1=0.f;
#pragma unroll 4
    for(int qq=0;qq<128;++qq){
      float w=wbase[(size_t)qq*cDY];
      a0+=ash[b0][qq]*w; a1+=ash[b1][qq]*w;
    }
    Gp[((size_t)b0*64+ch)*cDY+o]=a0;
    Gp[((size_t)b1*64+ch)*cDY+o]=a1;
  } else {
    int ch=blk-64;
    for(int l=t;l<512;l+=256){
      int b=l>>7, q=l&127;
      ash[b][q]=Xenc[(size_t)b*16384 + ch*128 + q];
    }
    __syncthreads();
    const float* wbase=W_Xtrans + (size_t)ch*128*cDY + o;
    float a0=0.f, a1=0.f;
#pragma unroll 4
    for(int qq=0;qq<128;++qq){
      float w=wbase[(size_t)qq*cDY];
      a0+=ash[b0][qq]*w; a1+=ash[b1][qq]*w;
    }
    Xp[((size_t)b0*128+ch)*cDY+o]=a0;
    Xp[((size_t)b1*128+ch)*cDY+o]=a1;
  }
}

// ---------------- head final -> new_y ----------------
__global__ void k_headB(const float* Gp, const float* Xp, const float* W_yout,
                        const float* y, const float* gy, const float* by, float* newy){
  int b=blockIdx.x; int o=threadIdx.x;
  float g=0.f,x=0.f;
  for(int ch=0;ch<64;++ch)  g+=Gp[((size_t)b*64+ch)*cDY+o];
  for(int ch=0;ch<128;++ch) x+=Xp[((size_t)b*128+ch)*cDY+o];
  __shared__ float srow[cDY];
  srow[o]=fmaxf(g,0.f)+fmaxf(x,0.f);
  __syncthreads();
  float h=0.f;
  for(int r=0;r<cDY;++r) h += srow[r]*W_yout[r*cDY+o];
  float v=fmaxf(h,0.f)+y[b*cDY+o];
  __shared__ float red[cDY];
  red[o]=v; __syncthreads();
  for(int st=64;st>0;st>>=1){ if(o<st) red[o]+=red[o+st]; __syncthreads(); }
  float mean=red[0]*(1.f/cDY); __syncthreads();
  float dv=v-mean;
  red[o]=dv*dv; __syncthreads();
  for(int st=64;st>0;st>>=1){ if(o<st) red[o]+=red[o+st]; __syncthreads(); }
  float var=red[0]*(1.f/cDY);
  newy[b*cDY+o]=dv*rsqrtf(var+1e-6f)*gy[o]+by[o];
}

extern "C" void kernel_launch(void* const* d_in, const int* in_sizes, int n_in,
                              void* d_out, int out_size, void* d_ws, size_t ws_size,
                              hipStream_t stream){
  const float* X     =(const float*)d_in[0];
  const float* E     =(const float*)d_in[1];
  const float* y     =(const float*)d_in[2];
  const int*   nm    =(const int*)  d_in[3];
  const float* W_emax=(const float*)d_in[4];
  const float* W_x1  =(const float*)d_in[5];
  const float* Wq    =(const float*)d_in[6];
  const float* Wk    =(const float*)d_in[7];
  const float* Wv    =(const float*)d_in[8];
  const float* Wo    =(const float*)d_in[9];
  const float* W_y2  =(const float*)d_in[10];
  const float* W_x2  =(const float*)d_in[11];
  const float* Wc    =(const float*)d_in[12];
  const float* bc    =(const float*)d_in[13];
  const float* salpha=(const float*)d_in[14];
  const float* W_Eout=(const float*)d_in[15];
  const float* G_kern=(const float*)d_in[16];
  const float* X_kern=(const float*)d_in[17];
  const float* W_Gtr =(const float*)d_in[18];
  const float* W_Xtr =(const float*)d_in[19];
  const float* W_yout=(const float*)d_in[20];
  const float* gx    =(const float*)d_in[21];
  const float* bx    =(const float*)d_in[22];
  const float* ge    =(const float*)d_in[23];
  const float* be    =(const float*)d_in[24];
  const float* gy    =(const float*)d_in[25];
  const float* by    =(const float*)d_in[26];

  char* wsb=(char*)d_ws;
  bf16* Gbf=(bf16*)wsb;                        // [0,32M)
  short* Gs=(short*)wsb;
  short* Bt2=(short*)(wsb+33554432);           // [32M,64M)
  short* Gts=(short*)(wsb+67108864);           // [64M,96M) Gt; reused as NEWEbf after bmm_t
  short* NEWEbf=(short*)(wsb+67108864);
  float* Npart=(float*)(wsb+33554432);         // aliases Bt2 (dead after poly2)
  float* f32=(float*)(wsb+100663296);          // [96M,...)
  float* sim  = f32+F_SIM;
  float* P    = f32+F_P;
  float* Dpart= f32+F_NP;
  float* Gp   = f32+F_GP;
  float* Xp   = f32+F_XP;
  float* S    = f32+F_S;
  float* eenc = f32+F_EENC;
  float* xplus= f32+F_XPL;
  float* qb   = f32+F_QB;
  float* kb   = f32+F_KB;
  float* vb   = f32+F_VB;
  float* yw   = f32+F_YW;
  float* xpy  = f32+F_XPY;
  float* coeff= f32+F_COEF;
  float* Genc = f32+F_GENC;
  float* Xenc = f32+F_XENC;

  float* out=(float*)d_out;
  float* newX=out;
  float* newE_out=out+262144;
  float* newy=out+17039360;

  k_coeff_yw<<<cB,256,0,stream>>>(y,Wc,bc,W_y2,coeff,yw);
  k_reduceE<<<cB*cN,dim3(64,4),0,stream>>>(E,nm,S);
  k_eenc<<<cB*cN,256,0,stream>>>(S,W_emax,nm,eenc);
  k_xplus<<<cB*cN,256,0,stream>>>(X,eenc,W_x1,nm,xplus);
  k_qkv<<<cB*cN,256,0,stream>>>(xplus,Wq,Wk,Wv,qb,kb,vb);
  k_attn_softmax<<<cB*cNH*cN,256,0,stream>>>(qb,kb,nm,P);
  k_attn_out<<<cB*cN,256,0,stream>>>(P,vb,Wo,X,nm,gx,bx,newX);
  k_xplusy<<<cB*cN,256,0,stream>>>(X,yw,W_x2,xpy);
  k_sim<<<dim3(16,16,cB),dim3(16,16),0,stream>>>(xpy,sim);
  k_G<<<cB*cN,256,0,stream>>>(E,sim,nm,salpha,Gbf);
  k_transp<<<dim3(2,2,cB*cDE),256,0,stream>>>(Gs,Gts);
  k_bmm_t<<<dim3(2,2,cB*cDE),256,0,stream>>>(Gs,Gts,Bt2,coeff);
  k_bmm_f<<<dim3(2,2,cB*cDE),256,0,stream>>>(Gs,Bt2,NEWEbf,coeff);
  k_Eout_mfma<<<1024,256,0,stream>>>(NEWEbf,E,nm,W_Eout,ge,be,newE_out);
  k_Gaccum_mfma<<<dim3(128,cB),256,0,stream>>>(E,nm,G_kern,Npart,Dpart);
  k_Gcombine<<<cB*128,64,0,stream>>>(Npart,Dpart,Genc);
  k_Xenc<<<dim3(64,cB),256,0,stream>>>(X,nm,X_kern,Xenc);
  k_headA<<<192,256,0,stream>>>(Genc,Xenc,W_Gtr,W_Xtr,Gp,Xp);
  k_headB<<<cB,128,0,stream>>>(Gp,Xp,W_yout,y,gy,by,newy);
}

// Round 15
// 383.021 us; speedup vs baseline: 4.3532x; 1.0184x over previous
//
#include <hip/hip_runtime.h>
#include <hip/hip_bf16.h>

typedef __hip_bfloat16 bf16;
__device__ __forceinline__ bf16 tobf(float v){ return __float2bfloat16(v); }
__device__ __forceinline__ float frombf(bf16 v){ return __bfloat162float(v); }
__device__ __forceinline__ short f2bs(float x){ bf16 h=tobf(x); return *reinterpret_cast<short*>(&h); }
__device__ __forceinline__ float bs2f(short s){ unsigned int v=((unsigned int)(unsigned short)s)<<16; return __int_as_float((int)v); }

typedef __attribute__((ext_vector_type(8))) short bf16x8;
typedef __attribute__((ext_vector_type(4))) short short4v;
typedef __attribute__((ext_vector_type(4))) float f32x4;
typedef __attribute__((ext_vector_type(4))) int int4v;

static constexpr int cB=4, cN=256, cDX=256, cDE=64, cDY=128, cNH=8, cDF=32;

// ---- workspace layout (bytes) ----
// [0,   32M)  G    bf16
// [32M, 64M)  Bt2  bf16 (poly1 out, transposed)  -- after poly2: Npart f32 (16.8MB)
// [64M, 96M)  Gt   bf16 (G transposed)  -- after bmm_t: NEWEbf bf16 (33.5MB, poly2 out)
// [96M, ...)  f32 region (offsets in floats below)
static constexpr size_t F_SIM  = 0;
static constexpr size_t F_P    = 262144;
static constexpr size_t F_NP   = 2359296;
static constexpr size_t F_GP   = F_NP + 1048576;
static constexpr size_t F_XP   = F_NP + 1048576 + 32768;
static constexpr size_t F_S    = 6619136;
static constexpr size_t F_EENC = 6684672;
static constexpr size_t F_XPL  = 6946816;
static constexpr size_t F_QB   = 7208960;
static constexpr size_t F_KB   = 7471104;
static constexpr size_t F_VB   = 7733248;
static constexpr size_t F_YW   = 7995392;
static constexpr size_t F_XPY  = 7996416;
static constexpr size_t F_COEF = 8258560;
static constexpr size_t F_GENC = 8258576;
static constexpr size_t F_XENC = 8291344;

// ---------------- coeff = y@Wc+bc ; yw = relu(y@W_y2) ----------------
__global__ void k_coeff_yw(const float* y, const float* Wc, const float* bc,
                           const float* W_y2, float* coeff, float* yw){
  int b = blockIdx.x; int f = threadIdx.x;
  float acc = 0.f;
  for(int r=0;r<cDY;++r) acc += y[b*cDY+r]*W_y2[r*cDX+f];
  yw[b*cDX+f] = fmaxf(acc,0.f);
  if (f < 3){
    float c = bc[f];
    for(int r=0;r<cDY;++r) c += y[b*cDY+r]*Wc[r*3+f];
    coeff[b*3+f] = c;
  }
}

// ---------------- S[b,i,d] = sum_j E[b,i,j,d]*m_j  (float4 vectorized) ----------------
__global__ void __launch_bounds__(256) k_reduceE(const float* E, const int* nm, float* S){
  int bi = blockIdx.x; int b = bi / cN;
  int t = threadIdx.x;
  int seg = t&15;      // d-segment of 4 floats
  int rg  = t>>4;      // row group 0..15
  const float* Eb = E + (size_t)bi*cN*cDE;
  f32x4 acc = (f32x4){0.f,0.f,0.f,0.f};
  for(int j=rg;j<cN;j+=16){
    float m = (float)nm[b*cN+j];
    f32x4 v = *(const f32x4*)&Eb[j*cDE + seg*4];
    acc[0]+=v[0]*m; acc[1]+=v[1]*m; acc[2]+=v[2]*m; acc[3]+=v[3]*m;
  }
  __shared__ f32x4 red[16][16];
  red[rg][seg]=acc; __syncthreads();
  for(int st=8;st>0;st>>=1){
    if(rg<st){
      f32x4 o=red[rg+st][seg];
      f32x4 s=red[rg][seg];
      s[0]+=o[0]; s[1]+=o[1]; s[2]+=o[2]; s[3]+=o[3];
      red[rg][seg]=s;
    }
    __syncthreads();
  }
  if(rg==0) *(f32x4*)&S[(size_t)bi*cDE + seg*4]=red[0][seg];
}

// ---------------- e_enc ----------------
__global__ void k_eenc(const float* S, const float* W_emax, const int* nm, float* eenc){
  int bi = blockIdx.x; int b = bi/cN; int i = bi%cN;
  int f = threadIdx.x;
  __shared__ float s[cDE];
  if (f<cDE) s[f]=S[(size_t)bi*cDE+f];
  __syncthreads();
  float acc=0.f;
  for(int d=0;d<cDE;++d) acc += s[d]*W_emax[d*cDX+f];
  float mi=(float)nm[b*cN+i];
  eenc[(size_t)bi*cDX+f] = fmaxf(acc*mi*(1.f/cN), 0.f);
}

// ---------------- xplus ----------------
__global__ void k_xplus(const float* X, const float* eenc, const float* W_x1,
                        const int* nm, float* xplus){
  int bi=blockIdx.x; int b=bi/cN; int i=bi%cN;
  int f=threadIdx.x;
  __shared__ float row[cDX];
  row[f]=eenc[(size_t)bi*cDX+f];
  __syncthreads();
  float acc=0.f;
  for(int c=0;c<cDX;++c) acc += row[c]*W_x1[c*cDX+f];
  float mi=(float)nm[b*cN+i];
  xplus[(size_t)bi*cDX+f] = (X[(size_t)bi*cDX+f] + fmaxf(acc,0.f))*mi;
}

// ---------------- q,k,v ----------------
__global__ void k_qkv(const float* xplus, const float* Wq, const float* Wk, const float* Wv,
                      float* qb, float* kb, float* vb){
  int bi=blockIdx.x; int f=threadIdx.x;
  __shared__ float row[cDX];
  row[f]=xplus[(size_t)bi*cDX+f];
  __syncthreads();
  float aq=0,ak=0,av=0;
  for(int c=0;c<cDX;++c){ float r=row[c]; aq+=r*Wq[c*cDX+f]; ak+=r*Wk[c*cDX+f]; av+=r*Wv[c*cDX+f]; }
  qb[(size_t)bi*cDX+f]=aq; kb[(size_t)bi*cDX+f]=ak; vb[(size_t)bi*cDX+f]=av;
}

// ---------------- attention softmax ----------------
__global__ void k_attn_softmax(const float* qb, const float* kb, const int* nm, float* P){
  int id=blockIdx.x; int b=id/(cNH*cN); int rem=id%(cNH*cN); int h=rem/cN; int i=rem%cN;
  int j=threadIdx.x;
  __shared__ float qrow[cDF];
  if (j<cDF) qrow[j]=qb[((size_t)b*cN+i)*cDX + h*cDF + j];
  __syncthreads();
  const float* krow = kb + ((size_t)b*cN+j)*cDX + h*cDF;
  float s=0.f;
  for(int c=0;c<cDF;++c) s += qrow[c]*krow[c];
  s *= 0.17677669529663687f;
  float val = (nm[b*cN+j]>0) ? s : -1e9f;
  __shared__ float red[256];
  red[j]=val; __syncthreads();
  for(int st=128;st>0;st>>=1){ if(j<st) red[j]=fmaxf(red[j],red[j+st]); __syncthreads(); }
  float mx=red[0]; __syncthreads();
  float e=__expf(val-mx);
  red[j]=e; __syncthreads();
  for(int st=128;st>0;st>>=1){ if(j<st) red[j]+=red[j+st]; __syncthreads(); }
  float denom=red[0];
  P[(size_t)id*cN + j] = e/denom;
}

// ---------------- attn out + LN -> new_X ----------------
__global__ void k_attn_out(const float* P, const float* vb, const float* Wo,
                           const float* X, const int* nm, const float* gx, const float* bx,
                           float* newX){
  int bi=blockIdx.x; int b=bi/cN; int i=bi%cN;
  int t=threadIdx.x;
  __shared__ float p8[cNH][cN];
  for(int h=0;h<cNH;++h) p8[h][t]=P[(((size_t)b*cNH+h)*cN+i)*cN + t];
  __syncthreads();
  int h=t/cDF;
  float acc=0.f;
  for(int j=0;j<cN;++j) acc += p8[h][j]*vb[((size_t)b*cN+j)*cDX + t];
  __shared__ float arow[cDX];
  arow[t]=acc; __syncthreads();
  float o=0.f;
  for(int c=0;c<cDX;++c) o += arow[c]*Wo[c*cDX+t];
  float mi=(float)nm[b*cN+i];
  float v = o*mi + X[(size_t)bi*cDX+t];
  __shared__ float red[256];
  red[t]=v; __syncthreads();
  for(int st=128;st>0;st>>=1){ if(t<st) red[t]+=red[t+st]; __syncthreads(); }
  float mean=red[0]*(1.f/cDX); __syncthreads();
  float dv=v-mean;
  red[t]=dv*dv; __syncthreads();
  for(int st=128;st>0;st>>=1){ if(t<st) red[t]+=red[t+st]; __syncthreads(); }
  float var=red[0]*(1.f/cDX);
  newX[(size_t)bi*cDX+t]=dv*rsqrtf(var+1e-6f)*gx[t]+bx[t];
}

// ---------------- xplusy ----------------
__global__ void k_xplusy(const float* X, const float* yw, const float* W_x2, float* xpy){
  int bi=blockIdx.x; int b=bi/cN;
  int f=threadIdx.x;
  __shared__ float row[cDX];
  row[f]=X[(size_t)bi*cDX+f]+yw[b*cDX+f];
  __syncthreads();
  float acc=0.f;
  for(int c=0;c<cDX;++c) acc += row[c]*W_x2[c*cDX+f];
  xpy[(size_t)bi*cDX+f]=fmaxf(acc,0.f);
}

// ---------------- sim ----------------
__global__ void k_sim(const float* xp, float* sim){
  int b=blockIdx.z;
  int tx=threadIdx.x, ty=threadIdx.y;
  __shared__ float Aa[16][17], Bb[16][17];
  const float* base = xp + (size_t)b*cN*cDX;
  float acc=0.f;
  for(int kt=0;kt<cDX;kt+=16){
    Aa[ty][tx]=base[(size_t)(blockIdx.y*16+ty)*cDX + kt+tx];
    Bb[ty][tx]=base[(size_t)(blockIdx.x*16+ty)*cDX + kt+tx];
    __syncthreads();
    for(int c=0;c<16;++c) acc += Aa[ty][c]*Bb[tx][c];
    __syncthreads();
  }
  sim[((size_t)b*cN + blockIdx.y*16+ty)*cN + blockIdx.x*16+tx] = acc*(1.f/16.f);
}

// ---------------- G = (alpha*sim + E)*emask (bf16) ----------------
__global__ void k_G(const float* E, const float* sim, const int* nm, const float* alpha_p,
                    bf16* G){
  int bi=blockIdx.x; int b=bi/cN; int i=bi%cN;
  float mi=(float)nm[b*cN+i];
  float alpha=alpha_p[0];
  size_t base=(size_t)bi*cN*cDE;
  for(int t=threadIdx.x;t<cN*cDE;t+=blockDim.x){
    int j=t>>6;
    float mj=(float)nm[b*cN+j];
    G[base+t]=tobf((alpha*sim[(size_t)bi*cN+j]+E[base+t])*mi*mj);
  }
}

// ---------------- per-slice transpose: Gt[bc][q][p] = G[bc][p][q] ----------------
__global__ void __launch_bounds__(256) k_transp(const short* G, short* Gt){
  const int bc=blockIdx.z;
  const int p0=blockIdx.y*128, q0=blockIdx.x*128;
  const int t=threadIdx.x;
  __shared__ short T[128][136];
  const short* src=G+(size_t)bc*65536;
  short* dst=Gt+(size_t)bc*65536;
#pragma unroll
  for(int l=0;l<8;++l){
    int idx=t+l*256;
    int r=idx>>4, seg=idx&15;
    *(int4v*)&T[r][seg*8]=*(const int4v*)&src[(size_t)(p0+r)*256 + q0 + seg*8];
  }
  __syncthreads();
  int qq=t&127, hf=t>>7;
#pragma unroll
  for(int ss=0;ss<8;++ss){
    bf16x8 v;
#pragma unroll
    for(int ii=0;ii<8;++ii) v[ii]=T[hf*64+ss*8+ii][qq];
    *(bf16x8*)&dst[(size_t)(q0+qq)*256 + p0 + hf*64 + ss*8]=v;
  }
}

// ---------------- poly1: Bt2 = (c0*(G@G) + c1*G)^T ----------------
__global__ void __launch_bounds__(256) k_bmm_t(const short* G, const short* Gt, short* Bt2,
                                               const float* coeff){
  const int bc=blockIdx.z; const int b=bc>>6;
  const float alpha=coeff[b*3+0];
  const float beta=coeff[b*3+1];
  const short* Ag=G+(size_t)bc*65536;
  const short* At=Gt+(size_t)bc*65536;
  short* Ct=Bt2+(size_t)bc*65536;
  const int row0=blockIdx.y*128, col0=blockIdx.x*128;
  const int t=threadIdx.x;
  const int lane=t&63, w=t>>6;
  const int wr=w>>1, wc=w&1;
  const int l15=lane&15, l4=lane>>4;
  __shared__ char smem[36864];
  short (*A_s)[72]=(short(*)[72])smem;
  short (*B_s)[72]=(short(*)[72])(smem+18432);
  float (*Cf)[132]=(float(*)[132])smem;
  f32x4 acc[4][4];
#pragma unroll
  for(int m=0;m<4;++m)
#pragma unroll
    for(int n=0;n<4;++n) acc[m][n]=(f32x4){0.f,0.f,0.f,0.f};

  for(int kt=0;kt<256;kt+=64){
#pragma unroll
    for(int l=0;l<4;++l){
      int idx=t+l*256;
      int r=idx>>3, seg=idx&7;
      *(int4v*)&A_s[r][seg*8]=*(const int4v*)&Ag[(size_t)(row0+r)*256 + kt + seg*8];
      *(int4v*)&B_s[r][seg*8]=*(const int4v*)&At[(size_t)(col0+r)*256 + kt + seg*8];
    }
    __syncthreads();
#pragma unroll
    for(int ks=0;ks<64;ks+=32){
      bf16x8 am[4], bn[4];
#pragma unroll
      for(int m=0;m<4;++m) am[m]=*(const bf16x8*)&A_s[wr*64+m*16+l15][ks+l4*8];
#pragma unroll
      for(int n=0;n<4;++n) bn[n]=*(const bf16x8*)&B_s[wc*64+n*16+l15][ks+l4*8];
#pragma unroll
      for(int m=0;m<4;++m)
#pragma unroll
        for(int n=0;n<4;++n)
          acc[m][n]=__builtin_amdgcn_mfma_f32_16x16x32_bf16(am[m],bn[n],acc[m][n],0,0,0);
    }
    __syncthreads();
  }
  for(int rs=0;rs<8;++rs){
    if(rs) __syncthreads();
    int m=rs&3;
    if(wr==(rs>>2)){
#pragma unroll
      for(int n=0;n<4;++n)
#pragma unroll
        for(int r=0;r<4;++r)
          Cf[l4*4+r][wc*64+n*16+l15]=acc[m][n][r];
    }
    __syncthreads();
    int c=t>>1, hf=t&1;
    const short* gsrc=&At[(size_t)(col0+c)*256 + row0 + rs*16 + hf*8];
    short* dst=&Ct[(size_t)(col0+c)*256 + row0 + rs*16 + hf*8];
    bf16x8 a8=*(const bf16x8*)gsrc;
    bf16x8 o8;
#pragma unroll
    for(int ii=0;ii<8;++ii)
      o8[ii]=f2bs(alpha*Cf[hf*8+ii][c] + beta*bs2f(a8[ii]));
    *(bf16x8*)dst=o8;
  }
}

// ---------------- poly2: NEWEbf = bf16(G@Bbuf + c2*G) ----------------
__global__ void __launch_bounds__(256) k_bmm_f(const short* G, const short* Bt2, short* Cbf,
                                               const float* coeff){
  const int bc=blockIdx.z; const int b=bc>>6;
  const float beta=coeff[b*3+2];
  const short* Ag=G+(size_t)bc*65536;
  const short* Bt=Bt2+(size_t)bc*65536;
  short* Cb=Cbf+(size_t)bc*65536;
  const int row0=blockIdx.y*128, col0=blockIdx.x*128;
  const int t=threadIdx.x;
  const int lane=t&63, w=t>>6;
  const int wr=w>>1, wc=w&1;
  const int l15=lane&15, l4=lane>>4;
  __shared__ char smem[36864];
  short (*A_s)[72]=(short(*)[72])smem;
  short (*B_s)[72]=(short(*)[72])(smem+18432);
  float (*Cf)[132]=(float(*)[132])smem;
  f32x4 acc[4][4];
#pragma unroll
  for(int m=0;m<4;++m)
#pragma unroll
    for(int n=0;n<4;++n) acc[m][n]=(f32x4){0.f,0.f,0.f,0.f};

  for(int kt=0;kt<256;kt+=64){
#pragma unroll
    for(int l=0;l<4;++l){
      int idx=t+l*256;
      int r=idx>>3, seg=idx&7;
      *(int4v*)&A_s[r][seg*8]=*(const int4v*)&Ag[(size_t)(row0+r)*256 + kt + seg*8];
      *(int4v*)&B_s[r][seg*8]=*(const int4v*)&Bt[(size_t)(col0+r)*256 + kt + seg*8];
    }
    __syncthreads();
#pragma unroll
    for(int ks=0;ks<64;ks+=32){
      bf16x8 am[4], bn[4];
#pragma unroll
      for(int m=0;m<4;++m) am[m]=*(const bf16x8*)&A_s[wr*64+m*16+l15][ks+l4*8];
#pragma unroll
      for(int n=0;n<4;++n) bn[n]=*(const bf16x8*)&B_s[wc*64+n*16+l15][ks+l4*8];
#pragma unroll
      for(int m=0;m<4;++m)
#pragma unroll
        for(int n=0;n<4;++n)
          acc[m][n]=__builtin_amdgcn_mfma_f32_16x16x32_bf16(am[m],bn[n],acc[m][n],0,0,0);
    }
    __syncthreads();
  }
  for(int rs=0;rs<8;++rs){
    if(rs) __syncthreads();
    int m=rs&3;
    if(wr==(rs>>2)){
#pragma unroll
      for(int n=0;n<4;++n)
#pragma unroll
        for(int r=0;r<4;++r)
          Cf[l4*4+r][wc*64+n*16+l15]=acc[m][n][r];
    }
    __syncthreads();
    int r=t>>4, cs=t&15;
    int row=row0+rs*16+r;
    const short* asrc=&Ag[(size_t)row*256 + col0 + cs*8];
    short* dst=&Cb[(size_t)row*256 + col0 + cs*8];
    bf16x8 a8=*(const bf16x8*)asrc;
    bf16x8 o8;
#pragma unroll
    for(int ii=0;ii<8;++ii)
      o8[ii]=f2bs(Cf[r][cs*8+ii] + beta*bs2f(a8[ii]));
    *(bf16x8*)dst=o8;
  }
}

// ---------------- k_Eout_mfma (reads bf16 NEWE staging) ----------------
__global__ void __launch_bounds__(256) k_Eout_mfma(const short* newE_in, const float* E,
                       const int* nm, const float* W_Eout, const float* ge, const float* be,
                       float* outE){
  const int t=threadIdx.x;
  const int lane=t&63, w=t>>6;
  const int l15=lane&15, l4=lane>>4;
  const int blk=blockIdx.x;
  const int b=blk>>8, i=blk&255;
  const float mi=(float)nm[b*cN+i];
  bf16x8 bnf[2][4];
#pragma unroll
  for(int ks=0;ks<2;++ks)
#pragma unroll
    for(int n=0;n<4;++n){
      bf16x8 v;
#pragma unroll
      for(int ii=0;ii<8;++ii)
        v[ii]=f2bs(W_Eout[(ks*32+l4*8+ii)*cDE + n*16+l15]);
      bnf[ks][n]=v;
    }
  float gev[4], bev[4];
#pragma unroll
  for(int n=0;n<4;++n){ gev[n]=ge[n*16+l15]; bev[n]=be[n*16+l15]; }

  for(int it=0;it<4;++it){
    const int j0=it*64+w*16;
    const int p0=blk*256 + j0;
    f32x4 acc[4];
#pragma unroll
    for(int n=0;n<4;++n) acc[n]=(f32x4){0.f,0.f,0.f,0.f};
    if(mi>0.f){
#pragma unroll
      for(int ks=0;ks<2;++ks){
        bf16x8 am=*(const bf16x8*)&newE_in[(size_t)(p0+l15)*cDE + ks*32 + l4*8];
#pragma unroll
        for(int n=0;n<4;++n)
          acc[n]=__builtin_amdgcn_mfma_f32_16x16x32_bf16(am,bnf[ks][n],acc[n],0,0,0);
      }
    }
    float mj[4];
#pragma unroll
    for(int r=0;r<4;++r) mj[r]=mi*(float)nm[b*cN + j0 + l4*4 + r];
#pragma unroll
    for(int reg=0;reg<4;++reg){
      size_t rowoff=(size_t)(p0 + l4*4 + reg)*cDE;
      float v0=fmaxf(acc[0][reg],0.f)*mj[reg]+E[rowoff + 0*16+l15];
      float v1=fmaxf(acc[1][reg],0.f)*mj[reg]+E[rowoff + 1*16+l15];
      float v2=fmaxf(acc[2][reg],0.f)*mj[reg]+E[rowoff + 2*16+l15];
      float v3=fmaxf(acc[3][reg],0.f)*mj[reg]+E[rowoff + 3*16+l15];
      float s=v0+v1+v2+v3;
      float q=v0*v0+v1*v1+v2*v2+v3*v3;
#pragma unroll
      for(int m=1;m<16;m<<=1){ s+=__shfl_xor(s,m); q+=__shfl_xor(q,m); }
      float mean=s*(1.f/cDE);
      float var=q*(1.f/cDE)-mean*mean;
      float inv=rsqrtf(var+1e-6f);
      outE[rowoff + 0*16+l15]=(v0-mean)*inv*gev[0]+bev[0];
      outE[rowoff + 1*16+l15]=(v1-mean)*inv*gev[1]+bev[1];
      outE[rowoff + 2*16+l15]=(v2-mean)*inv*gev[2]+bev[2];
      outE[rowoff + 3*16+l15]=(v3-mean)*inv*gev[3]+bev[3];
    }
  }
}

// ---------------- k_Gaccum_mfma ----------------
__global__ void __launch_bounds__(256) k_Gaccum_mfma(const float* E, const int* nm,
                                                     const float* G_kernel,
                                                     float* Npart, float* Dpart){
  const int chunk=blockIdx.x;
  const int b=blockIdx.y;
  const int t=threadIdx.x;
  const int lane=t&63, w=t>>6;
  const int l15=lane&15, l4=lane>>4;

  __shared__ short EmA[128][72];
  __shared__ short EmT[64][136];
  __shared__ short Wt[128][136];
  __shared__ float mrow[128];
  __shared__ float Dacc[128];
  __shared__ float Dpar[4][128];

  bf16x8 gk[2][8];
#pragma unroll
  for(int kt=0;kt<2;++kt)
#pragma unroll
    for(int n=0;n<8;++n){
      bf16x8 v;
#pragma unroll
      for(int ii=0;ii<8;++ii)
        v[ii]=f2bs(G_kernel[(kt*32+l4*8+ii)*128 + n*16+l15]*0.125f);
      gk[kt][n]=v;
    }

  f32x4 nacc[2][4];
#pragma unroll
  for(int a=0;a<2;++a)
#pragma unroll
    for(int d2=0;d2<4;++d2) nacc[a][d2]=(f32x4){0.f,0.f,0.f,0.f};

  if(t<128) Dacc[t]=0.f;
  __syncthreads();

  const size_t ebase=((size_t)b)<<16;
  for(int sub=0;sub<4;++sub){
    const int rowbase = chunk*512 + sub*128;
    {
      int pr=t>>1, hh=t&1;
      int p=rowbase+pr;
      const float* src=&E[(ebase+p)*cDE + hh*32];
#pragma unroll
      for(int q=0;q<8;++q){
        float4 v=*(const float4*)(src+q*4);
        short4v s4; s4[0]=f2bs(v.x); s4[1]=f2bs(v.y); s4[2]=f2bs(v.z); s4[3]=f2bs(v.w);
        *(short4v*)&EmA[pr][hh*32+q*4]=s4;
        EmT[hh*32+q*4+0][pr]=s4[0];
        EmT[hh*32+q*4+1][pr]=s4[1];
        EmT[hh*32+q*4+2][pr]=s4[2];
        EmT[hh*32+q*4+3][pr]=s4[3];
      }
      if(hh==0) mrow[pr]=(float)(nm[b*cN+(p>>8)]*nm[b*cN+(p&255)]);
    }
    __syncthreads();

    f32x4 wacc[2][8];
#pragma unroll
    for(int m=0;m<2;++m)
#pragma unroll
      for(int n=0;n<8;++n) wacc[m][n]=(f32x4){0.f,0.f,0.f,0.f};
#pragma unroll
    for(int kt=0;kt<2;++kt){
      bf16x8 am[2];
#pragma unroll
      for(int m=0;m<2;++m) am[m]=*(const bf16x8*)&EmA[w*32+m*16+l15][kt*32+l4*8];
#pragma unroll
      for(int m=0;m<2;++m)
#pragma unroll
        for(int n=0;n<8;++n)
          wacc[m][n]=__builtin_amdgcn_mfma_f32_16x16x32_bf16(am[m],gk[kt][n],wacc[m][n],0,0,0);
    }
    float dsum[8];
#pragma unroll
    for(int n=0;n<8;++n) dsum[n]=0.f;
#pragma unroll
    for(int m=0;m<2;++m){
#pragma unroll
      for(int r=0;r<4;++r){
        int pl=w*32+m*16+l4*4+r;
        float mv=mrow[pl];
#pragma unroll
        for(int n=0;n<8;++n){
          float wv=(mv>0.f)?__expf(wacc[m][n][r]):0.f;
          dsum[n]+=wv;
          Wt[n*16+l15][pl]=f2bs(wv);
        }
      }
    }
#pragma unroll
    for(int n=0;n<8;++n){
      float s=dsum[n];
      s+=__shfl_xor(s,16); s+=__shfl_xor(s,32);
      if(l4==0) Dpar[w][n*16+l15]=s;
    }
    __syncthreads();

#pragma unroll
    for(int ks=0;ks<4;++ks){
      bf16x8 aw[2];
#pragma unroll
      for(int a=0;a<2;++a) aw[a]=*(const bf16x8*)&Wt[w*32+a*16+l15][ks*32+l4*8];
      bf16x8 bm[4];
#pragma unroll
      for(int d2=0;d2<4;++d2)
        bm[d2]=*(const bf16x8*)&EmT[d2*16+l15][ks*32+l4*8];
#pragma unroll
      for(int a=0;a<2;++a)
#pragma unroll
        for(int d2=0;d2<4;++d2)
          nacc[a][d2]=__builtin_amdgcn_mfma_f32_16x16x32_bf16(aw[a],bm[d2],nacc[a][d2],0,0,0);
    }
    __syncthreads();
    if(t<128) Dacc[t]+=Dpar[0][t]+Dpar[1][t]+Dpar[2][t]+Dpar[3][t];
    __syncthreads();
  }

  size_t pi=(size_t)b*128+chunk;
  float* np=Npart + pi*128*cDE;
#pragma unroll
  for(int a=0;a<2;++a){
#pragma unroll
    for(int d2=0;d2<4;++d2){
#pragma unroll
      for(int r=0;r<4;++r){
        int k=w*32+a*16+l4*4+r;
        int d=d2*16+l15;
        np[(size_t)k*cDE+d]=nacc[a][d2][r];
      }
    }
  }
  if(t<128) Dpart[pi*128+t]=Dacc[t];
}

// ---------------- combine partials -> Genc ----------------
__global__ void k_Gcombine(const float* Npart, const float* Dpart, float* Genc){
  int bk=blockIdx.x; int b=bk>>7; int k=bk&127;
  int d=threadIdx.x;
  float n=0.f, dd=0.f;
  for(int pi=0;pi<128;++pi){
    size_t base=((size_t)b*128+pi)*128+k;
    n += Npart[base*cDE+d];
    dd += Dpart[base];
  }
  Genc[(size_t)b*8192 + k*cDE + d]=n/dd;
}

// ---------------- aX softmax + X_enc ----------------
__global__ void k_Xenc(const float* X, const int* nm, const float* X_kernel, float* Xenc){
  int k=blockIdx.x;
  int b=blockIdx.y;
  int n=threadIdx.x;
  float m=(float)nm[b*cN+n];
  const float* xr=X+((size_t)b*cN+n)*cDX;
  float acc=0.f;
  for(int c=0;c<cDX;++c) acc += xr[c]*X_kernel[c*64+k];
  float lg=(m>0.f)?acc*(1.f/16.f):-1e9f;
  __shared__ float red[256];
  red[n]=lg; __syncthreads();
  for(int st=128;st>0;st>>=1){ if(n<st) red[n]=fmaxf(red[n],red[n+st]); __syncthreads(); }
  float mx=red[0]; __syncthreads();
  float e=__expf(lg-mx);
  red[n]=e; __syncthreads();
  for(int st=128;st>0;st>>=1){ if(n<st) red[n]+=red[n+st]; __syncthreads(); }
  float denom=red[0]; __syncthreads();
  __shared__ float ps[256];
  ps[n]=e/denom;
  __syncthreads();
  int d=n;
  float s=0.f;
  for(int nn=0;nn<cN;++nn) s += ps[nn]*X[((size_t)b*cN+nn)*cDX+d];
  Xenc[(size_t)b*16384 + k*cDX + d]=s;
}

// ---------------- head partials ----------------
__global__ void __launch_bounds__(256) k_headA(const float* Genc, const float* Xenc,
                        const float* W_Gtrans, const float* W_Xtrans,
                        float* Gp, float* Xp){
  int blk=blockIdx.x;
  int t=threadIdx.x;
  int o=t&127, sub=t>>7;
  int b0=sub*2, b1=sub*2+1;
  __shared__ float ash[4][128];
  if(blk<64){
    int ch=blk;
    for(int l=t;l<512;l+=256){
      int b=l>>7, q=l&127;
      ash[b][q]=Genc[(size_t)b*8192 + ch*128 + q];
    }
    __syncthreads();
    const float* wbase=W_Gtrans + (size_t)ch*128*cDY + o;
    float a0=0.f, a1=0.f;
#pragma unroll 4
    for(int qq=0;qq<128;++qq){
      float w=wbase[(size_t)qq*cDY];
      a0+=ash[b0][qq]*w; a1+=ash[b1][qq]*w;
    }
    Gp[((size_t)b0*64+ch)*cDY+o]=a0;
    Gp[((size_t)b1*64+ch)*cDY+o]=a1;
  } else {
    int ch=blk-64;
    for(int l=t;l<512;l+=256){
      int b=l>>7, q=l&127;
      ash[b][q]=Xenc[(size_t)b*16384 + ch*128 + q];
    }
    __syncthreads();
    const float* wbase=W_Xtrans + (size_t)ch*128*cDY + o;
    float a0=0.f, a1=0.f;
#pragma unroll 4
    for(int qq=0;qq<128;++qq){
      float w=wbase[(size_t)qq*cDY];
      a0+=ash[b0][qq]*w; a1+=ash[b1][qq]*w;
    }
    Xp[((size_t)b0*128+ch)*cDY+o]=a0;
    Xp[((size_t)b1*128+ch)*cDY+o]=a1;
  }
}

// ---------------- head final -> new_y ----------------
__global__ void k_headB(const float* Gp, const float* Xp, const float* W_yout,
                        const float* y, const float* gy, const float* by, float* newy){
  int b=blockIdx.x; int o=threadIdx.x;
  float g=0.f,x=0.f;
  for(int ch=0;ch<64;++ch)  g+=Gp[((size_t)b*64+ch)*cDY+o];
  for(int ch=0;ch<128;++ch) x+=Xp[((size_t)b*128+ch)*cDY+o];
  __shared__ float srow[cDY];
  srow[o]=fmaxf(g,0.f)+fmaxf(x,0.f);
  __syncthreads();
  float h=0.f;
  for(int r=0;r<cDY;++r) h += srow[r]*W_yout[r*cDY+o];
  float v=fmaxf(h,0.f)+y[b*cDY+o];
  __shared__ float red[cDY];
  red[o]=v; __syncthreads();
  for(int st=64;st>0;st>>=1){ if(o<st) red[o]+=red[o+st]; __syncthreads(); }
  float mean=red[0]*(1.f/cDY); __syncthreads();
  float dv=v-mean;
  red[o]=dv*dv; __syncthreads();
  for(int st=64;st>0;st>>=1){ if(o<st) red[o]+=red[o+st]; __syncthreads(); }
  float var=red[0]*(1.f/cDY);
  newy[b*cDY+o]=dv*rsqrtf(var+1e-6f)*gy[o]+by[o];
}

extern "C" void kernel_launch(void* const* d_in, const int* in_sizes, int n_in,
                              void* d_out, int out_size, void* d_ws, size_t ws_size,
                              hipStream_t stream){
  const float* X     =(const float*)d_in[0];
  const float* E     =(const float*)d_in[1];
  const float* y     =(const float*)d_in[2];
  const int*   nm    =(const int*)  d_in[3];
  const float* W_emax=(const float*)d_in[4];
  const float* W_x1  =(const float*)d_in[5];
  const float* Wq    =(const float*)d_in[6];
  const float* Wk    =(const float*)d_in[7];
  const float* Wv    =(const float*)d_in[8];
  const float* Wo    =(const float*)d_in[9];
  const float* W_y2  =(const float*)d_in[10];
  const float* W_x2  =(const float*)d_in[11];
  const float* Wc    =(const float*)d_in[12];
  const float* bc    =(const float*)d_in[13];
  const float* salpha=(const float*)d_in[14];
  const float* W_Eout=(const float*)d_in[15];
  const float* G_kern=(const float*)d_in[16];
  const float* X_kern=(const float*)d_in[17];
  const float* W_Gtr =(const float*)d_in[18];
  const float* W_Xtr =(const float*)d_in[19];
  const float* W_yout=(const float*)d_in[20];
  const float* gx    =(const float*)d_in[21];
  const float* bx    =(const float*)d_in[22];
  const float* ge    =(const float*)d_in[23];
  const float* be    =(const float*)d_in[24];
  const float* gy    =(const float*)d_in[25];
  const float* by    =(const float*)d_in[26];

  char* wsb=(char*)d_ws;
  bf16* Gbf=(bf16*)wsb;                        // [0,32M)
  short* Gs=(short*)wsb;
  short* Bt2=(short*)(wsb+33554432);           // [32M,64M)
  short* Gts=(short*)(wsb+67108864);           // [64M,96M) Gt; reused as NEWEbf after bmm_t
  short* NEWEbf=(short*)(wsb+67108864);
  float* Npart=(float*)(wsb+33554432);         // aliases Bt2 (dead after poly2)
  float* f32=(float*)(wsb+100663296);          // [96M,...)
  float* sim  = f32+F_SIM;
  float* P    = f32+F_P;
  float* Dpart= f32+F_NP;
  float* Gp   = f32+F_GP;
  float* Xp   = f32+F_XP;
  float* S    = f32+F_S;
  float* eenc = f32+F_EENC;
  float* xplus= f32+F_XPL;
  float* qb   = f32+F_QB;
  float* kb   = f32+F_KB;
  float* vb   = f32+F_VB;
  float* yw   = f32+F_YW;
  float* xpy  = f32+F_XPY;
  float* coeff= f32+F_COEF;
  float* Genc = f32+F_GENC;
  float* Xenc = f32+F_XENC;

  float* out=(float*)d_out;
  float* newX=out;
  float* newE_out=out+262144;
  float* newy=out+17039360;

  k_coeff_yw<<<cB,256,0,stream>>>(y,Wc,bc,W_y2,coeff,yw);
  k_reduceE<<<cB*cN,256,0,stream>>>(E,nm,S);
  k_eenc<<<cB*cN,256,0,stream>>>(S,W_emax,nm,eenc);
  k_xplus<<<cB*cN,256,0,stream>>>(X,eenc,W_x1,nm,xplus);
  k_qkv<<<cB*cN,256,0,stream>>>(xplus,Wq,Wk,Wv,qb,kb,vb);
  k_attn_softmax<<<cB*cNH*cN,256,0,stream>>>(qb,kb,nm,P);
  k_attn_out<<<cB*cN,256,0,stream>>>(P,vb,Wo,X,nm,gx,bx,newX);
  k_xplusy<<<cB*cN,256,0,stream>>>(X,yw,W_x2,xpy);
  k_sim<<<dim3(16,16,cB),dim3(16,16),0,stream>>>(xpy,sim);
  k_G<<<cB*cN,256,0,stream>>>(E,sim,nm,salpha,Gbf);
  k_transp<<<dim3(2,2,cB*cDE),256,0,stream>>>(Gs,Gts);
  k_bmm_t<<<dim3(2,2,cB*cDE),256,0,stream>>>(Gs,Gts,Bt2,coeff);
  k_bmm_f<<<dim3(2,2,cB*cDE),256,0,stream>>>(Gs,Bt2,NEWEbf,coeff);
  k_Eout_mfma<<<1024,256,0,stream>>>(NEWEbf,E,nm,W_Eout,ge,be,newE_out);
  k_Gaccum_mfma<<<dim3(128,cB),256,0,stream>>>(E,nm,G_kern,Npart,Dpart);
  k_Gcombine<<<cB*128,64,0,stream>>>(Npart,Dpart,Genc);
  k_Xenc<<<dim3(64,cB),256,0,stream>>>(X,nm,X_kern,Xenc);
  k_headA<<<192,256,0,stream>>>(Genc,Xenc,W_Gtr,W_Xtr,Gp,Xp);
  k_headB<<<cB,128,0,stream>>>(Gp,Xp,W_yout,y,gy,by,newy);
}